// Round 1
// baseline (1641.099 us; speedup 1.0000x reference)
//
#include <hip/hip_runtime.h>
#include <math.h>

#define NT 50000
#define NP 256
#define NE 800000
#define ET 850000   // NE + NT self loops
#define EMBD 64
#define NHEADS 4
#define HE 256      // NHEADS*EMBD
#define NG 8

// ---- workspace layout (bytes), all 256-aligned ----
#define OFF_DEG      0u          // 50000 i32          = 200000
#define OFF_INDPTR   200192u     // 50001 i32          = 200004
#define OFF_CURSOR   400384u     // 50000 i32          = 200000
#define OFF_EIDS     600576u     // 850000 i32         = 3400000
#define OFF_MEAN     4000768u    // 8 f32 sums
#define OFF_M        4001024u    // 32 f32 (8x4)
#define OFF_TPSUM    4001280u    // 512 f32
#define OFF_TPCNT    4003328u    // 8 f32
#define OFF_ASRC     4003584u    // 50000*4 f32        = 800000
#define OFF_ADST     4803584u    // 800000
#define OFF_AEDG     5603584u    // 850000*4 f32       = 13600000
#define OFF_HT       19203584u   // 50000*64 f32       = 12800000
#define OFF_XL       32003584u   // 50000*256 f32      = 51200000
#define OFF_OUT      83203584u   // 50000*256 f32      = 51200000
// total ~134.4 MB

// ---------------- input embeds ----------------
__global__ __launch_bounds__(256) void k_embed_task(const float* __restrict__ x,
    const float* __restrict__ W, const float* __restrict__ b, float* __restrict__ ht) {
  int lane = threadIdx.x & 63, wid = threadIdx.x >> 6;
  float breg[16];
  #pragma unroll
  for (int k = 0; k < 16; k++) breg[k] = W[k * 64 + lane];
  float bias = b[lane];
  int row0 = blockIdx.x * 64 + wid * 16;
  #pragma unroll 1
  for (int r = 0; r < 16; r++) {
    int row = row0 + r;
    if (row >= NT) return;
    const float* xr = x + (size_t)row * 16;
    float acc = bias;
    #pragma unroll
    for (int k = 0; k < 16; k++) acc += xr[k] * breg[k];
    ht[(size_t)row * 64 + lane] = acc;
  }
}

__global__ __launch_bounds__(256) void k_embed_proc(const float* __restrict__ x,
    const float* __restrict__ W, const float* __restrict__ b, float* __restrict__ hp) {
  int lane = threadIdx.x & 63, wid = threadIdx.x >> 6;
  float breg[8];
  #pragma unroll
  for (int k = 0; k < 8; k++) breg[k] = W[k * 64 + lane];
  float bias = b[lane];
  #pragma unroll 1
  for (int r = 0; r < 64; r++) {
    int row = wid * 64 + r;
    const float* xr = x + (size_t)row * 8;
    float acc = bias;
    #pragma unroll
    for (int k = 0; k < 8; k++) acc += xr[k] * breg[k];
    hp[(size_t)row * 64 + lane] = acc;
  }
}

// ---------------- edge_attr mean ----------------
__global__ __launch_bounds__(256) void k_edge_mean(const float* __restrict__ ea,
                                                   float* __restrict__ sums) {
  __shared__ float lds[256];
  int k = threadIdx.x & 7;
  int rlane = threadIdx.x >> 3;
  float s = 0.f;
  for (int row = blockIdx.x * 32 + rlane; row < NE; row += gridDim.x * 32)
    s += ea[(size_t)row * 8 + k];
  lds[threadIdx.x] = s;
  __syncthreads();
  for (int off = 128; off >= 8; off >>= 1) {
    if (threadIdx.x < off) lds[threadIdx.x] += lds[threadIdx.x + off];
    __syncthreads();
  }
  if (threadIdx.x < 8) atomicAdd(&sums[threadIdx.x], lds[threadIdx.x]);
}

// ---------------- CSR build ----------------
__global__ __launch_bounds__(256) void k_degree(const int* __restrict__ ei1, int* __restrict__ deg) {
  int e = blockIdx.x * 256 + threadIdx.x;
  if (e >= ET) return;
  int d = (e < NE) ? ei1[e] : (e - NE);
  atomicAdd(&deg[d], 1);
}

__global__ __launch_bounds__(1024) void k_scan(const int* __restrict__ deg, int* __restrict__ indptr) {
  __shared__ int wsum[16];
  __shared__ int carry;
  int tid = threadIdx.x, lane = tid & 63, wid = tid >> 6;
  if (tid == 0) carry = 0;
  __syncthreads();
  for (int base = 0; base < NT; base += 1024) {
    int i = base + tid;
    int v = (i < NT) ? deg[i] : 0;
    int x = v;
    #pragma unroll
    for (int off = 1; off < 64; off <<= 1) {
      int t = __shfl_up(x, off, 64);
      if (lane >= off) x += t;
    }
    if (lane == 63) wsum[wid] = x;
    __syncthreads();
    int c0 = carry;
    if (wid == 0 && lane < 16) {
      int w = wsum[lane];
      #pragma unroll
      for (int off = 1; off < 16; off <<= 1) {
        int t = __shfl_up(w, off, 64);
        if (lane >= off) w += t;
      }
      wsum[lane] = w;  // inclusive
    }
    __syncthreads();
    int woff = (wid == 0) ? 0 : wsum[wid - 1];
    int incl = x + woff;
    if (i < NT) indptr[i] = c0 + incl - v;  // exclusive
    __syncthreads();
    if (tid == 1023) carry = c0 + wsum[15];
    __syncthreads();
  }
  if (threadIdx.x == 0) indptr[NT] = carry;
}

__global__ __launch_bounds__(256) void k_copy(const int* __restrict__ a, int* __restrict__ b) {
  int i = blockIdx.x * 256 + threadIdx.x;
  if (i < NT) b[i] = a[i];
}

__global__ __launch_bounds__(256) void k_fill(const int* __restrict__ ei1,
                                              int* __restrict__ cursor, int* __restrict__ eids) {
  int e = blockIdx.x * 256 + threadIdx.x;
  if (e >= ET) return;
  int d = (e < NE) ? ei1[e] : (e - NE);
  int pos = atomicAdd(&cursor[d], 1);
  eids[pos] = e;
}

// ---------------- per-layer kernels ----------------
// xl = ht @ W   (50000x64 @ 64x256)
__global__ __launch_bounds__(256) void k_gemm_xl(const float* __restrict__ ht,
    const float* __restrict__ W, float* __restrict__ xl) {
  const int c = threadIdx.x;
  float breg[64];
  #pragma unroll
  for (int k = 0; k < 64; k++) breg[k] = W[k * 256 + c];
  int row0 = blockIdx.x * 32;
  #pragma unroll 1
  for (int r = 0; r < 32; r++) {
    int row = row0 + r;
    if (row >= NT) return;
    const float* a = ht + (size_t)row * 64;
    float acc = 0.f;
    #pragma unroll
    for (int k = 0; k < 64; k++) acc += a[k] * breg[k];
    xl[(size_t)row * HE + c] = acc;
  }
}

__global__ __launch_bounds__(256) void k_asrcdst(const float* __restrict__ xl,
    const float* __restrict__ as, const float* __restrict__ ad,
    float* __restrict__ a_src, float* __restrict__ a_dst) {
  int node = blockIdx.x * 4 + (threadIdx.x >> 6);
  int lane = threadIdx.x & 63;
  float vs[4], vd[4];
  #pragma unroll
  for (int h = 0; h < 4; h++) {
    float x = xl[(size_t)node * HE + h * 64 + lane];
    vs[h] = x * as[h * 64 + lane];
    vd[h] = x * ad[h * 64 + lane];
  }
  #pragma unroll
  for (int off = 32; off; off >>= 1) {
    #pragma unroll
    for (int h = 0; h < 4; h++) {
      vs[h] += __shfl_xor(vs[h], off, 64);
      vd[h] += __shfl_xor(vd[h], off, 64);
    }
  }
  if (lane == 0) {
    #pragma unroll
    for (int h = 0; h < 4; h++) {
      a_src[node * 4 + h] = vs[h];
      a_dst[node * 4 + h] = vd[h];
    }
  }
}

// M[k][h] = sum_d We[k, h*64+d] * att_edge[h, d]   (8x4)
__global__ void k_att_edge_mat(const float* __restrict__ We, const float* __restrict__ ae,
                               float* __restrict__ M) {
  int t = threadIdx.x;
  if (t >= 32) return;
  int k = t >> 2, h = t & 3;
  float s = 0.f;
  for (int d = 0; d < 64; d++) s += We[k * HE + h * 64 + d] * ae[h * 64 + d];
  M[k * 4 + h] = s;
}

__global__ __launch_bounds__(256) void k_a_edg(const float* __restrict__ ea,
    const float* __restrict__ msum, const float* __restrict__ M, float* __restrict__ aedg) {
  int e = blockIdx.x * 256 + threadIdx.x;
  if (e >= ET) return;
  float v[8];
  if (e < NE) {
    const float4* p = (const float4*)(ea + (size_t)e * 8);
    float4 x0 = p[0], x1 = p[1];
    v[0] = x0.x; v[1] = x0.y; v[2] = x0.z; v[3] = x0.w;
    v[4] = x1.x; v[5] = x1.y; v[6] = x1.z; v[7] = x1.w;
  } else {
    #pragma unroll
    for (int k = 0; k < 8; k++) v[k] = msum[k] * (1.f / NE);
  }
  float rr[4];
  #pragma unroll
  for (int h = 0; h < 4; h++) {
    float s = 0.f;
    #pragma unroll
    for (int k = 0; k < 8; k++) s += v[k] * M[k * 4 + h];
    rr[h] = s;
  }
  float4 r; r.x = rr[0]; r.y = rr[1]; r.z = rr[2]; r.w = rr[3];
  *(float4*)(aedg + (size_t)e * 4) = r;
}

// one wave per dst node, online softmax over in-edges, 4 heads, lane=dim
__global__ __launch_bounds__(256) void k_aggregate(
    const float* __restrict__ xl, const float* __restrict__ a_src,
    const float* __restrict__ a_dst, const float* __restrict__ a_edg,
    const int* __restrict__ indptr, const int* __restrict__ eids,
    const int* __restrict__ ei0, const float* __restrict__ gb,
    float* __restrict__ out) {
  int node = blockIdx.x * 4 + (threadIdx.x >> 6);
  int lane = threadIdx.x & 63;
  int beg = indptr[node], end = indptr[node + 1];
  float ad[4], m[4], s[4], acc[4];
  #pragma unroll
  for (int h = 0; h < 4; h++) {
    ad[h] = a_dst[node * 4 + h];
    m[h] = -1e30f; s[h] = 0.f; acc[h] = 0.f;
  }
  for (int i = beg; i < end; i++) {
    int e = eids[i];
    e = __builtin_amdgcn_readfirstlane(e);
    int src = (e < NE) ? ei0[e] : (e - NE);
    src = __builtin_amdgcn_readfirstlane(src);
    const float* xr = xl + (size_t)src * HE;
    const float* asr = a_src + (size_t)src * 4;
    const float* aer = a_edg + (size_t)e * 4;
    #pragma unroll
    for (int h = 0; h < 4; h++) {
      float al = asr[h] + ad[h] + aer[h];
      al = (al > 0.f) ? al : 0.2f * al;
      float mn = fmaxf(m[h], al);
      float sc = __expf(m[h] - mn);
      float w = __expf(al - mn);
      s[h] = s[h] * sc + w;
      acc[h] = acc[h] * sc + w * xr[h * 64 + lane];
      m[h] = mn;
    }
  }
  #pragma unroll
  for (int h = 0; h < 4; h++)
    out[(size_t)node * HE + h * 64 + lane] = acc[h] / (s[h] + 1e-16f) + gb[h * 64 + lane];
}

// upd = elu(agg @ W + pb); h = ht_in + upd; LN(h) -> ht_out     (50000x256 @ 256x64)
__global__ __launch_bounds__(256) void k_proj_ln(const float* __restrict__ agg,
    const float* __restrict__ W, const float* __restrict__ pb,
    const float* __restrict__ g, const float* __restrict__ b,
    const float* __restrict__ ht_in, float* __restrict__ ht_out) {
  int lane = threadIdx.x & 63, wid = threadIdx.x >> 6;
  int row0 = blockIdx.x * 16 + wid * 4;
  float acc[4] = {0.f, 0.f, 0.f, 0.f};
  #pragma unroll 1
  for (int kc = 0; kc < 4; kc++) {
    float breg[64];
    #pragma unroll
    for (int kk = 0; kk < 64; kk++) breg[kk] = W[(kc * 64 + kk) * 64 + lane];
    #pragma unroll
    for (int rr = 0; rr < 4; rr++) {
      const float* a = agg + (size_t)(row0 + rr) * HE + kc * 64;
      float s = acc[rr];
      #pragma unroll
      for (int kk = 0; kk < 64; kk++) s += a[kk] * breg[kk];
      acc[rr] = s;
    }
  }
  float pbv = pb[lane], gv = g[lane], bv = b[lane];
  #pragma unroll
  for (int rr = 0; rr < 4; rr++) {
    int row = row0 + rr;
    float u = acc[rr] + pbv;
    u = (u > 0.f) ? u : (__expf(u) - 1.f);
    float h = ht_in[(size_t)row * 64 + lane] + u;
    float ssum = h;
    #pragma unroll
    for (int off = 32; off; off >>= 1) ssum += __shfl_xor(ssum, off, 64);
    float mu = ssum * 0.015625f;
    float dv = h - mu;
    float vv = dv * dv;
    #pragma unroll
    for (int off = 32; off; off >>= 1) vv += __shfl_xor(vv, off, 64);
    float rstd = rsqrtf(vv * 0.015625f + 1e-5f);
    ht_out[(size_t)row * 64 + lane] = dv * rstd * gv + bv;
  }
}

// ---------------- heads ----------------
__global__ __launch_bounds__(256) void k_task_head(const float* __restrict__ ht,
    const float* __restrict__ W1, const float* __restrict__ b1,
    const float* __restrict__ W2, const float* __restrict__ b2, float* __restrict__ logits) {
  __shared__ float lh[8 * 64];
  int t = threadIdx.x;
  size_t base = (size_t)blockIdx.x * 8 * 64;
  lh[t] = ht[base + t];
  lh[t + 256] = ht[base + t + 256];
  __syncthreads();
  int i = t >> 5, j = t & 31;
  float s = b1[j];
  #pragma unroll 8
  for (int d = 0; d < 64; d++) s += lh[i * 64 + d] * W1[d * 32 + j];
  s = fmaxf(s, 0.f);
  float p = s * W2[j];
  #pragma unroll
  for (int off = 16; off; off >>= 1) p += __shfl_xor(p, off, 64);
  if (j == 0) logits[blockIdx.x * 8 + i] = p + b2[0];
}

__global__ __launch_bounds__(256) void k_pool_task(const float* __restrict__ ht,
    const int* __restrict__ tb, float* __restrict__ sums, float* __restrict__ cnt) {
  int lane = threadIdx.x & 63, sub = threadIdx.x >> 6;
  float acc[8], c[8];
  #pragma unroll
  for (int g = 0; g < 8; g++) { acc[g] = 0.f; c[g] = 0.f; }
  int lim = min(NT, (int)((blockIdx.x + 1) * 512));
  for (int n = blockIdx.x * 512 + sub; n < lim; n += 4) {
    int g = tb[n];
    float v = ht[(size_t)n * 64 + lane];
    #pragma unroll
    for (int gg = 0; gg < 8; gg++) {
      if (g == gg) { acc[gg] += v; c[gg] += 1.f; }
    }
  }
  #pragma unroll
  for (int g = 0; g < 8; g++) {
    if (__any(acc[g] != 0.f || c[g] != 0.f)) {
      atomicAdd(&sums[g * 64 + lane], acc[g]);
      if (lane == 0) atomicAdd(&cnt[g], c[g]);
    }
  }
}

__global__ __launch_bounds__(512) void k_value(const float* __restrict__ tpsum,
    const float* __restrict__ tpcnt, const float* __restrict__ hp,
    const int* __restrict__ pbatch, const float* __restrict__ vW1,
    const float* __restrict__ vb1, const float* __restrict__ vW2,
    const float* __restrict__ vb2, float* __restrict__ val_out) {
  __shared__ float ge[8 * 128];
  int t = threadIdx.x;
  int g = t >> 6, d = t & 63;
  float c = fmaxf(tpcnt[g], 1.f);
  ge[g * 128 + d] = tpsum[g * 64 + d] / c;
  float s = 0.f, cc = 0.f;
  for (int p = 0; p < 256; p++) {
    int bg = pbatch[p];
    if (bg == g) { s += hp[(size_t)p * 64 + d]; cc += 1.f; }
  }
  ge[g * 128 + 64 + d] = s / fmaxf(cc, 1.f);
  __syncthreads();
  float acc = vb1[d];
  #pragma unroll 8
  for (int k = 0; k < 128; k++) acc += ge[g * 128 + k] * vW1[k * 64 + d];
  acc = fmaxf(acc, 0.f);
  float p = acc * vW2[d];
  #pragma unroll
  for (int off = 32; off; off >>= 1) p += __shfl_xor(p, off, 64);
  if (d == 0) val_out[g] = p + vb2[0];
}

extern "C" void kernel_launch(void* const* d_in, const int* in_sizes, int n_in,
                              void* d_out, int out_size, void* d_ws, size_t ws_size,
                              hipStream_t stream) {
  (void)in_sizes; (void)n_in; (void)out_size; (void)ws_size;
  const float* x_task  = (const float*)d_in[0];
  const float* x_proc  = (const float*)d_in[1];
  const int*   eidx    = (const int*)d_in[2];
  const float* eattr   = (const float*)d_in[3];
  const int*   tbatch  = (const int*)d_in[4];
  const int*   pbatch  = (const int*)d_in[5];
  const float* W_task  = (const float*)d_in[6];
  const float* b_task  = (const float*)d_in[7];
  const float* W_proc  = (const float*)d_in[8];
  const float* b_proc  = (const float*)d_in[9];
  const float* gat_W   = (const float*)d_in[10];
  const float* gat_We  = (const float*)d_in[11];
  const float* att_src = (const float*)d_in[12];
  const float* att_dst = (const float*)d_in[13];
  const float* att_edge= (const float*)d_in[14];
  const float* gat_b   = (const float*)d_in[15];
  const float* proj_W  = (const float*)d_in[16];
  const float* proj_b  = (const float*)d_in[17];
  const float* ln_g    = (const float*)d_in[18];
  const float* ln_b    = (const float*)d_in[19];
  const float* pt_W1   = (const float*)d_in[20];
  const float* pt_b1   = (const float*)d_in[21];
  const float* pt_W2   = (const float*)d_in[22];
  const float* pt_b2   = (const float*)d_in[23];
  const float* v_W1    = (const float*)d_in[24];
  const float* v_b1    = (const float*)d_in[25];
  const float* v_W2    = (const float*)d_in[26];
  const float* v_b2    = (const float*)d_in[27];

  char* ws = (char*)d_ws;
  int*   deg    = (int*)(ws + OFF_DEG);
  int*   indptr = (int*)(ws + OFF_INDPTR);
  int*   cursor = (int*)(ws + OFF_CURSOR);
  int*   eids   = (int*)(ws + OFF_EIDS);
  float* msum   = (float*)(ws + OFF_MEAN);
  float* Mmat   = (float*)(ws + OFF_M);
  float* tpsum  = (float*)(ws + OFF_TPSUM);
  float* tpcnt  = (float*)(ws + OFF_TPCNT);
  float* a_src  = (float*)(ws + OFF_ASRC);
  float* a_dst  = (float*)(ws + OFF_ADST);
  float* a_edg  = (float*)(ws + OFF_AEDG);
  float* ht     = (float*)(ws + OFF_HT);
  float* xl     = (float*)(ws + OFF_XL);
  float* aggout = (float*)(ws + OFF_OUT);

  float* out_logits = (float*)d_out;
  float* out_value  = (float*)d_out + NT;
  float* out_ht     = (float*)d_out + NT + NG;
  float* out_hp     = (float*)d_out + NT + NG + (size_t)NT * EMBD;

  hipMemsetAsync(ws + OFF_DEG, 0, NT * 4, stream);
  hipMemsetAsync(ws + OFF_MEAN, 0, 2816, stream);  // msum + Mmat + tpsum + tpcnt

  k_embed_task<<<782, 256, 0, stream>>>(x_task, W_task, b_task, ht);
  k_embed_proc<<<1, 256, 0, stream>>>(x_proc, W_proc, b_proc, out_hp);
  k_edge_mean<<<256, 256, 0, stream>>>(eattr, msum);
  k_degree<<<(ET + 255) / 256, 256, 0, stream>>>(eidx + NE, deg);
  k_scan<<<1, 1024, 0, stream>>>(deg, indptr);
  k_copy<<<(NT + 255) / 256, 256, 0, stream>>>(indptr, cursor);
  k_fill<<<(ET + 255) / 256, 256, 0, stream>>>(eidx + NE, cursor, eids);

  for (int l = 0; l < 3; l++) {
    k_gemm_xl<<<(NT + 31) / 32, 256, 0, stream>>>(ht, gat_W + (size_t)l * EMBD * HE, xl);
    k_asrcdst<<<NT / 4, 256, 0, stream>>>(xl, att_src + l * NHEADS * EMBD,
                                          att_dst + l * NHEADS * EMBD, a_src, a_dst);
    k_att_edge_mat<<<1, 32, 0, stream>>>(gat_We + (size_t)l * 8 * HE,
                                         att_edge + l * NHEADS * EMBD, Mmat);
    k_a_edg<<<(ET + 255) / 256, 256, 0, stream>>>(eattr, msum, Mmat, a_edg);
    k_aggregate<<<NT / 4, 256, 0, stream>>>(xl, a_src, a_dst, a_edg, indptr, eids,
                                            eidx, gat_b + l * HE, aggout);
    float* htout = (l == 2) ? out_ht : ht;
    k_proj_ln<<<NT / 16, 256, 0, stream>>>(aggout, proj_W + (size_t)l * HE * EMBD,
                                           proj_b + l * EMBD, ln_g + l * EMBD,
                                           ln_b + l * EMBD, ht, htout);
  }

  k_task_head<<<NT / 8, 256, 0, stream>>>(out_ht, pt_W1, pt_b1, pt_W2, pt_b2, out_logits);
  k_pool_task<<<(NT + 511) / 512, 256, 0, stream>>>(out_ht, tbatch, tpsum, tpcnt);
  k_value<<<1, 512, 0, stream>>>(tpsum, tpcnt, out_hp, pbatch, v_W1, v_b1, v_W2, v_b2, out_value);
}

// Round 2
// 1337.606 us; speedup vs baseline: 1.2269x; 1.2269x over previous
//
#include <hip/hip_runtime.h>
#include <hip/hip_bf16.h>
#include <math.h>

#define NT 50000
#define NP 256
#define NE 800000
#define ET 850000   // NE + NT self loops
#define EMBD 64
#define NHEADS 4
#define HE 256      // NHEADS*EMBD
#define NG 8

// ---- workspace layout (bytes), all 256-aligned ----
#define OFF_DEG      0u           // 50000 i32
#define OFF_INDPTR   200192u      // 50001 i32
#define OFF_CURSOR   400384u      // 50000 i32
#define OFF_EIDS     600576u      // 850000 i32 (CSR-ordered edge id)
#define OFF_SRCS     4000768u     // 850000 i32 (CSR-ordered src node)
#define OFF_MEAN     7400960u     // 8 f32
#define OFF_M        7401216u     // 32 f32
#define OFF_TPSUM    7401472u     // 512 f32
#define OFF_TPCNT    7403520u     // 8 f32
#define OFF_ASRC     7403776u     // 50000*4 f32
#define OFF_ADST     8203776u     // 50000*4 f32
#define OFF_SINV     9003776u     // 50000*4 f32
#define OFF_AEDG     9803776u     // 850000*4 f32
#define OFF_COEFF    23403776u    // 850000*4 f32 (CSR-ordered exp weights)
#define OFF_HT       37003776u    // 50000*64 f32
#define OFF_XL       49803776u    // 50000*256 bf16
#define OFF_AGG      75403776u    // 50000*256 bf16
// total ~101 MB

__device__ __forceinline__ float bf2f(unsigned short u) {
  union { unsigned int i; float f; } v; v.i = ((unsigned int)u) << 16; return v.f;
}

// ---------------- input embeds ----------------
__global__ __launch_bounds__(256) void k_embed_task(const float* __restrict__ x,
    const float* __restrict__ W, const float* __restrict__ b, float* __restrict__ ht) {
  int lane = threadIdx.x & 63, wid = threadIdx.x >> 6;
  float breg[16];
  #pragma unroll
  for (int k = 0; k < 16; k++) breg[k] = W[k * 64 + lane];
  float bias = b[lane];
  int row0 = blockIdx.x * 64 + wid * 16;
  #pragma unroll 1
  for (int r = 0; r < 16; r++) {
    int row = row0 + r;
    if (row >= NT) return;
    const float4* xr = (const float4*)(x + (size_t)row * 16);
    float acc = bias;
    #pragma unroll
    for (int q = 0; q < 4; q++) {
      float4 v = xr[q];
      acc += v.x * breg[q*4+0] + v.y * breg[q*4+1] + v.z * breg[q*4+2] + v.w * breg[q*4+3];
    }
    ht[(size_t)row * 64 + lane] = acc;
  }
}

__global__ __launch_bounds__(256) void k_embed_proc(const float* __restrict__ x,
    const float* __restrict__ W, const float* __restrict__ b, float* __restrict__ hp) {
  int lane = threadIdx.x & 63, wid = threadIdx.x >> 6;
  float breg[8];
  #pragma unroll
  for (int k = 0; k < 8; k++) breg[k] = W[k * 64 + lane];
  float bias = b[lane];
  #pragma unroll 1
  for (int r = 0; r < 64; r++) {
    int row = wid * 64 + r;
    const float* xr = x + (size_t)row * 8;
    float acc = bias;
    #pragma unroll
    for (int k = 0; k < 8; k++) acc += xr[k] * breg[k];
    hp[(size_t)row * 64 + lane] = acc;
  }
}

// ---------------- edge_attr mean ----------------
__global__ __launch_bounds__(256) void k_edge_mean(const float* __restrict__ ea,
                                                   float* __restrict__ sums) {
  __shared__ float lds[256];
  int k = threadIdx.x & 7;
  int rlane = threadIdx.x >> 3;
  float s = 0.f;
  for (int row = blockIdx.x * 32 + rlane; row < NE; row += gridDim.x * 32)
    s += ea[(size_t)row * 8 + k];
  lds[threadIdx.x] = s;
  __syncthreads();
  for (int off = 128; off >= 8; off >>= 1) {
    if (threadIdx.x < off) lds[threadIdx.x] += lds[threadIdx.x + off];
    __syncthreads();
  }
  if (threadIdx.x < 8) atomicAdd(&sums[threadIdx.x], lds[threadIdx.x]);
}

// ---------------- CSR build ----------------
__global__ __launch_bounds__(256) void k_degree(const int* __restrict__ ei1, int* __restrict__ deg) {
  int e = blockIdx.x * 256 + threadIdx.x;
  if (e >= ET) return;
  int d = (e < NE) ? ei1[e] : (e - NE);
  atomicAdd(&deg[d], 1);
}

__global__ __launch_bounds__(1024) void k_scan(const int* __restrict__ deg, int* __restrict__ indptr) {
  __shared__ int wsum[16];
  __shared__ int carry;
  int tid = threadIdx.x, lane = tid & 63, wid = tid >> 6;
  if (tid == 0) carry = 0;
  __syncthreads();
  for (int base = 0; base < NT; base += 1024) {
    int i = base + tid;
    int v = (i < NT) ? deg[i] : 0;
    int x = v;
    #pragma unroll
    for (int off = 1; off < 64; off <<= 1) {
      int t = __shfl_up(x, off, 64);
      if (lane >= off) x += t;
    }
    if (lane == 63) wsum[wid] = x;
    __syncthreads();
    int c0 = carry;
    if (wid == 0 && lane < 16) {
      int w = wsum[lane];
      #pragma unroll
      for (int off = 1; off < 16; off <<= 1) {
        int t = __shfl_up(w, off, 64);
        if (lane >= off) w += t;
      }
      wsum[lane] = w;  // inclusive
    }
    __syncthreads();
    int woff = (wid == 0) ? 0 : wsum[wid - 1];
    int incl = x + woff;
    if (i < NT) indptr[i] = c0 + incl - v;  // exclusive
    __syncthreads();
    if (tid == 1023) carry = c0 + wsum[15];
    __syncthreads();
  }
  if (threadIdx.x == 0) indptr[NT] = carry;
}

__global__ __launch_bounds__(256) void k_copy(const int* __restrict__ a, int* __restrict__ b) {
  int i = blockIdx.x * 256 + threadIdx.x;
  if (i < NT) b[i] = a[i];
}

__global__ __launch_bounds__(256) void k_fill(const int* __restrict__ ei0,
                                              const int* __restrict__ ei1,
                                              int* __restrict__ cursor,
                                              int* __restrict__ eids,
                                              int* __restrict__ srcs) {
  int e = blockIdx.x * 256 + threadIdx.x;
  if (e >= ET) return;
  int d, s;
  if (e < NE) { d = ei1[e]; s = ei0[e]; } else { d = e - NE; s = e - NE; }
  int pos = atomicAdd(&cursor[d], 1);
  eids[pos] = e;
  srcs[pos] = s;
}

// ---------------- per-layer kernels ----------------
// xl = ht @ W (bf16 out) + fused a_src/a_dst per-head reductions
__global__ __launch_bounds__(256) void k_gemm_xl(const float* __restrict__ ht,
    const float* __restrict__ W, const float* __restrict__ as, const float* __restrict__ ad,
    __hip_bfloat16* __restrict__ xl, float* __restrict__ a_src, float* __restrict__ a_dst) {
  int lane = threadIdx.x & 63, wid = threadIdx.x >> 6;
  const int c = threadIdx.x;
  float breg[64];
  #pragma unroll
  for (int k = 0; k < 64; k++) breg[k] = W[k * 256 + c];
  float asv = as[c], adv = ad[c];
  int row0 = blockIdx.x * 32;
  #pragma unroll 1
  for (int r = 0; r < 32; r++) {
    int row = row0 + r;
    if (row >= NT) return;
    const float4* a4 = (const float4*)(ht + (size_t)row * 64);
    float acc = 0.f;
    #pragma unroll
    for (int q = 0; q < 16; q++) {
      float4 v = a4[q];
      acc += v.x * breg[q*4+0] + v.y * breg[q*4+1] + v.z * breg[q*4+2] + v.w * breg[q*4+3];
    }
    xl[(size_t)row * HE + c] = __float2bfloat16(acc);
    float vs = acc * asv, vd = acc * adv;
    #pragma unroll
    for (int off = 32; off; off >>= 1) {
      vs += __shfl_xor(vs, off, 64);
      vd += __shfl_xor(vd, off, 64);
    }
    if (lane == 0) {
      a_src[row * 4 + wid] = vs;
      a_dst[row * 4 + wid] = vd;
    }
  }
}

// M[k][h] = sum_d We[k, h*64+d] * att_edge[h, d]   (8x4)
__global__ void k_att_edge_mat(const float* __restrict__ We, const float* __restrict__ ae,
                               float* __restrict__ M) {
  int t = threadIdx.x;
  if (t >= 32) return;
  int k = t >> 2, h = t & 3;
  float s = 0.f;
  for (int d = 0; d < 64; d++) s += We[k * HE + h * 64 + d] * ae[h * 64 + d];
  M[k * 4 + h] = s;
}

__global__ __launch_bounds__(256) void k_a_edg(const float* __restrict__ ea,
    const float* __restrict__ msum, const float* __restrict__ M, float* __restrict__ aedg) {
  int e = blockIdx.x * 256 + threadIdx.x;
  if (e >= ET) return;
  float v[8];
  if (e < NE) {
    const float4* p = (const float4*)(ea + (size_t)e * 8);
    float4 x0 = p[0], x1 = p[1];
    v[0] = x0.x; v[1] = x0.y; v[2] = x0.z; v[3] = x0.w;
    v[4] = x1.x; v[5] = x1.y; v[6] = x1.z; v[7] = x1.w;
  } else {
    #pragma unroll
    for (int k = 0; k < 8; k++) v[k] = msum[k] * (1.f / NE);
  }
  float rr[4];
  #pragma unroll
  for (int h = 0; h < 4; h++) {
    float s = 0.f;
    #pragma unroll
    for (int k = 0; k < 8; k++) s += v[k] * M[k * 4 + h];
    rr[h] = s;
  }
  float4 r; r.x = rr[0]; r.y = rr[1]; r.z = rr[2]; r.w = rr[3];
  *(float4*)(aedg + (size_t)e * 4) = r;
}

// wave per node, lanes parallel over edges: 2-pass softmax, writes exp weights
// in CSR order + per-node 1/denominator
__global__ __launch_bounds__(256) void k_softmax(
    const float* __restrict__ a_src, const float* __restrict__ a_dst,
    const float* __restrict__ a_edg, const int* __restrict__ indptr,
    const int* __restrict__ eids, const int* __restrict__ srcs,
    float* __restrict__ coeff, float* __restrict__ sinv) {
  int node = blockIdx.x * 4 + (threadIdx.x >> 6);
  int lane = threadIdx.x & 63;
  int beg = indptr[node], end = indptr[node + 1];
  float4 ad = *(const float4*)(a_dst + (size_t)node * 4);
  float m[4] = {-1e30f, -1e30f, -1e30f, -1e30f};
  for (int i = beg + lane; i < end; i += 64) {
    int e = eids[i], s = srcs[i];
    float4 asr = *(const float4*)(a_src + (size_t)s * 4);
    float4 aer = *(const float4*)(a_edg + (size_t)e * 4);
    float al[4] = {asr.x + ad.x + aer.x, asr.y + ad.y + aer.y,
                   asr.z + ad.z + aer.z, asr.w + ad.w + aer.w};
    #pragma unroll
    for (int h = 0; h < 4; h++) {
      float a = al[h];
      a = (a > 0.f) ? a : 0.2f * a;
      m[h] = fmaxf(m[h], a);
    }
  }
  #pragma unroll
  for (int off = 32; off; off >>= 1) {
    #pragma unroll
    for (int h = 0; h < 4; h++) m[h] = fmaxf(m[h], __shfl_xor(m[h], off, 64));
  }
  float sm[4] = {0.f, 0.f, 0.f, 0.f};
  for (int i = beg + lane; i < end; i += 64) {
    int e = eids[i], s = srcs[i];
    float4 asr = *(const float4*)(a_src + (size_t)s * 4);
    float4 aer = *(const float4*)(a_edg + (size_t)e * 4);
    float al[4] = {asr.x + ad.x + aer.x, asr.y + ad.y + aer.y,
                   asr.z + ad.z + aer.z, asr.w + ad.w + aer.w};
    float ex[4];
    #pragma unroll
    for (int h = 0; h < 4; h++) {
      float a = al[h];
      a = (a > 0.f) ? a : 0.2f * a;
      ex[h] = __expf(a - m[h]);
      sm[h] += ex[h];
    }
    float4 c; c.x = ex[0]; c.y = ex[1]; c.z = ex[2]; c.w = ex[3];
    *(float4*)(coeff + (size_t)i * 4) = c;
  }
  #pragma unroll
  for (int off = 32; off; off >>= 1) {
    #pragma unroll
    for (int h = 0; h < 4; h++) sm[h] += __shfl_xor(sm[h], off, 64);
  }
  if (lane == 0) {
    #pragma unroll
    for (int h = 0; h < 4; h++) sinv[node * 4 + h] = 1.f / (sm[h] + 1e-16f);
  }
}

// wave per node, lane=dim: acc[h] += coeff*xl[src], scale by 1/s, +bias, bf16 out
__global__ __launch_bounds__(256) void k_aggregate(
    const __hip_bfloat16* __restrict__ xl, const float* __restrict__ coeff,
    const float* __restrict__ sinv, const int* __restrict__ indptr,
    const int* __restrict__ srcs, const float* __restrict__ gb,
    __hip_bfloat16* __restrict__ agg) {
  int node = blockIdx.x * 4 + (threadIdx.x >> 6);
  int lane = threadIdx.x & 63;
  int beg = indptr[node], end = indptr[node + 1];
  float acc[4] = {0.f, 0.f, 0.f, 0.f};
  for (int i = beg; i < end; i++) {
    int src = __builtin_amdgcn_readfirstlane(srcs[i]);
    float4 cf = *(const float4*)(coeff + (size_t)i * 4);
    const __hip_bfloat16* xr = xl + (size_t)src * HE;
    #pragma unroll
    for (int h = 0; h < 4; h++)
      acc[h] += ((h == 0) ? cf.x : (h == 1) ? cf.y : (h == 2) ? cf.z : cf.w) *
                __bfloat162float(xr[h * 64 + lane]);
  }
  float4 inv = *(const float4*)(sinv + (size_t)node * 4);
  float iv[4] = {inv.x, inv.y, inv.z, inv.w};
  #pragma unroll
  for (int h = 0; h < 4; h++)
    agg[(size_t)node * HE + h * 64 + lane] =
        __float2bfloat16(acc[h] * iv[h] + gb[h * 64 + lane]);
}

// upd = elu(agg @ W + pb); h = ht_in + upd; LN(h) -> ht_out     (50000x256 @ 256x64)
__global__ __launch_bounds__(256) void k_proj_ln(const __hip_bfloat16* __restrict__ agg,
    const float* __restrict__ W, const float* __restrict__ pb,
    const float* __restrict__ g, const float* __restrict__ b,
    const float* __restrict__ ht_in, float* __restrict__ ht_out) {
  int lane = threadIdx.x & 63, wid = threadIdx.x >> 6;
  int row0 = blockIdx.x * 16 + wid * 4;
  float acc[4] = {0.f, 0.f, 0.f, 0.f};
  #pragma unroll 1
  for (int kc = 0; kc < 4; kc++) {
    float breg[64];
    #pragma unroll
    for (int kk = 0; kk < 64; kk++) breg[kk] = W[(kc * 64 + kk) * 64 + lane];
    #pragma unroll
    for (int rr = 0; rr < 4; rr++) {
      const uint2* a = (const uint2*)(agg + (size_t)(row0 + rr) * HE + kc * 64);
      float s = acc[rr];
      #pragma unroll
      for (int q = 0; q < 16; q++) {
        uint2 u = a[q];
        s += bf2f((unsigned short)(u.x & 0xffffu)) * breg[q*4+0];
        s += bf2f((unsigned short)(u.x >> 16))     * breg[q*4+1];
        s += bf2f((unsigned short)(u.y & 0xffffu)) * breg[q*4+2];
        s += bf2f((unsigned short)(u.y >> 16))     * breg[q*4+3];
      }
      acc[rr] = s;
    }
  }
  float pbv = pb[lane], gv = g[lane], bv = b[lane];
  #pragma unroll
  for (int rr = 0; rr < 4; rr++) {
    int row = row0 + rr;
    float u = acc[rr] + pbv;
    u = (u > 0.f) ? u : (__expf(u) - 1.f);
    float h = ht_in[(size_t)row * 64 + lane] + u;
    float ssum = h;
    #pragma unroll
    for (int off = 32; off; off >>= 1) ssum += __shfl_xor(ssum, off, 64);
    float mu = ssum * 0.015625f;
    float dv = h - mu;
    float vv = dv * dv;
    #pragma unroll
    for (int off = 32; off; off >>= 1) vv += __shfl_xor(vv, off, 64);
    float rstd = rsqrtf(vv * 0.015625f + 1e-5f);
    ht_out[(size_t)row * 64 + lane] = dv * rstd * gv + bv;
  }
}

// ---------------- heads ----------------
__global__ __launch_bounds__(256) void k_task_head(const float* __restrict__ ht,
    const float* __restrict__ W1, const float* __restrict__ b1,
    const float* __restrict__ W2, const float* __restrict__ b2, float* __restrict__ logits) {
  __shared__ float lh[8 * 64];
  int t = threadIdx.x;
  size_t base = (size_t)blockIdx.x * 8 * 64;
  lh[t] = ht[base + t];
  lh[t + 256] = ht[base + t + 256];
  __syncthreads();
  int i = t >> 5, j = t & 31;
  float s = b1[j];
  #pragma unroll 8
  for (int d = 0; d < 64; d++) s += lh[i * 64 + d] * W1[d * 32 + j];
  s = fmaxf(s, 0.f);
  float p = s * W2[j];
  #pragma unroll
  for (int off = 16; off; off >>= 1) p += __shfl_xor(p, off, 64);
  if (j == 0) logits[blockIdx.x * 8 + i] = p + b2[0];
}

__global__ __launch_bounds__(256) void k_pool_task(const float* __restrict__ ht,
    const int* __restrict__ tb, float* __restrict__ sums, float* __restrict__ cnt) {
  int lane = threadIdx.x & 63, sub = threadIdx.x >> 6;
  float acc[8], c[8];
  #pragma unroll
  for (int g = 0; g < 8; g++) { acc[g] = 0.f; c[g] = 0.f; }
  int lim = min(NT, (int)((blockIdx.x + 1) * 512));
  for (int n = blockIdx.x * 512 + sub; n < lim; n += 4) {
    int g = tb[n];
    float v = ht[(size_t)n * 64 + lane];
    #pragma unroll
    for (int gg = 0; gg < 8; gg++) {
      if (g == gg) { acc[gg] += v; c[gg] += 1.f; }
    }
  }
  #pragma unroll
  for (int g = 0; g < 8; g++) {
    if (__any(acc[g] != 0.f || c[g] != 0.f)) {
      atomicAdd(&sums[g * 64 + lane], acc[g]);
      if (lane == 0) atomicAdd(&cnt[g], c[g]);
    }
  }
}

__global__ __launch_bounds__(512) void k_value(const float* __restrict__ tpsum,
    const float* __restrict__ tpcnt, const float* __restrict__ hp,
    const int* __restrict__ pbatch, const float* __restrict__ vW1,
    const float* __restrict__ vb1, const float* __restrict__ vW2,
    const float* __restrict__ vb2, float* __restrict__ val_out) {
  __shared__ float ge[8 * 128];
  int t = threadIdx.x;
  int g = t >> 6, d = t & 63;
  float c = fmaxf(tpcnt[g], 1.f);
  ge[g * 128 + d] = tpsum[g * 64 + d] / c;
  float s = 0.f, cc = 0.f;
  for (int p = 0; p < 256; p++) {
    int bg = pbatch[p];
    if (bg == g) { s += hp[(size_t)p * 64 + d]; cc += 1.f; }
  }
  ge[g * 128 + 64 + d] = s / fmaxf(cc, 1.f);
  __syncthreads();
  float acc = vb1[d];
  #pragma unroll 8
  for (int k = 0; k < 128; k++) acc += ge[g * 128 + k] * vW1[k * 64 + d];
  acc = fmaxf(acc, 0.f);
  float p = acc * vW2[d];
  #pragma unroll
  for (int off = 32; off; off >>= 1) p += __shfl_xor(p, off, 64);
  if (d == 0) val_out[g] = p + vb2[0];
}

extern "C" void kernel_launch(void* const* d_in, const int* in_sizes, int n_in,
                              void* d_out, int out_size, void* d_ws, size_t ws_size,
                              hipStream_t stream) {
  (void)in_sizes; (void)n_in; (void)out_size; (void)ws_size;
  const float* x_task  = (const float*)d_in[0];
  const float* x_proc  = (const float*)d_in[1];
  const int*   eidx    = (const int*)d_in[2];
  const float* eattr   = (const float*)d_in[3];
  const int*   tbatch  = (const int*)d_in[4];
  const int*   pbatch  = (const int*)d_in[5];
  const float* W_task  = (const float*)d_in[6];
  const float* b_task  = (const float*)d_in[7];
  const float* W_proc  = (const float*)d_in[8];
  const float* b_proc  = (const float*)d_in[9];
  const float* gat_W   = (const float*)d_in[10];
  const float* gat_We  = (const float*)d_in[11];
  const float* att_src = (const float*)d_in[12];
  const float* att_dst = (const float*)d_in[13];
  const float* att_edge= (const float*)d_in[14];
  const float* gat_b   = (const float*)d_in[15];
  const float* proj_W  = (const float*)d_in[16];
  const float* proj_b  = (const float*)d_in[17];
  const float* ln_g    = (const float*)d_in[18];
  const float* ln_b    = (const float*)d_in[19];
  const float* pt_W1   = (const float*)d_in[20];
  const float* pt_b1   = (const float*)d_in[21];
  const float* pt_W2   = (const float*)d_in[22];
  const float* pt_b2   = (const float*)d_in[23];
  const float* v_W1    = (const float*)d_in[24];
  const float* v_b1    = (const float*)d_in[25];
  const float* v_W2    = (const float*)d_in[26];
  const float* v_b2    = (const float*)d_in[27];

  char* ws = (char*)d_ws;
  int*   deg    = (int*)(ws + OFF_DEG);
  int*   indptr = (int*)(ws + OFF_INDPTR);
  int*   cursor = (int*)(ws + OFF_CURSOR);
  int*   eids   = (int*)(ws + OFF_EIDS);
  int*   srcs   = (int*)(ws + OFF_SRCS);
  float* msum   = (float*)(ws + OFF_MEAN);
  float* Mmat   = (float*)(ws + OFF_M);
  float* tpsum  = (float*)(ws + OFF_TPSUM);
  float* tpcnt  = (float*)(ws + OFF_TPCNT);
  float* a_src  = (float*)(ws + OFF_ASRC);
  float* a_dst  = (float*)(ws + OFF_ADST);
  float* sinv   = (float*)(ws + OFF_SINV);
  float* a_edg  = (float*)(ws + OFF_AEDG);
  float* coeff  = (float*)(ws + OFF_COEFF);
  float* ht     = (float*)(ws + OFF_HT);
  __hip_bfloat16* xl  = (__hip_bfloat16*)(ws + OFF_XL);
  __hip_bfloat16* agg = (__hip_bfloat16*)(ws + OFF_AGG);

  float* out_logits = (float*)d_out;
  float* out_value  = (float*)d_out + NT;
  float* out_ht     = (float*)d_out + NT + NG;
  float* out_hp     = (float*)d_out + NT + NG + (size_t)NT * EMBD;

  hipMemsetAsync(ws + OFF_DEG, 0, NT * 4, stream);
  hipMemsetAsync(ws + OFF_MEAN, 0, 2592, stream);  // msum + Mmat + tpsum + tpcnt

  k_embed_task<<<782, 256, 0, stream>>>(x_task, W_task, b_task, ht);
  k_embed_proc<<<1, 256, 0, stream>>>(x_proc, W_proc, b_proc, out_hp);
  k_edge_mean<<<256, 256, 0, stream>>>(eattr, msum);
  k_degree<<<(ET + 255) / 256, 256, 0, stream>>>(eidx + NE, deg);
  k_scan<<<1, 1024, 0, stream>>>(deg, indptr);
  k_copy<<<(NT + 255) / 256, 256, 0, stream>>>(indptr, cursor);
  k_fill<<<(ET + 255) / 256, 256, 0, stream>>>(eidx, eidx + NE, cursor, eids, srcs);

  for (int l = 0; l < 3; l++) {
    k_gemm_xl<<<(NT + 31) / 32, 256, 0, stream>>>(ht, gat_W + (size_t)l * EMBD * HE,
                                                  att_src + l * NHEADS * EMBD,
                                                  att_dst + l * NHEADS * EMBD,
                                                  xl, a_src, a_dst);
    k_att_edge_mat<<<1, 32, 0, stream>>>(gat_We + (size_t)l * 8 * HE,
                                         att_edge + l * NHEADS * EMBD, Mmat);
    k_a_edg<<<(ET + 255) / 256, 256, 0, stream>>>(eattr, msum, Mmat, a_edg);
    k_softmax<<<NT / 4, 256, 0, stream>>>(a_src, a_dst, a_edg, indptr, eids, srcs,
                                          coeff, sinv);
    k_aggregate<<<NT / 4, 256, 0, stream>>>(xl, coeff, sinv, indptr, srcs,
                                            gat_b + l * HE, agg);
    float* htout = (l == 2) ? out_ht : ht;
    k_proj_ln<<<NT / 16, 256, 0, stream>>>(agg, proj_W + (size_t)l * HE * EMBD,
                                           proj_b + l * EMBD, ln_g + l * EMBD,
                                           ln_b + l * EMBD, ht, htout);
  }

  k_task_head<<<NT / 8, 256, 0, stream>>>(out_ht, pt_W1, pt_b1, pt_W2, pt_b2, out_logits);
  k_pool_task<<<(NT + 511) / 512, 256, 0, stream>>>(out_ht, tbatch, tpsum, tpcnt);
  k_value<<<1, 512, 0, stream>>>(tpsum, tpcnt, out_hp, pbatch, v_W1, v_b1, v_W2, v_b2, out_value);
}

// Round 3
// 919.116 us; speedup vs baseline: 1.7855x; 1.4553x over previous
//
#include <hip/hip_runtime.h>
#include <hip/hip_bf16.h>
#include <math.h>

#define NT 50000
#define NTP 50048   // padded rows (782*64)
#define NP 256
#define NE 800000
#define ET 850000   // NE + NT self loops
#define EMBD 64
#define NHEADS 4
#define HE 256      // NHEADS*EMBD
#define NG 8

typedef __attribute__((ext_vector_type(8))) short bf16x8;
typedef __attribute__((ext_vector_type(4))) float f32x4;

// ---- workspace layout (bytes), all 256-aligned ----
#define OFF_DEG      0u
#define OFF_INDPTR   200192u
#define OFF_CURSOR   400384u
#define OFF_EIDS     600576u
#define OFF_SRCS     4000768u
#define OFF_MEAN     7400960u
#define OFF_M        7401216u
#define OFF_TPSUM    7401472u
#define OFF_TPCNT    7403520u
#define OFF_ASRC     7403776u     // 50048*4 f32
#define OFF_ADST     8204544u
#define OFF_SINV     9005312u
#define OFF_AEDG     9805568u     // 850000*4 f32
#define OFF_COEFF    23405568u    // 850000*4 f32
#define OFF_HT       37005568u    // 50048*64 f32
#define OFF_HTB      49817856u    // 50048*64 bf16
#define OFF_XL       56224000u    // 50000*256 bf16
#define OFF_AGG      81824000u    // 50048*256 bf16
#define OFF_WXF      107448576u   // 3*16384 bf16 (xl B-frags)
#define OFF_WPF      107546880u   // 3*16384 bf16 (proj B-frags)
// total ~107.7 MB

__device__ __forceinline__ float bf2f(unsigned short u) {
  union { unsigned int i; float f; } v; v.i = ((unsigned int)u) << 16; return v.f;
}

// ---------------- input embeds ----------------
__global__ __launch_bounds__(256) void k_embed_task(const float* __restrict__ x,
    const float* __restrict__ W, const float* __restrict__ b,
    float* __restrict__ ht, __hip_bfloat16* __restrict__ htb) {
  int lane = threadIdx.x & 63, wid = threadIdx.x >> 6;
  float breg[16];
  #pragma unroll
  for (int k = 0; k < 16; k++) breg[k] = W[k * 64 + lane];
  float bias = b[lane];
  int row0 = blockIdx.x * 64 + wid * 16;
  #pragma unroll 1
  for (int r = 0; r < 16; r++) {
    int row = row0 + r;
    if (row >= NT) return;
    const float4* xr = (const float4*)(x + (size_t)row * 16);
    float acc = bias;
    #pragma unroll
    for (int q = 0; q < 4; q++) {
      float4 v = xr[q];
      acc += v.x * breg[q*4+0] + v.y * breg[q*4+1] + v.z * breg[q*4+2] + v.w * breg[q*4+3];
    }
    ht[(size_t)row * 64 + lane] = acc;
    htb[(size_t)row * 64 + lane] = __float2bfloat16(acc);
  }
}

__global__ __launch_bounds__(256) void k_embed_proc(const float* __restrict__ x,
    const float* __restrict__ W, const float* __restrict__ b, float* __restrict__ hp) {
  int lane = threadIdx.x & 63, wid = threadIdx.x >> 6;
  float breg[8];
  #pragma unroll
  for (int k = 0; k < 8; k++) breg[k] = W[k * 64 + lane];
  float bias = b[lane];
  #pragma unroll 1
  for (int r = 0; r < 64; r++) {
    int row = wid * 64 + r;
    const float* xr = x + (size_t)row * 8;
    float acc = bias;
    #pragma unroll
    for (int k = 0; k < 8; k++) acc += xr[k] * breg[k];
    hp[(size_t)row * 64 + lane] = acc;
  }
}

// ---------------- edge_attr mean ----------------
__global__ __launch_bounds__(256) void k_edge_mean(const float* __restrict__ ea,
                                                   float* __restrict__ sums) {
  __shared__ float lds[256];
  int k = threadIdx.x & 7;
  int rlane = threadIdx.x >> 3;
  float s = 0.f;
  for (int row = blockIdx.x * 32 + rlane; row < NE; row += gridDim.x * 32)
    s += ea[(size_t)row * 8 + k];
  lds[threadIdx.x] = s;
  __syncthreads();
  for (int off = 128; off >= 8; off >>= 1) {
    if (threadIdx.x < off) lds[threadIdx.x] += lds[threadIdx.x + off];
    __syncthreads();
  }
  if (threadIdx.x < 8) atomicAdd(&sums[threadIdx.x], lds[threadIdx.x]);
}

// ---------------- CSR build ----------------
__global__ __launch_bounds__(256) void k_degree(const int* __restrict__ ei1, int* __restrict__ deg) {
  int e = blockIdx.x * 256 + threadIdx.x;
  if (e >= ET) return;
  int d = (e < NE) ? ei1[e] : (e - NE);
  atomicAdd(&deg[d], 1);
}

__global__ __launch_bounds__(1024) void k_scan(const int* __restrict__ deg, int* __restrict__ indptr) {
  __shared__ int wsum[16];
  __shared__ int carry;
  int tid = threadIdx.x, lane = tid & 63, wid = tid >> 6;
  if (tid == 0) carry = 0;
  __syncthreads();
  for (int base = 0; base < NT; base += 1024) {
    int i = base + tid;
    int v = (i < NT) ? deg[i] : 0;
    int x = v;
    #pragma unroll
    for (int off = 1; off < 64; off <<= 1) {
      int t = __shfl_up(x, off, 64);
      if (lane >= off) x += t;
    }
    if (lane == 63) wsum[wid] = x;
    __syncthreads();
    int c0 = carry;
    if (wid == 0 && lane < 16) {
      int w = wsum[lane];
      #pragma unroll
      for (int off = 1; off < 16; off <<= 1) {
        int t = __shfl_up(w, off, 64);
        if (lane >= off) w += t;
      }
      wsum[lane] = w;  // inclusive
    }
    __syncthreads();
    int woff = (wid == 0) ? 0 : wsum[wid - 1];
    int incl = x + woff;
    if (i < NT) indptr[i] = c0 + incl - v;  // exclusive
    __syncthreads();
    if (tid == 1023) carry = c0 + wsum[15];
    __syncthreads();
  }
  if (threadIdx.x == 0) indptr[NT] = carry;
}

__global__ __launch_bounds__(256) void k_copy(const int* __restrict__ a, int* __restrict__ b) {
  int i = blockIdx.x * 256 + threadIdx.x;
  if (i < NT) b[i] = a[i];
}

__global__ __launch_bounds__(256) void k_fill(const int* __restrict__ ei0,
                                              const int* __restrict__ ei1,
                                              int* __restrict__ cursor,
                                              int* __restrict__ eids,
                                              int* __restrict__ srcs) {
  int e = blockIdx.x * 256 + threadIdx.x;
  if (e >= ET) return;
  int d, s;
  if (e < NE) { d = ei1[e]; s = ei0[e]; } else { d = e - NE; s = e - NE; }
  int pos = atomicAdd(&cursor[d], 1);
  eids[pos] = e;
  srcs[pos] = s;
}

// ---------------- weight fragment prep (once per launch) ----------------
// xl GEMM B-frags: W[l] is 64x256; Wf[l][((nt*2+kb)*64+lane)*8+j] = W[kb*32+quad*8+j][nt*16+l15]
__global__ void k_prep_wx(const float* __restrict__ W, __hip_bfloat16* __restrict__ Wf) {
  int lane = threadIdx.x;
  int bid = blockIdx.x;
  int l = bid >> 5, rem = bid & 31, t = rem >> 1, kb = rem & 1;
  int quad = lane >> 4, l15 = lane & 15;
  const float* Wl = W + (size_t)l * 64 * 256;
  __hip_bfloat16* out = Wf + (size_t)l * 16384 + (size_t)((t * 2 + kb) * 64 + lane) * 8;
  #pragma unroll
  for (int j = 0; j < 8; j++)
    out[j] = __float2bfloat16(Wl[(kb * 32 + quad * 8 + j) * 256 + t * 16 + l15]);
}

// proj GEMM B-frags: W[l] is 256x64; Wf[l][((nt*8+kb)*64+lane)*8+j] = W[kb*32+quad*8+j][nt*16+l15]
__global__ void k_prep_wp(const float* __restrict__ W, __hip_bfloat16* __restrict__ Wf) {
  int lane = threadIdx.x;
  int bid = blockIdx.x;
  int l = bid >> 5, rem = bid & 31, t = rem >> 3, kb = rem & 7;
  int quad = lane >> 4, l15 = lane & 15;
  const float* Wl = W + (size_t)l * 256 * 64;
  __hip_bfloat16* out = Wf + (size_t)l * 16384 + (size_t)((t * 8 + kb) * 64 + lane) * 8;
  #pragma unroll
  for (int j = 0; j < 8; j++)
    out[j] = __float2bfloat16(Wl[(kb * 32 + quad * 8 + j) * 64 + t * 16 + l15]);
}

// ---------------- per-layer kernels ----------------
// xl = htb @ W via MFMA (M=50048/blockx64, K=64, N=256) + fused a_src/a_dst
__global__ __launch_bounds__(256) void k_xl_mfma(
    const __hip_bfloat16* __restrict__ htb, const __hip_bfloat16* __restrict__ Wf,
    const float* __restrict__ as, const float* __restrict__ ad,
    __hip_bfloat16* __restrict__ xl, float* __restrict__ a_src, float* __restrict__ a_dst) {
  int lane = threadIdx.x & 63, wave = threadIdx.x >> 6;
  int quad = lane >> 4, l15 = lane & 15;
  int r0 = blockIdx.x * 64 + wave * 16;
  f32x4 acc[16];
  #pragma unroll
  for (int t = 0; t < 16; t++) acc[t] = (f32x4){0.f, 0.f, 0.f, 0.f};
  #pragma unroll
  for (int kb = 0; kb < 2; kb++) {
    bf16x8 a = *(const bf16x8*)(htb + (size_t)(r0 + l15) * 64 + kb * 32 + quad * 8);
    #pragma unroll
    for (int t = 0; t < 16; t++) {
      bf16x8 bfr = *(const bf16x8*)(Wf + (size_t)((t * 2 + kb) * 64 + lane) * 8);
      acc[t] = __builtin_amdgcn_mfma_f32_16x16x32_bf16(a, bfr, acc[t], 0, 0, 0);
    }
  }
  float asv[16], adv[16];
  #pragma unroll
  for (int t = 0; t < 16; t++) { asv[t] = as[t * 16 + l15]; adv[t] = ad[t * 16 + l15]; }
  #pragma unroll
  for (int reg = 0; reg < 4; reg++) {
    int row = r0 + quad * 4 + reg;
    bool ok = row < NT;
    float vs[4] = {0.f, 0.f, 0.f, 0.f}, vd[4] = {0.f, 0.f, 0.f, 0.f};
    #pragma unroll
    for (int t = 0; t < 16; t++) {
      float v = acc[t][reg];
      if (ok) xl[(size_t)row * HE + t * 16 + l15] = __float2bfloat16(v);
      vs[t >> 2] += v * asv[t];
      vd[t >> 2] += v * adv[t];
    }
    #pragma unroll
    for (int off = 8; off; off >>= 1) {
      #pragma unroll
      for (int h = 0; h < 4; h++) {
        vs[h] += __shfl_xor(vs[h], off, 64);
        vd[h] += __shfl_xor(vd[h], off, 64);
      }
    }
    if (ok && l15 == 0) {
      float4 s4; s4.x = vs[0]; s4.y = vs[1]; s4.z = vs[2]; s4.w = vs[3];
      float4 d4; d4.x = vd[0]; d4.y = vd[1]; d4.z = vd[2]; d4.w = vd[3];
      *(float4*)(a_src + (size_t)row * 4) = s4;
      *(float4*)(a_dst + (size_t)row * 4) = d4;
    }
  }
}

// M[k][h] = sum_d We[k, h*64+d] * att_edge[h, d]   (8x4)
__global__ void k_att_edge_mat(const float* __restrict__ We, const float* __restrict__ ae,
                               float* __restrict__ M) {
  int t = threadIdx.x;
  if (t >= 32) return;
  int k = t >> 2, h = t & 3;
  float s = 0.f;
  for (int d = 0; d < 64; d++) s += We[k * HE + h * 64 + d] * ae[h * 64 + d];
  M[k * 4 + h] = s;
}

__global__ __launch_bounds__(256) void k_a_edg(const float* __restrict__ ea,
    const float* __restrict__ msum, const float* __restrict__ M, float* __restrict__ aedg) {
  int e = blockIdx.x * 256 + threadIdx.x;
  if (e >= ET) return;
  float v[8];
  if (e < NE) {
    const float4* p = (const float4*)(ea + (size_t)e * 8);
    float4 x0 = p[0], x1 = p[1];
    v[0] = x0.x; v[1] = x0.y; v[2] = x0.z; v[3] = x0.w;
    v[4] = x1.x; v[5] = x1.y; v[6] = x1.z; v[7] = x1.w;
  } else {
    #pragma unroll
    for (int k = 0; k < 8; k++) v[k] = msum[k] * (1.f / NE);
  }
  float rr[4];
  #pragma unroll
  for (int h = 0; h < 4; h++) {
    float s = 0.f;
    #pragma unroll
    for (int k = 0; k < 8; k++) s += v[k] * M[k * 4 + h];
    rr[h] = s;
  }
  float4 r; r.x = rr[0]; r.y = rr[1]; r.z = rr[2]; r.w = rr[3];
  *(float4*)(aedg + (size_t)e * 4) = r;
}

// wave per node, lanes parallel over edges: 2-pass softmax
__global__ __launch_bounds__(256) void k_softmax(
    const float* __restrict__ a_src, const float* __restrict__ a_dst,
    const float* __restrict__ a_edg, const int* __restrict__ indptr,
    const int* __restrict__ eids, const int* __restrict__ srcs,
    float* __restrict__ coeff, float* __restrict__ sinv) {
  int node = blockIdx.x * 4 + (threadIdx.x >> 6);
  int lane = threadIdx.x & 63;
  int beg = indptr[node], end = indptr[node + 1];
  float4 ad = *(const float4*)(a_dst + (size_t)node * 4);
  float m[4] = {-1e30f, -1e30f, -1e30f, -1e30f};
  for (int i = beg + lane; i < end; i += 64) {
    int e = eids[i], s = srcs[i];
    float4 asr = *(const float4*)(a_src + (size_t)s * 4);
    float4 aer = *(const float4*)(a_edg + (size_t)e * 4);
    float al[4] = {asr.x + ad.x + aer.x, asr.y + ad.y + aer.y,
                   asr.z + ad.z + aer.z, asr.w + ad.w + aer.w};
    #pragma unroll
    for (int h = 0; h < 4; h++) {
      float a = al[h];
      a = (a > 0.f) ? a : 0.2f * a;
      m[h] = fmaxf(m[h], a);
    }
  }
  #pragma unroll
  for (int off = 32; off; off >>= 1) {
    #pragma unroll
    for (int h = 0; h < 4; h++) m[h] = fmaxf(m[h], __shfl_xor(m[h], off, 64));
  }
  float sm[4] = {0.f, 0.f, 0.f, 0.f};
  for (int i = beg + lane; i < end; i += 64) {
    int e = eids[i], s = srcs[i];
    float4 asr = *(const float4*)(a_src + (size_t)s * 4);
    float4 aer = *(const float4*)(a_edg + (size_t)e * 4);
    float al[4] = {asr.x + ad.x + aer.x, asr.y + ad.y + aer.y,
                   asr.z + ad.z + aer.z, asr.w + ad.w + aer.w};
    float ex[4];
    #pragma unroll
    for (int h = 0; h < 4; h++) {
      float a = al[h];
      a = (a > 0.f) ? a : 0.2f * a;
      ex[h] = __expf(a - m[h]);
      sm[h] += ex[h];
    }
    float4 c; c.x = ex[0]; c.y = ex[1]; c.z = ex[2]; c.w = ex[3];
    *(float4*)(coeff + (size_t)i * 4) = c;
  }
  #pragma unroll
  for (int off = 32; off; off >>= 1) {
    #pragma unroll
    for (int h = 0; h < 4; h++) sm[h] += __shfl_xor(sm[h], off, 64);
  }
  if (lane == 0) {
    #pragma unroll
    for (int h = 0; h < 4; h++) sinv[node * 4 + h] = 1.f / (sm[h] + 1e-16f);
  }
}

// wave per node, lane=dim
__global__ __launch_bounds__(256) void k_aggregate(
    const __hip_bfloat16* __restrict__ xl, const float* __restrict__ coeff,
    const float* __restrict__ sinv, const int* __restrict__ indptr,
    const int* __restrict__ srcs, const float* __restrict__ gb,
    __hip_bfloat16* __restrict__ agg) {
  int node = blockIdx.x * 4 + (threadIdx.x >> 6);
  int lane = threadIdx.x & 63;
  int beg = indptr[node], end = indptr[node + 1];
  float acc[4] = {0.f, 0.f, 0.f, 0.f};
  for (int i = beg; i < end; i++) {
    int src = __builtin_amdgcn_readfirstlane(srcs[i]);
    float4 cf = *(const float4*)(coeff + (size_t)i * 4);
    const __hip_bfloat16* xr = xl + (size_t)src * HE;
    #pragma unroll
    for (int h = 0; h < 4; h++)
      acc[h] += ((h == 0) ? cf.x : (h == 1) ? cf.y : (h == 2) ? cf.z : cf.w) *
                __bfloat162float(xr[h * 64 + lane]);
  }
  float4 inv = *(const float4*)(sinv + (size_t)node * 4);
  float iv[4] = {inv.x, inv.y, inv.z, inv.w};
  #pragma unroll
  for (int h = 0; h < 4; h++)
    agg[(size_t)node * HE + h * 64 + lane] =
        __float2bfloat16(acc[h] * iv[h] + gb[h * 64 + lane]);
}

// proj GEMM via MFMA + fused bias/ELU/residual/LN
__global__ __launch_bounds__(256) void k_proj_mfma(
    const __hip_bfloat16* __restrict__ agg, const __hip_bfloat16* __restrict__ Wf,
    const float* __restrict__ pb, const float* __restrict__ g, const float* __restrict__ b,
    const float* __restrict__ ht_in, float* __restrict__ ht_out,
    __hip_bfloat16* __restrict__ htb_out, int writebf) {
  int lane = threadIdx.x & 63, wave = threadIdx.x >> 6;
  int quad = lane >> 4, l15 = lane & 15;
  int r0 = blockIdx.x * 64 + wave * 16;
  f32x4 acc[4];
  #pragma unroll
  for (int t = 0; t < 4; t++) acc[t] = (f32x4){0.f, 0.f, 0.f, 0.f};
  #pragma unroll
  for (int kb = 0; kb < 8; kb++) {
    bf16x8 a = *(const bf16x8*)(agg + (size_t)(r0 + l15) * HE + kb * 32 + quad * 8);
    #pragma unroll
    for (int t = 0; t < 4; t++) {
      bf16x8 bfr = *(const bf16x8*)(Wf + (size_t)((t * 8 + kb) * 64 + lane) * 8);
      acc[t] = __builtin_amdgcn_mfma_f32_16x16x32_bf16(a, bfr, acc[t], 0, 0, 0);
    }
  }
  float pbv[4], gv[4], bv[4];
  #pragma unroll
  for (int t = 0; t < 4; t++) {
    pbv[t] = pb[t * 16 + l15];
    gv[t] = g[t * 16 + l15];
    bv[t] = b[t * 16 + l15];
  }
  #pragma unroll
  for (int reg = 0; reg < 4; reg++) {
    int row = r0 + quad * 4 + reg;
    bool ok = row < NT;
    float h[4], rs = 0.f;
    #pragma unroll
    for (int t = 0; t < 4; t++) {
      float u = acc[t][reg] + pbv[t];
      u = (u > 0.f) ? u : (__expf(u) - 1.f);
      h[t] = ht_in[(size_t)row * 64 + t * 16 + l15] + u;
      rs += h[t];
    }
    #pragma unroll
    for (int off = 8; off; off >>= 1) rs += __shfl_xor(rs, off, 64);
    float mu = rs * 0.015625f;
    float vv = 0.f;
    #pragma unroll
    for (int t = 0; t < 4; t++) { float d = h[t] - mu; vv += d * d; }
    #pragma unroll
    for (int off = 8; off; off >>= 1) vv += __shfl_xor(vv, off, 64);
    float rstd = rsqrtf(vv * 0.015625f + 1e-5f);
    #pragma unroll
    for (int t = 0; t < 4; t++) {
      float o = (h[t] - mu) * rstd * gv[t] + bv[t];
      if (ok) {
        ht_out[(size_t)row * 64 + t * 16 + l15] = o;
        if (writebf) htb_out[(size_t)row * 64 + t * 16 + l15] = __float2bfloat16(o);
      }
    }
  }
}

// ---------------- heads ----------------
__global__ __launch_bounds__(256) void k_task_head(const float* __restrict__ ht,
    const float* __restrict__ W1, const float* __restrict__ b1,
    const float* __restrict__ W2, const float* __restrict__ b2, float* __restrict__ logits) {
  __shared__ float lh[8 * 64];
  int t = threadIdx.x;
  size_t base = (size_t)blockIdx.x * 8 * 64;
  lh[t] = ht[base + t];
  lh[t + 256] = ht[base + t + 256];
  __syncthreads();
  int i = t >> 5, j = t & 31;
  float s = b1[j];
  #pragma unroll 8
  for (int d = 0; d < 64; d++) s += lh[i * 64 + d] * W1[d * 32 + j];
  s = fmaxf(s, 0.f);
  float p = s * W2[j];
  #pragma unroll
  for (int off = 16; off; off >>= 1) p += __shfl_xor(p, off, 64);
  if (j == 0) logits[blockIdx.x * 8 + i] = p + b2[0];
}

__global__ __launch_bounds__(256) void k_pool_task(const float* __restrict__ ht,
    const int* __restrict__ tb, float* __restrict__ sums, float* __restrict__ cnt) {
  int lane = threadIdx.x & 63, sub = threadIdx.x >> 6;
  float acc[8], c[8];
  #pragma unroll
  for (int g = 0; g < 8; g++) { acc[g] = 0.f; c[g] = 0.f; }
  int lim = min(NT, (int)((blockIdx.x + 1) * 512));
  for (int n = blockIdx.x * 512 + sub; n < lim; n += 4) {
    int g = tb[n];
    float v = ht[(size_t)n * 64 + lane];
    #pragma unroll
    for (int gg = 0; gg < 8; gg++) {
      if (g == gg) { acc[gg] += v; c[gg] += 1.f; }
    }
  }
  #pragma unroll
  for (int g = 0; g < 8; g++) {
    if (__any(acc[g] != 0.f || c[g] != 0.f)) {
      atomicAdd(&sums[g * 64 + lane], acc[g]);
      if (lane == 0) atomicAdd(&cnt[g], c[g]);
    }
  }
}

__global__ __launch_bounds__(512) void k_value(const float* __restrict__ tpsum,
    const float* __restrict__ tpcnt, const float* __restrict__ hp,
    const int* __restrict__ pbatch, const float* __restrict__ vW1,
    const float* __restrict__ vb1, const float* __restrict__ vW2,
    const float* __restrict__ vb2, float* __restrict__ val_out) {
  __shared__ float ge[8 * 128];
  int t = threadIdx.x;
  int g = t >> 6, d = t & 63;
  float c = fmaxf(tpcnt[g], 1.f);
  ge[g * 128 + d] = tpsum[g * 64 + d] / c;
  float s = 0.f, cc = 0.f;
  for (int p = 0; p < 256; p++) {
    int bg = pbatch[p];
    if (bg == g) { s += hp[(size_t)p * 64 + d]; cc += 1.f; }
  }
  ge[g * 128 + 64 + d] = s / fmaxf(cc, 1.f);
  __syncthreads();
  float acc = vb1[d];
  #pragma unroll 8
  for (int k = 0; k < 128; k++) acc += ge[g * 128 + k] * vW1[k * 64 + d];
  acc = fmaxf(acc, 0.f);
  float p = acc * vW2[d];
  #pragma unroll
  for (int off = 32; off; off >>= 1) p += __shfl_xor(p, off, 64);
  if (d == 0) val_out[g] = p + vb2[0];
}

extern "C" void kernel_launch(void* const* d_in, const int* in_sizes, int n_in,
                              void* d_out, int out_size, void* d_ws, size_t ws_size,
                              hipStream_t stream) {
  (void)in_sizes; (void)n_in; (void)out_size; (void)ws_size;
  const float* x_task  = (const float*)d_in[0];
  const float* x_proc  = (const float*)d_in[1];
  const int*   eidx    = (const int*)d_in[2];
  const float* eattr   = (const float*)d_in[3];
  const int*   tbatch  = (const int*)d_in[4];
  const int*   pbatch  = (const int*)d_in[5];
  const float* W_task  = (const float*)d_in[6];
  const float* b_task  = (const float*)d_in[7];
  const float* W_proc  = (const float*)d_in[8];
  const float* b_proc  = (const float*)d_in[9];
  const float* gat_W   = (const float*)d_in[10];
  const float* gat_We  = (const float*)d_in[11];
  const float* att_src = (const float*)d_in[12];
  const float* att_dst = (const float*)d_in[13];
  const float* att_edge= (const float*)d_in[14];
  const float* gat_b   = (const float*)d_in[15];
  const float* proj_W  = (const float*)d_in[16];
  const float* proj_b  = (const float*)d_in[17];
  const float* ln_g    = (const float*)d_in[18];
  const float* ln_b    = (const float*)d_in[19];
  const float* pt_W1   = (const float*)d_in[20];
  const float* pt_b1   = (const float*)d_in[21];
  const float* pt_W2   = (const float*)d_in[22];
  const float* pt_b2   = (const float*)d_in[23];
  const float* v_W1    = (const float*)d_in[24];
  const float* v_b1    = (const float*)d_in[25];
  const float* v_W2    = (const float*)d_in[26];
  const float* v_b2    = (const float*)d_in[27];

  char* ws = (char*)d_ws;
  int*   deg    = (int*)(ws + OFF_DEG);
  int*   indptr = (int*)(ws + OFF_INDPTR);
  int*   cursor = (int*)(ws + OFF_CURSOR);
  int*   eids   = (int*)(ws + OFF_EIDS);
  int*   srcs   = (int*)(ws + OFF_SRCS);
  float* msum   = (float*)(ws + OFF_MEAN);
  float* Mmat   = (float*)(ws + OFF_M);
  float* tpsum  = (float*)(ws + OFF_TPSUM);
  float* tpcnt  = (float*)(ws + OFF_TPCNT);
  float* a_src  = (float*)(ws + OFF_ASRC);
  float* a_dst  = (float*)(ws + OFF_ADST);
  float* sinv   = (float*)(ws + OFF_SINV);
  float* a_edg  = (float*)(ws + OFF_AEDG);
  float* coeff  = (float*)(ws + OFF_COEFF);
  float* ht     = (float*)(ws + OFF_HT);
  __hip_bfloat16* htb = (__hip_bfloat16*)(ws + OFF_HTB);
  __hip_bfloat16* xl  = (__hip_bfloat16*)(ws + OFF_XL);
  __hip_bfloat16* agg = (__hip_bfloat16*)(ws + OFF_AGG);
  __hip_bfloat16* wxf = (__hip_bfloat16*)(ws + OFF_WXF);
  __hip_bfloat16* wpf = (__hip_bfloat16*)(ws + OFF_WPF);

  float* out_logits = (float*)d_out;
  float* out_value  = (float*)d_out + NT;
  float* out_ht     = (float*)d_out + NT + NG;
  float* out_hp     = (float*)d_out + NT + NG + (size_t)NT * EMBD;

  hipMemsetAsync(ws + OFF_DEG, 0, NT * 4, stream);
  hipMemsetAsync(ws + OFF_MEAN, 0, 2816, stream);  // msum + Mmat + tpsum + tpcnt

  k_embed_task<<<782, 256, 0, stream>>>(x_task, W_task, b_task, ht, htb);
  k_embed_proc<<<1, 256, 0, stream>>>(x_proc, W_proc, b_proc, out_hp);
  k_edge_mean<<<256, 256, 0, stream>>>(eattr, msum);
  k_degree<<<(ET + 255) / 256, 256, 0, stream>>>(eidx + NE, deg);
  k_scan<<<1, 1024, 0, stream>>>(deg, indptr);
  k_copy<<<(NT + 255) / 256, 256, 0, stream>>>(indptr, cursor);
  k_fill<<<(ET + 255) / 256, 256, 0, stream>>>(eidx, eidx + NE, cursor, eids, srcs);
  k_prep_wx<<<96, 64, 0, stream>>>(gat_W, wxf);
  k_prep_wp<<<96, 64, 0, stream>>>(proj_W, wpf);

  for (int l = 0; l < 3; l++) {
    k_xl_mfma<<<782, 256, 0, stream>>>(htb, wxf + (size_t)l * 16384,
                                       att_src + l * NHEADS * EMBD,
                                       att_dst + l * NHEADS * EMBD,
                                       xl, a_src, a_dst);
    k_att_edge_mat<<<1, 32, 0, stream>>>(gat_We + (size_t)l * 8 * HE,
                                         att_edge + l * NHEADS * EMBD, Mmat);
    k_a_edg<<<(ET + 255) / 256, 256, 0, stream>>>(eattr, msum, Mmat, a_edg);
    k_softmax<<<NT / 4, 256, 0, stream>>>(a_src, a_dst, a_edg, indptr, eids, srcs,
                                          coeff, sinv);
    k_aggregate<<<NT / 4, 256, 0, stream>>>(xl, coeff, sinv, indptr, srcs,
                                            gat_b + l * HE, agg);
    float* htout = (l == 2) ? out_ht : ht;
    k_proj_mfma<<<782, 256, 0, stream>>>(agg, wpf + (size_t)l * 16384,
                                         proj_b + l * EMBD, ln_g + l * EMBD,
                                         ln_b + l * EMBD, ht, htout, htb,
                                         (l == 2) ? 0 : 1);
  }

  k_task_head<<<NT / 8, 256, 0, stream>>>(out_ht, pt_W1, pt_b1, pt_W2, pt_b2, out_logits);
  k_pool_task<<<(NT + 511) / 512, 256, 0, stream>>>(out_ht, tbatch, tpsum, tpcnt);
  k_value<<<1, 512, 0, stream>>>(tpsum, tpcnt, out_hp, pbatch, v_W1, v_b1, v_W2, v_b2, out_value);
}

// Round 4
// 806.845 us; speedup vs baseline: 2.0340x; 1.1391x over previous
//
#include <hip/hip_runtime.h>
#include <hip/hip_bf16.h>
#include <math.h>

#define NT 50000
#define NTP 50048   // padded rows (782*64)
#define NP 256
#define NE 800000
#define ET 850000   // NE + NT self loops
#define EMBD 64
#define NHEADS 4
#define HE 256      // NHEADS*EMBD
#define NG 8

typedef __attribute__((ext_vector_type(8))) short bf16x8;
typedef __attribute__((ext_vector_type(4))) float f32x4;

// ---- workspace layout (bytes), all 256-aligned ----
#define OFF_DEG      0u
#define OFF_INDPTR   200192u
#define OFF_CURSOR   400384u
#define OFF_EIDS     600576u
#define OFF_SRCS     4000768u
#define OFF_MEAN     7400960u
#define OFF_M        7401216u
#define OFF_TPSUM    7401472u
#define OFF_TPCNT    7403520u
#define OFF_ASRC     7403776u     // 50048*4 f32
#define OFF_ADST     8204544u
#define OFF_SINV     9005312u
#define OFF_AEDG     9805568u     // 850000*4 f32
#define OFF_COEFF    23405568u    // 850000*4 f32
#define OFF_HT       37005568u    // 50048*64 f32
#define OFF_HTB      49817856u    // 50048*64 bf16
#define OFF_XL       56224000u    // 50000*256 bf16
#define OFF_AGG      81824000u    // 50048*256 bf16
#define OFF_WXF      107448576u   // 3*16384 bf16 (xl B-frags)
#define OFF_WPF      107546880u   // 3*16384 bf16 (proj B-frags)
// total ~107.7 MB

__device__ __forceinline__ float bf2f(unsigned short u) {
  union { unsigned int i; float f; } v; v.i = ((unsigned int)u) << 16; return v.f;
}
__device__ __forceinline__ float bf_lo(unsigned int u) {
  union { unsigned int i; float f; } v; v.i = u << 16; return v.f;
}
__device__ __forceinline__ float bf_hi(unsigned int u) {
  union { unsigned int i; float f; } v; v.i = u & 0xffff0000u; return v.f;
}

// ---------------- input embeds ----------------
__global__ __launch_bounds__(256) void k_embed_task(const float* __restrict__ x,
    const float* __restrict__ W, const float* __restrict__ b,
    float* __restrict__ ht, __hip_bfloat16* __restrict__ htb) {
  int lane = threadIdx.x & 63, wid = threadIdx.x >> 6;
  float breg[16];
  #pragma unroll
  for (int k = 0; k < 16; k++) breg[k] = W[k * 64 + lane];
  float bias = b[lane];
  int row0 = blockIdx.x * 64 + wid * 16;
  #pragma unroll 1
  for (int r = 0; r < 16; r++) {
    int row = row0 + r;
    if (row >= NT) return;
    const float4* xr = (const float4*)(x + (size_t)row * 16);
    float acc = bias;
    #pragma unroll
    for (int q = 0; q < 4; q++) {
      float4 v = xr[q];
      acc += v.x * breg[q*4+0] + v.y * breg[q*4+1] + v.z * breg[q*4+2] + v.w * breg[q*4+3];
    }
    ht[(size_t)row * 64 + lane] = acc;
    htb[(size_t)row * 64 + lane] = __float2bfloat16(acc);
  }
}

__global__ __launch_bounds__(256) void k_embed_proc(const float* __restrict__ x,
    const float* __restrict__ W, const float* __restrict__ b, float* __restrict__ hp) {
  int lane = threadIdx.x & 63, wid = threadIdx.x >> 6;
  float breg[8];
  #pragma unroll
  for (int k = 0; k < 8; k++) breg[k] = W[k * 64 + lane];
  float bias = b[lane];
  #pragma unroll 1
  for (int r = 0; r < 64; r++) {
    int row = wid * 64 + r;
    const float* xr = x + (size_t)row * 8;
    float acc = bias;
    #pragma unroll
    for (int k = 0; k < 8; k++) acc += xr[k] * breg[k];
    hp[(size_t)row * 64 + lane] = acc;
  }
}

// ---------------- edge_attr mean ----------------
__global__ __launch_bounds__(256) void k_edge_mean(const float* __restrict__ ea,
                                                   float* __restrict__ sums) {
  __shared__ float lds[256];
  int k = threadIdx.x & 7;
  int rlane = threadIdx.x >> 3;
  float s = 0.f;
  for (int row = blockIdx.x * 32 + rlane; row < NE; row += gridDim.x * 32)
    s += ea[(size_t)row * 8 + k];
  lds[threadIdx.x] = s;
  __syncthreads();
  for (int off = 128; off >= 8; off >>= 1) {
    if (threadIdx.x < off) lds[threadIdx.x] += lds[threadIdx.x + off];
    __syncthreads();
  }
  if (threadIdx.x < 8) atomicAdd(&sums[threadIdx.x], lds[threadIdx.x]);
}

// ---------------- CSR build ----------------
__global__ __launch_bounds__(256) void k_degree(const int* __restrict__ ei1, int* __restrict__ deg) {
  int e = blockIdx.x * 256 + threadIdx.x;
  if (e >= ET) return;
  int d = (e < NE) ? ei1[e] : (e - NE);
  atomicAdd(&deg[d], 1);
}

__global__ __launch_bounds__(1024) void k_scan(const int* __restrict__ deg, int* __restrict__ indptr) {
  __shared__ int wsum[16];
  __shared__ int carry;
  int tid = threadIdx.x, lane = tid & 63, wid = tid >> 6;
  if (tid == 0) carry = 0;
  __syncthreads();
  for (int base = 0; base < NT; base += 1024) {
    int i = base + tid;
    int v = (i < NT) ? deg[i] : 0;
    int x = v;
    #pragma unroll
    for (int off = 1; off < 64; off <<= 1) {
      int t = __shfl_up(x, off, 64);
      if (lane >= off) x += t;
    }
    if (lane == 63) wsum[wid] = x;
    __syncthreads();
    int c0 = carry;
    if (wid == 0 && lane < 16) {
      int w = wsum[lane];
      #pragma unroll
      for (int off = 1; off < 16; off <<= 1) {
        int t = __shfl_up(w, off, 64);
        if (lane >= off) w += t;
      }
      wsum[lane] = w;  // inclusive
    }
    __syncthreads();
    int woff = (wid == 0) ? 0 : wsum[wid - 1];
    int incl = x + woff;
    if (i < NT) indptr[i] = c0 + incl - v;  // exclusive
    __syncthreads();
    if (tid == 1023) carry = c0 + wsum[15];
    __syncthreads();
  }
  if (threadIdx.x == 0) indptr[NT] = carry;
}

__global__ __launch_bounds__(256) void k_copy(const int* __restrict__ a, int* __restrict__ b) {
  int i = blockIdx.x * 256 + threadIdx.x;
  if (i < NT) b[i] = a[i];
}

__global__ __launch_bounds__(256) void k_fill(const int* __restrict__ ei0,
                                              const int* __restrict__ ei1,
                                              int* __restrict__ cursor,
                                              int* __restrict__ eids,
                                              int* __restrict__ srcs) {
  int e = blockIdx.x * 256 + threadIdx.x;
  if (e >= ET) return;
  int d, s;
  if (e < NE) { d = ei1[e]; s = ei0[e]; } else { d = e - NE; s = e - NE; }
  int pos = atomicAdd(&cursor[d], 1);
  eids[pos] = e;
  srcs[pos] = s;
}

// ---------------- weight fragment prep (once per launch) ----------------
__global__ void k_prep_wx(const float* __restrict__ W, __hip_bfloat16* __restrict__ Wf) {
  int lane = threadIdx.x;
  int bid = blockIdx.x;
  int l = bid >> 5, rem = bid & 31, t = rem >> 1, kb = rem & 1;
  int quad = lane >> 4, l15 = lane & 15;
  const float* Wl = W + (size_t)l * 64 * 256;
  __hip_bfloat16* out = Wf + (size_t)l * 16384 + (size_t)((t * 2 + kb) * 64 + lane) * 8;
  #pragma unroll
  for (int j = 0; j < 8; j++)
    out[j] = __float2bfloat16(Wl[(kb * 32 + quad * 8 + j) * 256 + t * 16 + l15]);
}

__global__ void k_prep_wp(const float* __restrict__ W, __hip_bfloat16* __restrict__ Wf) {
  int lane = threadIdx.x;
  int bid = blockIdx.x;
  int l = bid >> 5, rem = bid & 31, t = rem >> 3, kb = rem & 7;
  int quad = lane >> 4, l15 = lane & 15;
  const float* Wl = W + (size_t)l * 256 * 64;
  __hip_bfloat16* out = Wf + (size_t)l * 16384 + (size_t)((t * 8 + kb) * 64 + lane) * 8;
  #pragma unroll
  for (int j = 0; j < 8; j++)
    out[j] = __float2bfloat16(Wl[(kb * 32 + quad * 8 + j) * 64 + t * 16 + l15]);
}

// ---------------- per-layer kernels ----------------
// xl = htb @ W via MFMA + fused a_src/a_dst
__global__ __launch_bounds__(256) void k_xl_mfma(
    const __hip_bfloat16* __restrict__ htb, const __hip_bfloat16* __restrict__ Wf,
    const float* __restrict__ as, const float* __restrict__ ad,
    __hip_bfloat16* __restrict__ xl, float* __restrict__ a_src, float* __restrict__ a_dst) {
  int lane = threadIdx.x & 63, wave = threadIdx.x >> 6;
  int quad = lane >> 4, l15 = lane & 15;
  int r0 = blockIdx.x * 64 + wave * 16;
  f32x4 acc[16];
  #pragma unroll
  for (int t = 0; t < 16; t++) acc[t] = (f32x4){0.f, 0.f, 0.f, 0.f};
  #pragma unroll
  for (int kb = 0; kb < 2; kb++) {
    bf16x8 a = *(const bf16x8*)(htb + (size_t)(r0 + l15) * 64 + kb * 32 + quad * 8);
    #pragma unroll
    for (int t = 0; t < 16; t++) {
      bf16x8 bfr = *(const bf16x8*)(Wf + (size_t)((t * 2 + kb) * 64 + lane) * 8);
      acc[t] = __builtin_amdgcn_mfma_f32_16x16x32_bf16(a, bfr, acc[t], 0, 0, 0);
    }
  }
  float asv[16], adv[16];
  #pragma unroll
  for (int t = 0; t < 16; t++) { asv[t] = as[t * 16 + l15]; adv[t] = ad[t * 16 + l15]; }
  #pragma unroll
  for (int reg = 0; reg < 4; reg++) {
    int row = r0 + quad * 4 + reg;
    bool ok = row < NT;
    float vs[4] = {0.f, 0.f, 0.f, 0.f}, vd[4] = {0.f, 0.f, 0.f, 0.f};
    #pragma unroll
    for (int t = 0; t < 16; t++) {
      float v = acc[t][reg];
      if (ok) xl[(size_t)row * HE + t * 16 + l15] = __float2bfloat16(v);
      vs[t >> 2] += v * asv[t];
      vd[t >> 2] += v * adv[t];
    }
    #pragma unroll
    for (int off = 8; off; off >>= 1) {
      #pragma unroll
      for (int h = 0; h < 4; h++) {
        vs[h] += __shfl_xor(vs[h], off, 64);
        vd[h] += __shfl_xor(vd[h], off, 64);
      }
    }
    if (ok && l15 == 0) {
      float4 s4; s4.x = vs[0]; s4.y = vs[1]; s4.z = vs[2]; s4.w = vs[3];
      float4 d4; d4.x = vd[0]; d4.y = vd[1]; d4.z = vd[2]; d4.w = vd[3];
      *(float4*)(a_src + (size_t)row * 4) = s4;
      *(float4*)(a_dst + (size_t)row * 4) = d4;
    }
  }
}

// M[k][h] = sum_d We[k, h*64+d] * att_edge[h, d]   (8x4)
__global__ void k_att_edge_mat(const float* __restrict__ We, const float* __restrict__ ae,
                               float* __restrict__ M) {
  int t = threadIdx.x;
  if (t >= 32) return;
  int k = t >> 2, h = t & 3;
  float s = 0.f;
  for (int d = 0; d < 64; d++) s += We[k * HE + h * 64 + d] * ae[h * 64 + d];
  M[k * 4 + h] = s;
}

__global__ __launch_bounds__(256) void k_a_edg(const float* __restrict__ ea,
    const float* __restrict__ msum, const float* __restrict__ M, float* __restrict__ aedg) {
  int e = blockIdx.x * 256 + threadIdx.x;
  if (e >= ET) return;
  float v[8];
  if (e < NE) {
    const float4* p = (const float4*)(ea + (size_t)e * 8);
    float4 x0 = p[0], x1 = p[1];
    v[0] = x0.x; v[1] = x0.y; v[2] = x0.z; v[3] = x0.w;
    v[4] = x1.x; v[5] = x1.y; v[6] = x1.z; v[7] = x1.w;
  } else {
    #pragma unroll
    for (int k = 0; k < 8; k++) v[k] = msum[k] * (1.f / NE);
  }
  float rr[4];
  #pragma unroll
  for (int h = 0; h < 4; h++) {
    float s = 0.f;
    #pragma unroll
    for (int k = 0; k < 8; k++) s += v[k] * M[k * 4 + h];
    rr[h] = s;
  }
  float4 r; r.x = rr[0]; r.y = rr[1]; r.z = rr[2]; r.w = rr[3];
  *(float4*)(aedg + (size_t)e * 4) = r;
}

// wave per node, lanes parallel over edges; pass1 caches al in coeff so pass2
// avoids re-gathering a_src/a_edg
__global__ __launch_bounds__(256) void k_softmax(
    const float* __restrict__ a_src, const float* __restrict__ a_dst,
    const float* __restrict__ a_edg, const int* __restrict__ indptr,
    const int* __restrict__ eids, const int* __restrict__ srcs,
    float* __restrict__ coeff, float* __restrict__ sinv) {
  int node = blockIdx.x * 4 + (threadIdx.x >> 6);
  int lane = threadIdx.x & 63;
  int beg = indptr[node], end = indptr[node + 1];
  float4 ad = *(const float4*)(a_dst + (size_t)node * 4);
  float m[4] = {-1e30f, -1e30f, -1e30f, -1e30f};
  for (int i = beg + lane; i < end; i += 64) {
    int e = eids[i], s = srcs[i];
    float4 asr = *(const float4*)(a_src + (size_t)s * 4);
    float4 aer = *(const float4*)(a_edg + (size_t)e * 4);
    float al[4] = {asr.x + ad.x + aer.x, asr.y + ad.y + aer.y,
                   asr.z + ad.z + aer.z, asr.w + ad.w + aer.w};
    #pragma unroll
    for (int h = 0; h < 4; h++) {
      float a = al[h];
      a = (a > 0.f) ? a : 0.2f * a;
      al[h] = a;
      m[h] = fmaxf(m[h], a);
    }
    float4 c; c.x = al[0]; c.y = al[1]; c.z = al[2]; c.w = al[3];
    *(float4*)(coeff + (size_t)i * 4) = c;
  }
  #pragma unroll
  for (int off = 32; off; off >>= 1) {
    #pragma unroll
    for (int h = 0; h < 4; h++) m[h] = fmaxf(m[h], __shfl_xor(m[h], off, 64));
  }
  float sm[4] = {0.f, 0.f, 0.f, 0.f};
  for (int i = beg + lane; i < end; i += 64) {
    float4 al = *(const float4*)(coeff + (size_t)i * 4);
    float ex[4];
    ex[0] = __expf(al.x - m[0]);
    ex[1] = __expf(al.y - m[1]);
    ex[2] = __expf(al.z - m[2]);
    ex[3] = __expf(al.w - m[3]);
    #pragma unroll
    for (int h = 0; h < 4; h++) sm[h] += ex[h];
    float4 c; c.x = ex[0]; c.y = ex[1]; c.z = ex[2]; c.w = ex[3];
    *(float4*)(coeff + (size_t)i * 4) = c;
  }
  #pragma unroll
  for (int off = 32; off; off >>= 1) {
    #pragma unroll
    for (int h = 0; h < 4; h++) sm[h] += __shfl_xor(sm[h], off, 64);
  }
  if (lane == 0) {
    #pragma unroll
    for (int h = 0; h < 4; h++) sinv[node * 4 + h] = 1.f / (sm[h] + 1e-16f);
  }
}

// wave per node, lane L owns dims 4L..4L+3 (head = L>>4): whole 512B xl row is
// ONE global_load_dwordx2 per wave; srcs prefetched lane-parallel, coeff
// prefetched 16 edges coalesced + bpermute broadcast
__global__ __launch_bounds__(256) void k_aggregate(
    const __hip_bfloat16* __restrict__ xl, const float* __restrict__ coeff,
    const float* __restrict__ sinv, const int* __restrict__ indptr,
    const int* __restrict__ srcs, const float* __restrict__ gb,
    __hip_bfloat16* __restrict__ agg) {
  int node = blockIdx.x * 4 + (threadIdx.x >> 6);
  int lane = threadIdx.x & 63;
  int h = lane >> 4;
  int hbase = lane & 48;      // h*16, for coeff bpermute index
  int beg = indptr[node], end = indptr[node + 1];
  float acc0 = 0.f, acc1 = 0.f, acc2 = 0.f, acc3 = 0.f;
  for (int base = beg; base < end; base += 64) {
    int cnt = min(64, end - base);
    int my_src = (lane < cnt) ? srcs[base + lane] : 0;
    for (int c16 = 0; c16 < cnt; c16 += 16) {
      int n16 = min(16, cnt - c16);
      int el = c16 + (lane & 15);
      float my_cf = (el < cnt) ? coeff[(size_t)(base + el) * 4 + h] : 0.f;
      if (n16 == 16) {
        #pragma unroll 4
        for (int j = 0; j < 16; j++) {
          int src = __shfl(my_src, c16 + j, 64);
          float cf = __shfl(my_cf, hbase | j, 64);
          uint2 u = *(const uint2*)(xl + (size_t)src * HE + lane * 4);
          acc0 += cf * bf_lo(u.x);
          acc1 += cf * bf_hi(u.x);
          acc2 += cf * bf_lo(u.y);
          acc3 += cf * bf_hi(u.y);
        }
      } else {
        for (int j = 0; j < n16; j++) {
          int src = __shfl(my_src, c16 + j, 64);
          float cf = __shfl(my_cf, hbase | j, 64);
          uint2 u = *(const uint2*)(xl + (size_t)src * HE + lane * 4);
          acc0 += cf * bf_lo(u.x);
          acc1 += cf * bf_hi(u.x);
          acc2 += cf * bf_lo(u.y);
          acc3 += cf * bf_hi(u.y);
        }
      }
    }
  }
  float inv = sinv[node * 4 + h];
  float4 g4 = *(const float4*)(gb + lane * 4);
  unsigned int o0 = __bfloat16_as_ushort(__float2bfloat16(acc0 * inv + g4.x));
  unsigned int o1 = __bfloat16_as_ushort(__float2bfloat16(acc1 * inv + g4.y));
  unsigned int o2 = __bfloat16_as_ushort(__float2bfloat16(acc2 * inv + g4.z));
  unsigned int o3 = __bfloat16_as_ushort(__float2bfloat16(acc3 * inv + g4.w));
  uint2 out; out.x = o0 | (o1 << 16); out.y = o2 | (o3 << 16);
  *(uint2*)(agg + (size_t)node * HE + lane * 4) = out;
}

// proj GEMM via MFMA + fused bias/ELU/residual/LN
__global__ __launch_bounds__(256) void k_proj_mfma(
    const __hip_bfloat16* __restrict__ agg, const __hip_bfloat16* __restrict__ Wf,
    const float* __restrict__ pb, const float* __restrict__ g, const float* __restrict__ b,
    const float* __restrict__ ht_in, float* __restrict__ ht_out,
    __hip_bfloat16* __restrict__ htb_out, int writebf) {
  int lane = threadIdx.x & 63, wave = threadIdx.x >> 6;
  int quad = lane >> 4, l15 = lane & 15;
  int r0 = blockIdx.x * 64 + wave * 16;
  f32x4 acc[4];
  #pragma unroll
  for (int t = 0; t < 4; t++) acc[t] = (f32x4){0.f, 0.f, 0.f, 0.f};
  #pragma unroll
  for (int kb = 0; kb < 8; kb++) {
    bf16x8 a = *(const bf16x8*)(agg + (size_t)(r0 + l15) * HE + kb * 32 + quad * 8);
    #pragma unroll
    for (int t = 0; t < 4; t++) {
      bf16x8 bfr = *(const bf16x8*)(Wf + (size_t)((t * 8 + kb) * 64 + lane) * 8);
      acc[t] = __builtin_amdgcn_mfma_f32_16x16x32_bf16(a, bfr, acc[t], 0, 0, 0);
    }
  }
  float pbv[4], gv[4], bv[4];
  #pragma unroll
  for (int t = 0; t < 4; t++) {
    pbv[t] = pb[t * 16 + l15];
    gv[t] = g[t * 16 + l15];
    bv[t] = b[t * 16 + l15];
  }
  #pragma unroll
  for (int reg = 0; reg < 4; reg++) {
    int row = r0 + quad * 4 + reg;
    bool ok = row < NT;
    float h[4], rs = 0.f;
    #pragma unroll
    for (int t = 0; t < 4; t++) {
      float u = acc[t][reg] + pbv[t];
      u = (u > 0.f) ? u : (__expf(u) - 1.f);
      h[t] = ht_in[(size_t)row * 64 + t * 16 + l15] + u;
      rs += h[t];
    }
    #pragma unroll
    for (int off = 8; off; off >>= 1) rs += __shfl_xor(rs, off, 64);
    float mu = rs * 0.015625f;
    float vv = 0.f;
    #pragma unroll
    for (int t = 0; t < 4; t++) { float d = h[t] - mu; vv += d * d; }
    #pragma unroll
    for (int off = 8; off; off >>= 1) vv += __shfl_xor(vv, off, 64);
    float rstd = rsqrtf(vv * 0.015625f + 1e-5f);
    #pragma unroll
    for (int t = 0; t < 4; t++) {
      float o = (h[t] - mu) * rstd * gv[t] + bv[t];
      if (ok) {
        ht_out[(size_t)row * 64 + t * 16 + l15] = o;
        if (writebf) htb_out[(size_t)row * 64 + t * 16 + l15] = __float2bfloat16(o);
      }
    }
  }
}

// ---------------- heads ----------------
__global__ __launch_bounds__(256) void k_task_head(const float* __restrict__ ht,
    const float* __restrict__ W1, const float* __restrict__ b1,
    const float* __restrict__ W2, const float* __restrict__ b2, float* __restrict__ logits) {
  __shared__ float lh[8 * 64];
  int t = threadIdx.x;
  size_t base = (size_t)blockIdx.x * 8 * 64;
  lh[t] = ht[base + t];
  lh[t + 256] = ht[base + t + 256];
  __syncthreads();
  int i = t >> 5, j = t & 31;
  float s = b1[j];
  #pragma unroll 8
  for (int d = 0; d < 64; d++) s += lh[i * 64 + d] * W1[d * 32 + j];
  s = fmaxf(s, 0.f);
  float p = s * W2[j];
  #pragma unroll
  for (int off = 16; off; off >>= 1) p += __shfl_xor(p, off, 64);
  if (j == 0) logits[blockIdx.x * 8 + i] = p + b2[0];
}

__global__ __launch_bounds__(256) void k_pool_task(const float* __restrict__ ht,
    const int* __restrict__ tb, float* __restrict__ sums, float* __restrict__ cnt) {
  int lane = threadIdx.x & 63, sub = threadIdx.x >> 6;
  float acc[8], c[8];
  #pragma unroll
  for (int g = 0; g < 8; g++) { acc[g] = 0.f; c[g] = 0.f; }
  int lim = min(NT, (int)((blockIdx.x + 1) * 512));
  for (int n = blockIdx.x * 512 + sub; n < lim; n += 4) {
    int g = tb[n];
    float v = ht[(size_t)n * 64 + lane];
    #pragma unroll
    for (int gg = 0; gg < 8; gg++) {
      if (g == gg) { acc[gg] += v; c[gg] += 1.f; }
    }
  }
  #pragma unroll
  for (int g = 0; g < 8; g++) {
    if (__any(acc[g] != 0.f || c[g] != 0.f)) {
      atomicAdd(&sums[g * 64 + lane], acc[g]);
      if (lane == 0) atomicAdd(&cnt[g], c[g]);
    }
  }
}

__global__ __launch_bounds__(512) void k_value(const float* __restrict__ tpsum,
    const float* __restrict__ tpcnt, const float* __restrict__ hp,
    const int* __restrict__ pbatch, const float* __restrict__ vW1,
    const float* __restrict__ vb1, const float* __restrict__ vW2,
    const float* __restrict__ vb2, float* __restrict__ val_out) {
  __shared__ float ge[8 * 128];
  int t = threadIdx.x;
  int g = t >> 6, d = t & 63;
  float c = fmaxf(tpcnt[g], 1.f);
  ge[g * 128 + d] = tpsum[g * 64 + d] / c;
  float s = 0.f, cc = 0.f;
  for (int p = 0; p < 256; p++) {
    int bg = pbatch[p];
    if (bg == g) { s += hp[(size_t)p * 64 + d]; cc += 1.f; }
  }
  ge[g * 128 + 64 + d] = s / fmaxf(cc, 1.f);
  __syncthreads();
  float acc = vb1[d];
  #pragma unroll 8
  for (int k = 0; k < 128; k++) acc += ge[g * 128 + k] * vW1[k * 64 + d];
  acc = fmaxf(acc, 0.f);
  float p = acc * vW2[d];
  #pragma unroll
  for (int off = 32; off; off >>= 1) p += __shfl_xor(p, off, 64);
  if (d == 0) val_out[g] = p + vb2[0];
}

extern "C" void kernel_launch(void* const* d_in, const int* in_sizes, int n_in,
                              void* d_out, int out_size, void* d_ws, size_t ws_size,
                              hipStream_t stream) {
  (void)in_sizes; (void)n_in; (void)out_size; (void)ws_size;
  const float* x_task  = (const float*)d_in[0];
  const float* x_proc  = (const float*)d_in[1];
  const int*   eidx    = (const int*)d_in[2];
  const float* eattr   = (const float*)d_in[3];
  const int*   tbatch  = (const int*)d_in[4];
  const int*   pbatch  = (const int*)d_in[5];
  const float* W_task  = (const float*)d_in[6];
  const float* b_task  = (const float*)d_in[7];
  const float* W_proc  = (const float*)d_in[8];
  const float* b_proc  = (const float*)d_in[9];
  const float* gat_W   = (const float*)d_in[10];
  const float* gat_We  = (const float*)d_in[11];
  const float* att_src = (const float*)d_in[12];
  const float* att_dst = (const float*)d_in[13];
  const float* att_edge= (const float*)d_in[14];
  const float* gat_b   = (const float*)d_in[15];
  const float* proj_W  = (const float*)d_in[16];
  const float* proj_b  = (const float*)d_in[17];
  const float* ln_g    = (const float*)d_in[18];
  const float* ln_b    = (const float*)d_in[19];
  const float* pt_W1   = (const float*)d_in[20];
  const float* pt_b1   = (const float*)d_in[21];
  const float* pt_W2   = (const float*)d_in[22];
  const float* pt_b2   = (const float*)d_in[23];
  const float* v_W1    = (const float*)d_in[24];
  const float* v_b1    = (const float*)d_in[25];
  const float* v_W2    = (const float*)d_in[26];
  const float* v_b2    = (const float*)d_in[27];

  char* ws = (char*)d_ws;
  int*   deg    = (int*)(ws + OFF_DEG);
  int*   indptr = (int*)(ws + OFF_INDPTR);
  int*   cursor = (int*)(ws + OFF_CURSOR);
  int*   eids   = (int*)(ws + OFF_EIDS);
  int*   srcs   = (int*)(ws + OFF_SRCS);
  float* msum   = (float*)(ws + OFF_MEAN);
  float* Mmat   = (float*)(ws + OFF_M);
  float* tpsum  = (float*)(ws + OFF_TPSUM);
  float* tpcnt  = (float*)(ws + OFF_TPCNT);
  float* a_src  = (float*)(ws + OFF_ASRC);
  float* a_dst  = (float*)(ws + OFF_ADST);
  float* sinv   = (float*)(ws + OFF_SINV);
  float* a_edg  = (float*)(ws + OFF_AEDG);
  float* coeff  = (float*)(ws + OFF_COEFF);
  float* ht     = (float*)(ws + OFF_HT);
  __hip_bfloat16* htb = (__hip_bfloat16*)(ws + OFF_HTB);
  __hip_bfloat16* xl  = (__hip_bfloat16*)(ws + OFF_XL);
  __hip_bfloat16* agg = (__hip_bfloat16*)(ws + OFF_AGG);
  __hip_bfloat16* wxf = (__hip_bfloat16*)(ws + OFF_WXF);
  __hip_bfloat16* wpf = (__hip_bfloat16*)(ws + OFF_WPF);

  float* out_logits = (float*)d_out;
  float* out_value  = (float*)d_out + NT;
  float* out_ht     = (float*)d_out + NT + NG;
  float* out_hp     = (float*)d_out + NT + NG + (size_t)NT * EMBD;

  hipMemsetAsync(ws + OFF_DEG, 0, NT * 4, stream);
  hipMemsetAsync(ws + OFF_MEAN, 0, 2816, stream);  // msum + Mmat + tpsum + tpcnt

  k_embed_task<<<782, 256, 0, stream>>>(x_task, W_task, b_task, ht, htb);
  k_embed_proc<<<1, 256, 0, stream>>>(x_proc, W_proc, b_proc, out_hp);
  k_edge_mean<<<256, 256, 0, stream>>>(eattr, msum);
  k_degree<<<(ET + 255) / 256, 256, 0, stream>>>(eidx + NE, deg);
  k_scan<<<1, 1024, 0, stream>>>(deg, indptr);
  k_copy<<<(NT + 255) / 256, 256, 0, stream>>>(indptr, cursor);
  k_fill<<<(ET + 255) / 256, 256, 0, stream>>>(eidx, eidx + NE, cursor, eids, srcs);
  k_prep_wx<<<96, 64, 0, stream>>>(gat_W, wxf);
  k_prep_wp<<<96, 64, 0, stream>>>(proj_W, wpf);

  for (int l = 0; l < 3; l++) {
    k_xl_mfma<<<782, 256, 0, stream>>>(htb, wxf + (size_t)l * 16384,
                                       att_src + l * NHEADS * EMBD,
                                       att_dst + l * NHEADS * EMBD,
                                       xl, a_src, a_dst);
    k_att_edge_mat<<<1, 32, 0, stream>>>(gat_We + (size_t)l * 8 * HE,
                                         att_edge + l * NHEADS * EMBD, Mmat);
    k_a_edg<<<(ET + 255) / 256, 256, 0, stream>>>(eattr, msum, Mmat, a_edg);
    k_softmax<<<NT / 4, 256, 0, stream>>>(a_src, a_dst, a_edg, indptr, eids, srcs,
                                          coeff, sinv);
    k_aggregate<<<NT / 4, 256, 0, stream>>>(xl, coeff, sinv, indptr, srcs,
                                            gat_b + l * HE, agg);
    float* htout = (l == 2) ? out_ht : ht;
    k_proj_mfma<<<782, 256, 0, stream>>>(agg, wpf + (size_t)l * 16384,
                                         proj_b + l * EMBD, ln_g + l * EMBD,
                                         ln_b + l * EMBD, ht, htout, htb,
                                         (l == 2) ? 0 : 1);
  }

  k_task_head<<<NT / 8, 256, 0, stream>>>(out_ht, pt_W1, pt_b1, pt_W2, pt_b2, out_logits);
  k_pool_task<<<(NT + 511) / 512, 256, 0, stream>>>(out_ht, tbatch, tpsum, tpcnt);
  k_value<<<1, 512, 0, stream>>>(tpsum, tpcnt, out_hp, pbatch, v_W1, v_b1, v_W2, v_b2, out_value);
}

// Round 5
// 768.638 us; speedup vs baseline: 2.1351x; 1.0497x over previous
//
#include <hip/hip_runtime.h>
#include <hip/hip_bf16.h>
#include <math.h>

#define NT 50000
#define NP 256
#define NE 800000
#define ET 850000   // NE + NT self loops
#define EMBD 64
#define NHEADS 4
#define HE 256      // NHEADS*EMBD
#define NG 8

typedef __attribute__((ext_vector_type(8))) short bf16x8;
typedef __attribute__((ext_vector_type(4))) float f32x4;

// ---- workspace layout (bytes), all 256-aligned ----
#define OFF_DEG      0u
#define OFF_INDPTR   200192u
#define OFF_CURSOR   400384u
#define OFF_POS      600576u      // 850000 i32: CSR slot of edge e
#define OFF_SRCS     4000768u     // 850000 i32 (CSR-ordered src node)
#define OFF_MEAN     7400960u     // 8 f32
#define OFF_M        7401216u     // 32 f32 (unused)
#define OFF_TPSUM    7401472u     // 512 f32
#define OFF_TPCNT    7403520u     // 8 f32
#define OFF_ASRC     7403776u     // 50048*4 f32
#define OFF_ADST     8204544u
#define OFF_AEDG     9805568u     // 850000*4 f32, CSR order
#define OFF_HT       37005568u    // 50048*64 f32
#define OFF_HTB      49817856u    // 50048*64 bf16
#define OFF_XL       56224000u    // 50000*256 bf16
#define OFF_AGG      81824000u    // 50048*256 bf16
#define OFF_WXF      107448576u   // 3*16384 bf16 (xl B-frags)
#define OFF_WPF      107546880u   // 3*16384 bf16 (proj B-frags)
// total ~107.7 MB

__device__ __forceinline__ float bf_lo(unsigned int u) {
  union { unsigned int i; float f; } v; v.i = u << 16; return v.f;
}
__device__ __forceinline__ float bf_hi(unsigned int u) {
  union { unsigned int i; float f; } v; v.i = u & 0xffff0000u; return v.f;
}

// ---------------- input embeds ----------------
__global__ __launch_bounds__(256) void k_embed_task(const float* __restrict__ x,
    const float* __restrict__ W, const float* __restrict__ b,
    float* __restrict__ ht, __hip_bfloat16* __restrict__ htb) {
  int lane = threadIdx.x & 63, wid = threadIdx.x >> 6;
  float breg[16];
  #pragma unroll
  for (int k = 0; k < 16; k++) breg[k] = W[k * 64 + lane];
  float bias = b[lane];
  int row0 = blockIdx.x * 64 + wid * 16;
  #pragma unroll 1
  for (int r = 0; r < 16; r++) {
    int row = row0 + r;
    if (row >= NT) return;
    const float4* xr = (const float4*)(x + (size_t)row * 16);
    float acc = bias;
    #pragma unroll
    for (int q = 0; q < 4; q++) {
      float4 v = xr[q];
      acc += v.x * breg[q*4+0] + v.y * breg[q*4+1] + v.z * breg[q*4+2] + v.w * breg[q*4+3];
    }
    ht[(size_t)row * 64 + lane] = acc;
    htb[(size_t)row * 64 + lane] = __float2bfloat16(acc);
  }
}

__global__ __launch_bounds__(256) void k_embed_proc(const float* __restrict__ x,
    const float* __restrict__ W, const float* __restrict__ b, float* __restrict__ hp) {
  int lane = threadIdx.x & 63, wid = threadIdx.x >> 6;
  float breg[8];
  #pragma unroll
  for (int k = 0; k < 8; k++) breg[k] = W[k * 64 + lane];
  float bias = b[lane];
  #pragma unroll 1
  for (int r = 0; r < 64; r++) {
    int row = wid * 64 + r;
    const float* xr = x + (size_t)row * 8;
    float acc = bias;
    #pragma unroll
    for (int k = 0; k < 8; k++) acc += xr[k] * breg[k];
    hp[(size_t)row * 64 + lane] = acc;
  }
}

// ---------------- edge_attr mean ----------------
__global__ __launch_bounds__(256) void k_edge_mean(const float* __restrict__ ea,
                                                   float* __restrict__ sums) {
  __shared__ float lds[256];
  int k = threadIdx.x & 7;
  int rlane = threadIdx.x >> 3;
  float s = 0.f;
  for (int row = blockIdx.x * 32 + rlane; row < NE; row += gridDim.x * 32)
    s += ea[(size_t)row * 8 + k];
  lds[threadIdx.x] = s;
  __syncthreads();
  for (int off = 128; off >= 8; off >>= 1) {
    if (threadIdx.x < off) lds[threadIdx.x] += lds[threadIdx.x + off];
    __syncthreads();
  }
  if (threadIdx.x < 8) atomicAdd(&sums[threadIdx.x], lds[threadIdx.x]);
}

// ---------------- CSR build ----------------
__global__ __launch_bounds__(256) void k_degree(const int* __restrict__ ei1, int* __restrict__ deg) {
  int e = blockIdx.x * 256 + threadIdx.x;
  if (e >= ET) return;
  int d = (e < NE) ? ei1[e] : (e - NE);
  atomicAdd(&deg[d], 1);
}

__global__ __launch_bounds__(1024) void k_scan(const int* __restrict__ deg,
                                               int* __restrict__ indptr,
                                               int* __restrict__ cursor) {
  __shared__ int wsum[16];
  __shared__ int carry;
  int tid = threadIdx.x, lane = tid & 63, wid = tid >> 6;
  if (tid == 0) carry = 0;
  __syncthreads();
  for (int base = 0; base < NT; base += 1024) {
    int i = base + tid;
    int v = (i < NT) ? deg[i] : 0;
    int x = v;
    #pragma unroll
    for (int off = 1; off < 64; off <<= 1) {
      int t = __shfl_up(x, off, 64);
      if (lane >= off) x += t;
    }
    if (lane == 63) wsum[wid] = x;
    __syncthreads();
    int c0 = carry;
    if (wid == 0 && lane < 16) {
      int w = wsum[lane];
      #pragma unroll
      for (int off = 1; off < 16; off <<= 1) {
        int t = __shfl_up(w, off, 64);
        if (lane >= off) w += t;
      }
      wsum[lane] = w;  // inclusive
    }
    __syncthreads();
    int woff = (wid == 0) ? 0 : wsum[wid - 1];
    int incl = x + woff;
    if (i < NT) {
      int excl = c0 + incl - v;
      indptr[i] = excl;
      cursor[i] = excl;
    }
    __syncthreads();
    if (tid == 1023) carry = c0 + wsum[15];
    __syncthreads();
  }
  if (threadIdx.x == 0) indptr[NT] = carry;
}

__global__ __launch_bounds__(256) void k_fill(const int* __restrict__ ei0,
                                              const int* __restrict__ ei1,
                                              int* __restrict__ cursor,
                                              int* __restrict__ pos,
                                              int* __restrict__ srcs) {
  int e = blockIdx.x * 256 + threadIdx.x;
  if (e >= ET) return;
  int d, s;
  if (e < NE) { d = ei1[e]; s = ei0[e]; } else { d = e - NE; s = e - NE; }
  int p = atomicAdd(&cursor[d], 1);
  srcs[p] = s;
  pos[e] = p;
}

// ---------------- weight fragment prep (once per launch) ----------------
__global__ void k_prep_wx(const float* __restrict__ W, __hip_bfloat16* __restrict__ Wf) {
  int lane = threadIdx.x;
  int bid = blockIdx.x;
  int l = bid >> 5, rem = bid & 31, t = rem >> 1, kb = rem & 1;
  int quad = lane >> 4, l15 = lane & 15;
  const float* Wl = W + (size_t)l * 64 * 256;
  __hip_bfloat16* out = Wf + (size_t)l * 16384 + (size_t)((t * 2 + kb) * 64 + lane) * 8;
  #pragma unroll
  for (int j = 0; j < 8; j++)
    out[j] = __float2bfloat16(Wl[(kb * 32 + quad * 8 + j) * 256 + t * 16 + l15]);
}

__global__ void k_prep_wp(const float* __restrict__ W, __hip_bfloat16* __restrict__ Wf) {
  int lane = threadIdx.x;
  int bid = blockIdx.x;
  int l = bid >> 5, rem = bid & 31, t = rem >> 3, kb = rem & 7;
  int quad = lane >> 4, l15 = lane & 15;
  const float* Wl = W + (size_t)l * 256 * 64;
  __hip_bfloat16* out = Wf + (size_t)l * 16384 + (size_t)((t * 8 + kb) * 64 + lane) * 8;
  #pragma unroll
  for (int j = 0; j < 8; j++)
    out[j] = __float2bfloat16(Wl[(kb * 32 + quad * 8 + j) * 64 + t * 16 + l15]);
}

// ---------------- per-layer kernels ----------------
// xl = htb @ W via MFMA + fused a_src/a_dst
__global__ __launch_bounds__(256) void k_xl_mfma(
    const __hip_bfloat16* __restrict__ htb, const __hip_bfloat16* __restrict__ Wf,
    const float* __restrict__ as, const float* __restrict__ ad,
    __hip_bfloat16* __restrict__ xl, float* __restrict__ a_src, float* __restrict__ a_dst) {
  int lane = threadIdx.x & 63, wave = threadIdx.x >> 6;
  int quad = lane >> 4, l15 = lane & 15;
  int r0 = blockIdx.x * 64 + wave * 16;
  f32x4 acc[16];
  #pragma unroll
  for (int t = 0; t < 16; t++) acc[t] = (f32x4){0.f, 0.f, 0.f, 0.f};
  #pragma unroll
  for (int kb = 0; kb < 2; kb++) {
    bf16x8 a = *(const bf16x8*)(htb + (size_t)(r0 + l15) * 64 + kb * 32 + quad * 8);
    #pragma unroll
    for (int t = 0; t < 16; t++) {
      bf16x8 bfr = *(const bf16x8*)(Wf + (size_t)((t * 2 + kb) * 64 + lane) * 8);
      acc[t] = __builtin_amdgcn_mfma_f32_16x16x32_bf16(a, bfr, acc[t], 0, 0, 0);
    }
  }
  float asv[16], adv[16];
  #pragma unroll
  for (int t = 0; t < 16; t++) { asv[t] = as[t * 16 + l15]; adv[t] = ad[t * 16 + l15]; }
  #pragma unroll
  for (int reg = 0; reg < 4; reg++) {
    int row = r0 + quad * 4 + reg;
    bool ok = row < NT;
    float vs[4] = {0.f, 0.f, 0.f, 0.f}, vd[4] = {0.f, 0.f, 0.f, 0.f};
    #pragma unroll
    for (int t = 0; t < 16; t++) {
      float v = acc[t][reg];
      if (ok) xl[(size_t)row * HE + t * 16 + l15] = __float2bfloat16(v);
      vs[t >> 2] += v * asv[t];
      vd[t >> 2] += v * adv[t];
    }
    #pragma unroll
    for (int off = 8; off; off >>= 1) {
      #pragma unroll
      for (int h = 0; h < 4; h++) {
        vs[h] += __shfl_xor(vs[h], off, 64);
        vd[h] += __shfl_xor(vd[h], off, 64);
      }
    }
    if (ok && l15 == 0) {
      float4 s4; s4.x = vs[0]; s4.y = vs[1]; s4.z = vs[2]; s4.w = vs[3];
      float4 d4; d4.x = vd[0]; d4.y = vd[1]; d4.z = vd[2]; d4.w = vd[3];
      *(float4*)(a_src + (size_t)row * 4) = s4;
      *(float4*)(a_dst + (size_t)row * 4) = d4;
    }
  }
}

// a_edg in CSR order: Mmat computed per-block in LDS, value scattered to pos[e]
__global__ __launch_bounds__(256) void k_a_edg(const float* __restrict__ ea,
    const float* __restrict__ msum, const float* __restrict__ We,
    const float* __restrict__ ae, const int* __restrict__ pos,
    float* __restrict__ aedg_csr) {
  __shared__ float Ms[32];
  int t = threadIdx.x;
  if (t < 32) {
    int k = t >> 2, hh = t & 3;
    float s = 0.f;
    #pragma unroll
    for (int d = 0; d < 64; d++) s += We[k * HE + hh * 64 + d] * ae[hh * 64 + d];
    Ms[t] = s;
  }
  __syncthreads();
  int e = blockIdx.x * 256 + t;
  if (e >= ET) return;
  float v[8];
  if (e < NE) {
    const float4* p = (const float4*)(ea + (size_t)e * 8);
    float4 x0 = p[0], x1 = p[1];
    v[0] = x0.x; v[1] = x0.y; v[2] = x0.z; v[3] = x0.w;
    v[4] = x1.x; v[5] = x1.y; v[6] = x1.z; v[7] = x1.w;
  } else {
    #pragma unroll
    for (int k = 0; k < 8; k++) v[k] = msum[k] * (1.f / NE);
  }
  float rr[4];
  #pragma unroll
  for (int h = 0; h < 4; h++) {
    float s = 0.f;
    #pragma unroll
    for (int k = 0; k < 8; k++) s += v[k] * Ms[k * 4 + h];
    rr[h] = s;
  }
  float4 r; r.x = rr[0]; r.y = rr[1]; r.z = rr[2]; r.w = rr[3];
  *(float4*)(aedg_csr + (size_t)pos[e] * 4) = r;
}

// fused softmax + aggregate: one wave per node, 16-edge chunks.
// phase A: lane=(head,edge16): al + 16-lane shuffle max/sum, chunk-online rescale
// phase B: lane owns dims 4L..4L+3 (head L>>4): one dwordx2 gather per edge
__global__ __launch_bounds__(256) void k_attn(
    const __hip_bfloat16* __restrict__ xl, const float* __restrict__ a_src,
    const float* __restrict__ a_dst, const float* __restrict__ aedg_csr,
    const int* __restrict__ indptr, const int* __restrict__ srcs,
    const float* __restrict__ gb, __hip_bfloat16* __restrict__ agg) {
  int node = blockIdx.x * 4 + (threadIdx.x >> 6);
  int lane = threadIdx.x & 63;
  int h = lane >> 4;
  int hbase = lane & 48;
  int e15 = lane & 15;
  int beg = indptr[node], end = indptr[node + 1];
  float adh = a_dst[node * 4 + h];
  float M = -1e30f, S = 0.f;
  float acc0 = 0.f, acc1 = 0.f, acc2 = 0.f, acc3 = 0.f;
  for (int base = beg; base < end; base += 16) {
    int cnt = min(16, end - base);
    int el = base + e15;
    bool ok = e15 < cnt;
    int my_src = ok ? srcs[el] : 0;
    float aer = ok ? aedg_csr[(size_t)el * 4 + h] : 0.f;
    float asr = ok ? a_src[(size_t)my_src * 4 + h] : 0.f;
    float al = asr + adh + aer;
    al = (al > 0.f) ? al : 0.2f * al;
    if (!ok) al = -1e30f;
    float cm = al;
    #pragma unroll
    for (int off = 1; off < 16; off <<= 1) cm = fmaxf(cm, __shfl_xor(cm, off, 64));
    float newM = fmaxf(M, cm);
    float corr = __expf(M - newM);
    float ex = __expf(al - newM);
    float cs = ex;
    #pragma unroll
    for (int off = 1; off < 16; off <<= 1) cs += __shfl_xor(cs, off, 64);
    S = S * corr + cs;
    M = newM;
    acc0 *= corr; acc1 *= corr; acc2 *= corr; acc3 *= corr;
    if (cnt == 16) {
      #pragma unroll 4
      for (int j = 0; j < 16; j++) {
        int src = __shfl(my_src, j, 64);
        float cf = __shfl(ex, hbase | j, 64);
        uint2 u = *(const uint2*)(xl + (size_t)src * HE + lane * 4);
        acc0 += cf * bf_lo(u.x);
        acc1 += cf * bf_hi(u.x);
        acc2 += cf * bf_lo(u.y);
        acc3 += cf * bf_hi(u.y);
      }
    } else {
      for (int j = 0; j < cnt; j++) {
        int src = __shfl(my_src, j, 64);
        float cf = __shfl(ex, hbase | j, 64);
        uint2 u = *(const uint2*)(xl + (size_t)src * HE + lane * 4);
        acc0 += cf * bf_lo(u.x);
        acc1 += cf * bf_hi(u.x);
        acc2 += cf * bf_lo(u.y);
        acc3 += cf * bf_hi(u.y);
      }
    }
  }
  float inv = 1.f / (S + 1e-16f);
  float4 g4 = *(const float4*)(gb + lane * 4);
  unsigned int o0 = __bfloat16_as_ushort(__float2bfloat16(acc0 * inv + g4.x));
  unsigned int o1 = __bfloat16_as_ushort(__float2bfloat16(acc1 * inv + g4.y));
  unsigned int o2 = __bfloat16_as_ushort(__float2bfloat16(acc2 * inv + g4.z));
  unsigned int o3 = __bfloat16_as_ushort(__float2bfloat16(acc3 * inv + g4.w));
  uint2 out; out.x = o0 | (o1 << 16); out.y = o2 | (o3 << 16);
  *(uint2*)(agg + (size_t)node * HE + lane * 4) = out;
}

// proj GEMM via MFMA + fused bias/ELU/residual/LN
__global__ __launch_bounds__(256) void k_proj_mfma(
    const __hip_bfloat16* __restrict__ agg, const __hip_bfloat16* __restrict__ Wf,
    const float* __restrict__ pb, const float* __restrict__ g, const float* __restrict__ b,
    const float* __restrict__ ht_in, float* __restrict__ ht_out,
    __hip_bfloat16* __restrict__ htb_out, int writebf) {
  int lane = threadIdx.x & 63, wave = threadIdx.x >> 6;
  int quad = lane >> 4, l15 = lane & 15;
  int r0 = blockIdx.x * 64 + wave * 16;
  f32x4 acc[4];
  #pragma unroll
  for (int t = 0; t < 4; t++) acc[t] = (f32x4){0.f, 0.f, 0.f, 0.f};
  #pragma unroll
  for (int kb = 0; kb < 8; kb++) {
    bf16x8 a = *(const bf16x8*)(agg + (size_t)(r0 + l15) * HE + kb * 32 + quad * 8);
    #pragma unroll
    for (int t = 0; t < 4; t++) {
      bf16x8 bfr = *(const bf16x8*)(Wf + (size_t)((t * 8 + kb) * 64 + lane) * 8);
      acc[t] = __builtin_amdgcn_mfma_f32_16x16x32_bf16(a, bfr, acc[t], 0, 0, 0);
    }
  }
  float pbv[4], gv[4], bv[4];
  #pragma unroll
  for (int t = 0; t < 4; t++) {
    pbv[t] = pb[t * 16 + l15];
    gv[t] = g[t * 16 + l15];
    bv[t] = b[t * 16 + l15];
  }
  #pragma unroll
  for (int reg = 0; reg < 4; reg++) {
    int row = r0 + quad * 4 + reg;
    bool ok = row < NT;
    float h[4], rs = 0.f;
    #pragma unroll
    for (int t = 0; t < 4; t++) {
      float u = acc[t][reg] + pbv[t];
      u = (u > 0.f) ? u : (__expf(u) - 1.f);
      h[t] = ht_in[(size_t)row * 64 + t * 16 + l15] + u;
      rs += h[t];
    }
    #pragma unroll
    for (int off = 8; off; off >>= 1) rs += __shfl_xor(rs, off, 64);
    float mu = rs * 0.015625f;
    float vv = 0.f;
    #pragma unroll
    for (int t = 0; t < 4; t++) { float d = h[t] - mu; vv += d * d; }
    #pragma unroll
    for (int off = 8; off; off >>= 1) vv += __shfl_xor(vv, off, 64);
    float rstd = rsqrtf(vv * 0.015625f + 1e-5f);
    #pragma unroll
    for (int t = 0; t < 4; t++) {
      float o = (h[t] - mu) * rstd * gv[t] + bv[t];
      if (ok) {
        ht_out[(size_t)row * 64 + t * 16 + l15] = o;
        if (writebf) htb_out[(size_t)row * 64 + t * 16 + l15] = __float2bfloat16(o);
      }
    }
  }
}

// ---------------- heads ----------------
__global__ __launch_bounds__(256) void k_task_head(const float* __restrict__ ht,
    const float* __restrict__ W1, const float* __restrict__ b1,
    const float* __restrict__ W2, const float* __restrict__ b2, float* __restrict__ logits) {
  __shared__ float lh[8 * 64];
  int t = threadIdx.x;
  size_t base = (size_t)blockIdx.x * 8 * 64;
  lh[t] = ht[base + t];
  lh[t + 256] = ht[base + t + 256];
  __syncthreads();
  int i = t >> 5, j = t & 31;
  float s = b1[j];
  #pragma unroll 8
  for (int d = 0; d < 64; d++) s += lh[i * 64 + d] * W1[d * 32 + j];
  s = fmaxf(s, 0.f);
  float p = s * W2[j];
  #pragma unroll
  for (int off = 16; off; off >>= 1) p += __shfl_xor(p, off, 64);
  if (j == 0) logits[blockIdx.x * 8 + i] = p + b2[0];
}

__global__ __launch_bounds__(256) void k_pool_task(const float* __restrict__ ht,
    const int* __restrict__ tb, float* __restrict__ sums, float* __restrict__ cnt) {
  int lane = threadIdx.x & 63, sub = threadIdx.x >> 6;
  float acc[8], c[8];
  #pragma unroll
  for (int g = 0; g < 8; g++) { acc[g] = 0.f; c[g] = 0.f; }
  int lim = min(NT, (int)((blockIdx.x + 1) * 512));
  for (int n = blockIdx.x * 512 + sub; n < lim; n += 4) {
    int g = tb[n];
    float v = ht[(size_t)n * 64 + lane];
    #pragma unroll
    for (int gg = 0; gg < 8; gg++) {
      if (g == gg) { acc[gg] += v; c[gg] += 1.f; }
    }
  }
  #pragma unroll
  for (int g = 0; g < 8; g++) {
    if (__any(acc[g] != 0.f || c[g] != 0.f)) {
      atomicAdd(&sums[g * 64 + lane], acc[g]);
      if (lane == 0) atomicAdd(&cnt[g], c[g]);
    }
  }
}

__global__ __launch_bounds__(512) void k_value(const float* __restrict__ tpsum,
    const float* __restrict__ tpcnt, const float* __restrict__ hp,
    const int* __restrict__ pbatch, const float* __restrict__ vW1,
    const float* __restrict__ vb1, const float* __restrict__ vW2,
    const float* __restrict__ vb2, float* __restrict__ val_out) {
  __shared__ float ge[8 * 128];
  int t = threadIdx.x;
  int g = t >> 6, d = t & 63;
  float c = fmaxf(tpcnt[g], 1.f);
  ge[g * 128 + d] = tpsum[g * 64 + d] / c;
  float s = 0.f, cc = 0.f;
  for (int p = 0; p < 256; p++) {
    int bg = pbatch[p];
    if (bg == g) { s += hp[(size_t)p * 64 + d]; cc += 1.f; }
  }
  ge[g * 128 + 64 + d] = s / fmaxf(cc, 1.f);
  __syncthreads();
  float acc = vb1[d];
  #pragma unroll 8
  for (int k = 0; k < 128; k++) acc += ge[g * 128 + k] * vW1[k * 64 + d];
  acc = fmaxf(acc, 0.f);
  float p = acc * vW2[d];
  #pragma unroll
  for (int off = 32; off; off >>= 1) p += __shfl_xor(p, off, 64);
  if (d == 0) val_out[g] = p + vb2[0];
}

extern "C" void kernel_launch(void* const* d_in, const int* in_sizes, int n_in,
                              void* d_out, int out_size, void* d_ws, size_t ws_size,
                              hipStream_t stream) {
  (void)in_sizes; (void)n_in; (void)out_size; (void)ws_size;
  const float* x_task  = (const float*)d_in[0];
  const float* x_proc  = (const float*)d_in[1];
  const int*   eidx    = (const int*)d_in[2];
  const float* eattr   = (const float*)d_in[3];
  const int*   tbatch  = (const int*)d_in[4];
  const int*   pbatch  = (const int*)d_in[5];
  const float* W_task  = (const float*)d_in[6];
  const float* b_task  = (const float*)d_in[7];
  const float* W_proc  = (const float*)d_in[8];
  const float* b_proc  = (const float*)d_in[9];
  const float* gat_W   = (const float*)d_in[10];
  const float* gat_We  = (const float*)d_in[11];
  const float* att_src = (const float*)d_in[12];
  const float* att_dst = (const float*)d_in[13];
  const float* att_edge= (const float*)d_in[14];
  const float* gat_b   = (const float*)d_in[15];
  const float* proj_W  = (const float*)d_in[16];
  const float* proj_b  = (const float*)d_in[17];
  const float* ln_g    = (const float*)d_in[18];
  const float* ln_b    = (const float*)d_in[19];
  const float* pt_W1   = (const float*)d_in[20];
  const float* pt_b1   = (const float*)d_in[21];
  const float* pt_W2   = (const float*)d_in[22];
  const float* pt_b2   = (const float*)d_in[23];
  const float* v_W1    = (const float*)d_in[24];
  const float* v_b1    = (const float*)d_in[25];
  const float* v_W2    = (const float*)d_in[26];
  const float* v_b2    = (const float*)d_in[27];

  char* ws = (char*)d_ws;
  int*   deg    = (int*)(ws + OFF_DEG);
  int*   indptr = (int*)(ws + OFF_INDPTR);
  int*   cursor = (int*)(ws + OFF_CURSOR);
  int*   pos    = (int*)(ws + OFF_POS);
  int*   srcs   = (int*)(ws + OFF_SRCS);
  float* msum   = (float*)(ws + OFF_MEAN);
  float* tpsum  = (float*)(ws + OFF_TPSUM);
  float* tpcnt  = (float*)(ws + OFF_TPCNT);
  float* a_src  = (float*)(ws + OFF_ASRC);
  float* a_dst  = (float*)(ws + OFF_ADST);
  float* a_edg  = (float*)(ws + OFF_AEDG);
  float* ht     = (float*)(ws + OFF_HT);
  __hip_bfloat16* htb = (__hip_bfloat16*)(ws + OFF_HTB);
  __hip_bfloat16* xl  = (__hip_bfloat16*)(ws + OFF_XL);
  __hip_bfloat16* agg = (__hip_bfloat16*)(ws + OFF_AGG);
  __hip_bfloat16* wxf = (__hip_bfloat16*)(ws + OFF_WXF);
  __hip_bfloat16* wpf = (__hip_bfloat16*)(ws + OFF_WPF);

  float* out_logits = (float*)d_out;
  float* out_value  = (float*)d_out + NT;
  float* out_ht     = (float*)d_out + NT + NG;
  float* out_hp     = (float*)d_out + NT + NG + (size_t)NT * EMBD;

  hipMemsetAsync(ws + OFF_DEG, 0, NT * 4, stream);
  hipMemsetAsync(ws + OFF_MEAN, 0, 2816, stream);  // msum + (unused) + tpsum + tpcnt

  k_embed_task<<<782, 256, 0, stream>>>(x_task, W_task, b_task, ht, htb);
  k_embed_proc<<<1, 256, 0, stream>>>(x_proc, W_proc, b_proc, out_hp);
  k_edge_mean<<<256, 256, 0, stream>>>(eattr, msum);
  k_degree<<<(ET + 255) / 256, 256, 0, stream>>>(eidx + NE, deg);
  k_scan<<<1, 1024, 0, stream>>>(deg, indptr, cursor);
  k_fill<<<(ET + 255) / 256, 256, 0, stream>>>(eidx, eidx + NE, cursor, pos, srcs);
  k_prep_wx<<<96, 64, 0, stream>>>(gat_W, wxf);
  k_prep_wp<<<96, 64, 0, stream>>>(proj_W, wpf);

  for (int l = 0; l < 3; l++) {
    k_xl_mfma<<<782, 256, 0, stream>>>(htb, wxf + (size_t)l * 16384,
                                       att_src + l * NHEADS * EMBD,
                                       att_dst + l * NHEADS * EMBD,
                                       xl, a_src, a_dst);
    k_a_edg<<<(ET + 255) / 256, 256, 0, stream>>>(eattr, msum,
                                                  gat_We + (size_t)l * 8 * HE,
                                                  att_edge + l * NHEADS * EMBD,
                                                  pos, a_edg);
    k_attn<<<NT / 4, 256, 0, stream>>>(xl, a_src, a_dst, a_edg, indptr, srcs,
                                       gat_b + l * HE, agg);
    float* htout = (l == 2) ? out_ht : ht;
    k_proj_mfma<<<782, 256, 0, stream>>>(agg, wpf + (size_t)l * 16384,
                                         proj_b + l * EMBD, ln_g + l * EMBD,
                                         ln_b + l * EMBD, ht, htout, htb,
                                         (l == 2) ? 0 : 1);
  }

  k_task_head<<<NT / 8, 256, 0, stream>>>(out_ht, pt_W1, pt_b1, pt_W2, pt_b2, out_logits);
  k_pool_task<<<(NT + 511) / 512, 256, 0, stream>>>(out_ht, tbatch, tpsum, tpcnt);
  k_value<<<1, 512, 0, stream>>>(tpsum, tpcnt, out_hp, pbatch, v_W1, v_b1, v_W2, v_b2, out_value);
}

// Round 6
// 720.482 us; speedup vs baseline: 2.2778x; 1.0668x over previous
//
#include <hip/hip_runtime.h>
#include <hip/hip_bf16.h>
#include <math.h>

#define NT 50000
#define NP 256
#define NE 800000
#define ET 850000   // NE + NT self loops
#define EMBD 64
#define NHEADS 4
#define HE 256      // NHEADS*EMBD
#define NG 8
#define NBLK 49     // scan blocks of 1024

typedef __attribute__((ext_vector_type(8))) short bf16x8;
typedef __attribute__((ext_vector_type(4))) float f32x4;

// ---- workspace layout (bytes) ----
#define OFF_DEG    0u          // 50000 i32
#define OFF_INDPTR 200192u     // 50001 i32
#define OFF_CURSOR 400384u     // 50000 i32
#define OFF_BLKSUM 600576u     // 64 i32
#define OFF_MG     600832u     // 96 f32 (3 layers x 32: M[k][h])
#define OFF_MH     601216u     // 12 f32 (3 layers x 4: mean-edge per head)
#define OFF_MEAN   601280u     // 8 f32 msum        <- memset zone start
#define OFF_TPSUM  601344u     // 512 f32
#define OFF_TPCNT  603392u     // 8 f32             <- memset zone end (2144 B)
#define OFF_ER     603648u     // 850000 uint2 (CSR: edge id, src)
#define OFF_ASRC   7403648u    // 50048*4 f32
#define OFF_ADST   8204416u    // 50048*4 f32
#define OFF_HT     9005184u    // 50048*64 f32
#define OFF_HTB    21817472u   // 50048*64 bf16
#define OFF_XL     28223616u   // 50000*256 bf16
#define OFF_AGG    53823616u   // 50048*256 bf16
#define OFF_WXF    79448192u   // 3*16384 bf16
#define OFF_WPF    79546496u   // 3*16384 bf16
// total ~79.6 MB

__device__ __forceinline__ float bf_lo(unsigned int u) {
  union { unsigned int i; float f; } v; v.i = u << 16; return v.f;
}
__device__ __forceinline__ float bf_hi(unsigned int u) {
  union { unsigned int i; float f; } v; v.i = u & 0xffff0000u; return v.f;
}

// ---------------- input embed (task) ----------------
__global__ __launch_bounds__(256) void k_embed_task(const float* __restrict__ x,
    const float* __restrict__ W, const float* __restrict__ b,
    float* __restrict__ ht, __hip_bfloat16* __restrict__ htb) {
  int lane = threadIdx.x & 63, wid = threadIdx.x >> 6;
  float breg[16];
  #pragma unroll
  for (int k = 0; k < 16; k++) breg[k] = W[k * 64 + lane];
  float bias = b[lane];
  int row0 = blockIdx.x * 64 + wid * 16;
  #pragma unroll 1
  for (int r = 0; r < 16; r++) {
    int row = row0 + r;
    if (row >= NT) return;
    const float4* xr = (const float4*)(x + (size_t)row * 16);
    float acc = bias;
    #pragma unroll
    for (int q = 0; q < 4; q++) {
      float4 v = xr[q];
      acc += v.x * breg[q*4+0] + v.y * breg[q*4+1] + v.z * breg[q*4+2] + v.w * breg[q*4+3];
    }
    ht[(size_t)row * 64 + lane] = acc;
    htb[(size_t)row * 64 + lane] = __float2bfloat16(acc);
  }
}

// ---------------- degree + edge_attr mean (fused) ----------------
__global__ __launch_bounds__(256) void k_degree_mean(const int* __restrict__ ei1,
    const float* __restrict__ ea, int* __restrict__ deg, float* __restrict__ sums) {
  __shared__ float lds[256];
  int tid = threadIdx.x;
  int e = blockIdx.x * 256 + tid;
  if (e < ET) {
    int d = (e < NE) ? ei1[e] : (e - NE);
    atomicAdd(&deg[d], 1);
  }
  int k = tid & 7, rl = tid >> 3;
  float s = 0.f;
  for (int row = blockIdx.x * 32 + rl; row < NE; row += gridDim.x * 32)
    s += ea[(size_t)row * 8 + k];
  lds[tid] = s;
  __syncthreads();
  for (int off = 128; off >= 8; off >>= 1) {
    if (tid < off) lds[tid] += lds[tid + off];
    __syncthreads();
  }
  if (tid < 8) atomicAdd(&sums[tid], lds[tid]);
}

// ---------------- parallel scan (2 kernels) ----------------
__global__ __launch_bounds__(1024) void k_scanA(const int* __restrict__ deg,
    int* __restrict__ indptr, int* __restrict__ blksum) {
  __shared__ int wsum[16];
  int tid = threadIdx.x, lane = tid & 63, wid = tid >> 6;
  int i = blockIdx.x * 1024 + tid;
  int v = (i < NT) ? deg[i] : 0;
  int x = v;
  #pragma unroll
  for (int off = 1; off < 64; off <<= 1) {
    int t = __shfl_up(x, off, 64);
    if (lane >= off) x += t;
  }
  if (lane == 63) wsum[wid] = x;
  __syncthreads();
  if (wid == 0 && lane < 16) {
    int w = wsum[lane];
    #pragma unroll
    for (int off = 1; off < 16; off <<= 1) {
      int t = __shfl_up(w, off, 64);
      if (lane >= off) w += t;
    }
    wsum[lane] = w;  // inclusive
  }
  __syncthreads();
  int woff = (wid == 0) ? 0 : wsum[wid - 1];
  if (i < NT) indptr[i] = x + woff - v;   // block-local exclusive
  if (tid == 1023) blksum[blockIdx.x] = wsum[15];
}

__global__ __launch_bounds__(1024) void k_scanB(const int* __restrict__ blksum,
    int* __restrict__ indptr, int* __restrict__ cursor) {
  __shared__ int bs[NBLK];
  int tid = threadIdx.x;
  if (tid < NBLK) bs[tid] = blksum[tid];
  __syncthreads();
  int off = 0;
  for (int j = 0; j < (int)blockIdx.x; j++) off += bs[j];
  int i = blockIdx.x * 1024 + tid;
  if (i < NT) {
    int e = indptr[i] + off;
    indptr[i] = e;
    cursor[i] = e;
  }
  if (blockIdx.x == 0 && tid == 0) {
    int tot = 0;
    for (int j = 0; j < NBLK; j++) tot += bs[j];
    indptr[NT] = tot;
  }
}

// ---------------- CSR fill: er[p] = (edge id, src) ----------------
__global__ __launch_bounds__(256) void k_fill(const int* __restrict__ ei0,
                                              const int* __restrict__ ei1,
                                              int* __restrict__ cursor,
                                              uint2* __restrict__ er) {
  int e = blockIdx.x * 256 + threadIdx.x;
  if (e >= ET) return;
  int d, s;
  if (e < NE) { d = ei1[e]; s = ei0[e]; } else { d = e - NE; s = e - NE; }
  int p = atomicAdd(&cursor[d], 1);
  uint2 r; r.x = (unsigned)e; r.y = (unsigned)s;
  er[p] = r;
}

// ---------------- M matrices for edge attention (all 3 layers) ----------------
__global__ __launch_bounds__(128) void k_mprep(const float* __restrict__ We,
    const float* __restrict__ ae, const float* __restrict__ msum,
    float* __restrict__ Mg, float* __restrict__ Mh) {
  int t = threadIdx.x;
  if (t < 96) {
    int l = t >> 5, idx = t & 31, k = idx >> 2, h = idx & 3;
    const float* Wl = We + (size_t)l * 8 * HE;
    const float* al = ae + (size_t)l * NHEADS * EMBD;
    float s = 0.f;
    #pragma unroll
    for (int d = 0; d < 64; d++) s += Wl[k * HE + h * 64 + d] * al[h * 64 + d];
    Mg[t] = s;
  }
  __syncthreads();
  if (t < 12) {
    int l = t >> 2, h = t & 3;
    float m = 0.f;
    #pragma unroll
    for (int k = 0; k < 8; k++) m += msum[k] * (1.f / NE) * Mg[l * 32 + k * 4 + h];
    Mh[t] = m;
  }
}

// ---------------- weight fragment prep (fused xl+proj) ----------------
__global__ void k_prep_w(const float* __restrict__ Wx, const float* __restrict__ Wp,
                         __hip_bfloat16* __restrict__ Wxf, __hip_bfloat16* __restrict__ Wpf) {
  int lane = threadIdx.x;
  int bid = blockIdx.x;
  int quad = lane >> 4, l15 = lane & 15;
  if (bid < 96) {
    int l = bid >> 5, rem = bid & 31, t = rem >> 1, kb = rem & 1;
    const float* Wl = Wx + (size_t)l * 64 * 256;
    __hip_bfloat16* out = Wxf + (size_t)l * 16384 + (size_t)((t * 2 + kb) * 64 + lane) * 8;
    #pragma unroll
    for (int j = 0; j < 8; j++)
      out[j] = __float2bfloat16(Wl[(kb * 32 + quad * 8 + j) * 256 + t * 16 + l15]);
  } else {
    bid -= 96;
    int l = bid >> 5, rem = bid & 31, t = rem >> 3, kb = rem & 7;
    const float* Wl = Wp + (size_t)l * 256 * 64;
    __hip_bfloat16* out = Wpf + (size_t)l * 16384 + (size_t)((t * 8 + kb) * 64 + lane) * 8;
    #pragma unroll
    for (int j = 0; j < 8; j++)
      out[j] = __float2bfloat16(Wl[(kb * 32 + quad * 8 + j) * 64 + t * 16 + l15]);
  }
}

// ---------------- per-layer kernels ----------------
// xl = htb @ W via MFMA + fused a_src/a_dst
__global__ __launch_bounds__(256) void k_xl_mfma(
    const __hip_bfloat16* __restrict__ htb, const __hip_bfloat16* __restrict__ Wf,
    const float* __restrict__ as, const float* __restrict__ ad,
    __hip_bfloat16* __restrict__ xl, float* __restrict__ a_src, float* __restrict__ a_dst) {
  int lane = threadIdx.x & 63, wave = threadIdx.x >> 6;
  int quad = lane >> 4, l15 = lane & 15;
  int r0 = blockIdx.x * 64 + wave * 16;
  f32x4 acc[16];
  #pragma unroll
  for (int t = 0; t < 16; t++) acc[t] = (f32x4){0.f, 0.f, 0.f, 0.f};
  #pragma unroll
  for (int kb = 0; kb < 2; kb++) {
    bf16x8 a = *(const bf16x8*)(htb + (size_t)(r0 + l15) * 64 + kb * 32 + quad * 8);
    #pragma unroll
    for (int t = 0; t < 16; t++) {
      bf16x8 bfr = *(const bf16x8*)(Wf + (size_t)((t * 2 + kb) * 64 + lane) * 8);
      acc[t] = __builtin_amdgcn_mfma_f32_16x16x32_bf16(a, bfr, acc[t], 0, 0, 0);
    }
  }
  float asv[16], adv[16];
  #pragma unroll
  for (int t = 0; t < 16; t++) { asv[t] = as[t * 16 + l15]; adv[t] = ad[t * 16 + l15]; }
  #pragma unroll
  for (int reg = 0; reg < 4; reg++) {
    int row = r0 + quad * 4 + reg;
    bool ok = row < NT;
    float vs[4] = {0.f, 0.f, 0.f, 0.f}, vd[4] = {0.f, 0.f, 0.f, 0.f};
    #pragma unroll
    for (int t = 0; t < 16; t++) {
      float v = acc[t][reg];
      if (ok) xl[(size_t)row * HE + t * 16 + l15] = __float2bfloat16(v);
      vs[t >> 2] += v * asv[t];
      vd[t >> 2] += v * adv[t];
    }
    #pragma unroll
    for (int off = 8; off; off >>= 1) {
      #pragma unroll
      for (int h = 0; h < 4; h++) {
        vs[h] += __shfl_xor(vs[h], off, 64);
        vd[h] += __shfl_xor(vd[h], off, 64);
      }
    }
    if (ok && l15 == 0) {
      float4 s4; s4.x = vs[0]; s4.y = vs[1]; s4.z = vs[2]; s4.w = vs[3];
      float4 d4; d4.x = vd[0]; d4.y = vd[1]; d4.z = vd[2]; d4.w = vd[3];
      *(float4*)(a_src + (size_t)row * 4) = s4;
      *(float4*)(a_dst + (size_t)row * 4) = d4;
    }
  }
}

// fused a_edg + softmax + aggregate: one wave per node, 16-edge chunks
__global__ __launch_bounds__(256) void k_attn(
    const __hip_bfloat16* __restrict__ xl, const float* __restrict__ a_src,
    const float* __restrict__ a_dst, const float* __restrict__ ea,
    const uint2* __restrict__ er, const int* __restrict__ indptr,
    const float* __restrict__ Mg, const float* __restrict__ Mh,
    const float* __restrict__ gb, __hip_bfloat16* __restrict__ agg) {
  int node = blockIdx.x * 4 + (threadIdx.x >> 6);
  int lane = threadIdx.x & 63;
  int h = lane >> 4;
  int hbase = lane & 48;
  int e15 = lane & 15;
  float MsR[8];
  #pragma unroll
  for (int k = 0; k < 8; k++) MsR[k] = Mg[k * 4 + h];
  float mhR = Mh[h];
  int beg = indptr[node], end = indptr[node + 1];
  float adh = a_dst[node * 4 + h];
  float M = -1e30f, S = 0.f;
  float acc0 = 0.f, acc1 = 0.f, acc2 = 0.f, acc3 = 0.f;
  for (int base = beg; base < end; base += 16) {
    int cnt = min(16, end - base);
    int el = base + e15;
    bool ok = e15 < cnt;
    uint2 r = ok ? er[el] : (uint2){0u, 0u};
    int e = (int)r.x;
    int my_src = (int)r.y;
    float asr = ok ? a_src[(size_t)my_src * 4 + h] : 0.f;
    float aeh;
    if (e < NE) {
      const float4* p = (const float4*)(ea + (size_t)e * 8);
      float4 v0 = p[0], v1 = p[1];
      aeh = v0.x * MsR[0] + v0.y * MsR[1] + v0.z * MsR[2] + v0.w * MsR[3]
          + v1.x * MsR[4] + v1.y * MsR[5] + v1.z * MsR[6] + v1.w * MsR[7];
    } else {
      aeh = mhR;
    }
    float al = asr + adh + aeh;
    al = (al > 0.f) ? al : 0.2f * al;
    if (!ok) al = -1e30f;
    float cm = al;
    #pragma unroll
    for (int off = 1; off < 16; off <<= 1) cm = fmaxf(cm, __shfl_xor(cm, off, 64));
    float newM = fmaxf(M, cm);
    float corr = __expf(M - newM);
    float ex = __expf(al - newM);
    float cs = ex;
    #pragma unroll
    for (int off = 1; off < 16; off <<= 1) cs += __shfl_xor(cs, off, 64);
    S = S * corr + cs;
    M = newM;
    acc0 *= corr; acc1 *= corr; acc2 *= corr; acc3 *= corr;
    if (cnt == 16) {
      #pragma unroll 4
      for (int j = 0; j < 16; j++) {
        int src = __shfl(my_src, j, 64);
        float cf = __shfl(ex, hbase | j, 64);
        uint2 u = *(const uint2*)(xl + (size_t)src * HE + lane * 4);
        acc0 += cf * bf_lo(u.x);
        acc1 += cf * bf_hi(u.x);
        acc2 += cf * bf_lo(u.y);
        acc3 += cf * bf_hi(u.y);
      }
    } else {
      for (int j = 0; j < cnt; j++) {
        int src = __shfl(my_src, j, 64);
        float cf = __shfl(ex, hbase | j, 64);
        uint2 u = *(const uint2*)(xl + (size_t)src * HE + lane * 4);
        acc0 += cf * bf_lo(u.x);
        acc1 += cf * bf_hi(u.x);
        acc2 += cf * bf_lo(u.y);
        acc3 += cf * bf_hi(u.y);
      }
    }
  }
  float inv = 1.f / (S + 1e-16f);
  float4 g4 = *(const float4*)(gb + lane * 4);
  unsigned int o0 = __bfloat16_as_ushort(__float2bfloat16(acc0 * inv + g4.x));
  unsigned int o1 = __bfloat16_as_ushort(__float2bfloat16(acc1 * inv + g4.y));
  unsigned int o2 = __bfloat16_as_ushort(__float2bfloat16(acc2 * inv + g4.z));
  unsigned int o3 = __bfloat16_as_ushort(__float2bfloat16(acc3 * inv + g4.w));
  uint2 out; out.x = o0 | (o1 << 16); out.y = o2 | (o3 << 16);
  *(uint2*)(agg + (size_t)node * HE + lane * 4) = out;
}

// proj GEMM via MFMA + fused bias/ELU/residual/LN
__global__ __launch_bounds__(256) void k_proj_mfma(
    const __hip_bfloat16* __restrict__ agg, const __hip_bfloat16* __restrict__ Wf,
    const float* __restrict__ pb, const float* __restrict__ g, const float* __restrict__ b,
    const float* __restrict__ ht_in, float* __restrict__ ht_out,
    __hip_bfloat16* __restrict__ htb_out, int writebf) {
  int lane = threadIdx.x & 63, wave = threadIdx.x >> 6;
  int quad = lane >> 4, l15 = lane & 15;
  int r0 = blockIdx.x * 64 + wave * 16;
  f32x4 acc[4];
  #pragma unroll
  for (int t = 0; t < 4; t++) acc[t] = (f32x4){0.f, 0.f, 0.f, 0.f};
  #pragma unroll
  for (int kb = 0; kb < 8; kb++) {
    bf16x8 a = *(const bf16x8*)(agg + (size_t)(r0 + l15) * HE + kb * 32 + quad * 8);
    #pragma unroll
    for (int t = 0; t < 4; t++) {
      bf16x8 bfr = *(const bf16x8*)(Wf + (size_t)((t * 8 + kb) * 64 + lane) * 8);
      acc[t] = __builtin_amdgcn_mfma_f32_16x16x32_bf16(a, bfr, acc[t], 0, 0, 0);
    }
  }
  float pbv[4], gv[4], bv[4];
  #pragma unroll
  for (int t = 0; t < 4; t++) {
    pbv[t] = pb[t * 16 + l15];
    gv[t] = g[t * 16 + l15];
    bv[t] = b[t * 16 + l15];
  }
  #pragma unroll
  for (int reg = 0; reg < 4; reg++) {
    int row = r0 + quad * 4 + reg;
    bool ok = row < NT;
    float h[4], rs = 0.f;
    #pragma unroll
    for (int t = 0; t < 4; t++) {
      float u = acc[t][reg] + pbv[t];
      u = (u > 0.f) ? u : (__expf(u) - 1.f);
      h[t] = ht_in[(size_t)row * 64 + t * 16 + l15] + u;
      rs += h[t];
    }
    #pragma unroll
    for (int off = 8; off; off >>= 1) rs += __shfl_xor(rs, off, 64);
    float mu = rs * 0.015625f;
    float vv = 0.f;
    #pragma unroll
    for (int t = 0; t < 4; t++) { float d = h[t] - mu; vv += d * d; }
    #pragma unroll
    for (int off = 8; off; off >>= 1) vv += __shfl_xor(vv, off, 64);
    float rstd = rsqrtf(vv * 0.015625f + 1e-5f);
    #pragma unroll
    for (int t = 0; t < 4; t++) {
      float o = (h[t] - mu) * rstd * gv[t] + bv[t];
      if (ok) {
        ht_out[(size_t)row * 64 + t * 16 + l15] = o;
        if (writebf) htb_out[(size_t)row * 64 + t * 16 + l15] = __float2bfloat16(o);
      }
    }
  }
}

// ---------------- heads ----------------
__global__ __launch_bounds__(256) void k_task_head(const float* __restrict__ ht,
    const float* __restrict__ W1, const float* __restrict__ b1,
    const float* __restrict__ W2, const float* __restrict__ b2, float* __restrict__ logits) {
  __shared__ float lh[8 * 64];
  int t = threadIdx.x;
  size_t base = (size_t)blockIdx.x * 8 * 64;
  lh[t] = ht[base + t];
  lh[t + 256] = ht[base + t + 256];
  __syncthreads();
  int i = t >> 5, j = t & 31;
  float s = b1[j];
  #pragma unroll 8
  for (int d = 0; d < 64; d++) s += lh[i * 64 + d] * W1[d * 32 + j];
  s = fmaxf(s, 0.f);
  float p = s * W2[j];
  #pragma unroll
  for (int off = 16; off; off >>= 1) p += __shfl_xor(p, off, 64);
  if (j == 0) logits[blockIdx.x * 8 + i] = p + b2[0];
}

__global__ __launch_bounds__(256) void k_pool_task(const float* __restrict__ ht,
    const int* __restrict__ tb, float* __restrict__ sums, float* __restrict__ cnt) {
  int lane = threadIdx.x & 63, sub = threadIdx.x >> 6;
  float acc[8], c[8];
  #pragma unroll
  for (int g = 0; g < 8; g++) { acc[g] = 0.f; c[g] = 0.f; }
  int lim = min(NT, (int)((blockIdx.x + 1) * 512));
  for (int n = blockIdx.x * 512 + sub; n < lim; n += 4) {
    int g = tb[n];
    float v = ht[(size_t)n * 64 + lane];
    #pragma unroll
    for (int gg = 0; gg < 8; gg++) {
      if (g == gg) { acc[gg] += v; c[gg] += 1.f; }
    }
  }
  #pragma unroll
  for (int g = 0; g < 8; g++) {
    if (__any(acc[g] != 0.f || c[g] != 0.f)) {
      atomicAdd(&sums[g * 64 + lane], acc[g]);
      if (lane == 0) atomicAdd(&cnt[g], c[g]);
    }
  }
}

// value head with fused proc embed (writes out_hp too)
__global__ __launch_bounds__(512) void k_value(const float* __restrict__ tpsum,
    const float* __restrict__ tpcnt, const float* __restrict__ x_proc,
    const float* __restrict__ W_proc, const float* __restrict__ b_proc,
    float* __restrict__ hp_out, const int* __restrict__ pbatch,
    const float* __restrict__ vW1, const float* __restrict__ vb1,
    const float* __restrict__ vW2, const float* __restrict__ vb2,
    float* __restrict__ val_out) {
  __shared__ float ge[8 * 128];
  int t = threadIdx.x;
  int g = t >> 6, d = t & 63;
  float wreg[8];
  #pragma unroll
  for (int k = 0; k < 8; k++) wreg[k] = W_proc[k * 64 + d];
  float bd = b_proc[d];
  for (int p = g; p < 256; p += 8) {
    const float* xr = x_proc + (size_t)p * 8;
    float a = bd;
    #pragma unroll
    for (int k = 0; k < 8; k++) a += xr[k] * wreg[k];
    hp_out[(size_t)p * 64 + d] = a;
  }
  __syncthreads();
  float c = fmaxf(tpcnt[g], 1.f);
  ge[g * 128 + d] = tpsum[g * 64 + d] / c;
  float s = 0.f, cc = 0.f;
  for (int p = 0; p < 256; p++) {
    int bg = pbatch[p];
    if (bg == g) { s += hp_out[(size_t)p * 64 + d]; cc += 1.f; }
  }
  ge[g * 128 + 64 + d] = s / fmaxf(cc, 1.f);
  __syncthreads();
  float acc = vb1[d];
  #pragma unroll 8
  for (int k = 0; k < 128; k++) acc += ge[g * 128 + k] * vW1[k * 64 + d];
  acc = fmaxf(acc, 0.f);
  float p = acc * vW2[d];
  #pragma unroll
  for (int off = 32; off; off >>= 1) p += __shfl_xor(p, off, 64);
  if (d == 0) val_out[g] = p + vb2[0];
}

extern "C" void kernel_launch(void* const* d_in, const int* in_sizes, int n_in,
                              void* d_out, int out_size, void* d_ws, size_t ws_size,
                              hipStream_t stream) {
  (void)in_sizes; (void)n_in; (void)out_size; (void)ws_size;
  const float* x_task  = (const float*)d_in[0];
  const float* x_proc  = (const float*)d_in[1];
  const int*   eidx    = (const int*)d_in[2];
  const float* eattr   = (const float*)d_in[3];
  const int*   tbatch  = (const int*)d_in[4];
  const int*   pbatch  = (const int*)d_in[5];
  const float* W_task  = (const float*)d_in[6];
  const float* b_task  = (const float*)d_in[7];
  const float* W_proc  = (const float*)d_in[8];
  const float* b_proc  = (const float*)d_in[9];
  const float* gat_W   = (const float*)d_in[10];
  const float* gat_We  = (const float*)d_in[11];
  const float* att_src = (const float*)d_in[12];
  const float* att_dst = (const float*)d_in[13];
  const float* att_edge= (const float*)d_in[14];
  const float* gat_b   = (const float*)d_in[15];
  const float* proj_W  = (const float*)d_in[16];
  const float* proj_b  = (const float*)d_in[17];
  const float* ln_g    = (const float*)d_in[18];
  const float* ln_b    = (const float*)d_in[19];
  const float* pt_W1   = (const float*)d_in[20];
  const float* pt_b1   = (const float*)d_in[21];
  const float* pt_W2   = (const float*)d_in[22];
  const float* pt_b2   = (const float*)d_in[23];
  const float* v_W1    = (const float*)d_in[24];
  const float* v_b1    = (const float*)d_in[25];
  const float* v_W2    = (const float*)d_in[26];
  const float* v_b2    = (const float*)d_in[27];

  char* ws = (char*)d_ws;
  int*   deg    = (int*)(ws + OFF_DEG);
  int*   indptr = (int*)(ws + OFF_INDPTR);
  int*   cursor = (int*)(ws + OFF_CURSOR);
  int*   blksum = (int*)(ws + OFF_BLKSUM);
  float* Mg     = (float*)(ws + OFF_MG);
  float* Mh     = (float*)(ws + OFF_MH);
  float* msum   = (float*)(ws + OFF_MEAN);
  float* tpsum  = (float*)(ws + OFF_TPSUM);
  float* tpcnt  = (float*)(ws + OFF_TPCNT);
  uint2* er     = (uint2*)(ws + OFF_ER);
  float* a_src  = (float*)(ws + OFF_ASRC);
  float* a_dst  = (float*)(ws + OFF_ADST);
  float* ht     = (float*)(ws + OFF_HT);
  __hip_bfloat16* htb = (__hip_bfloat16*)(ws + OFF_HTB);
  __hip_bfloat16* xl  = (__hip_bfloat16*)(ws + OFF_XL);
  __hip_bfloat16* agg = (__hip_bfloat16*)(ws + OFF_AGG);
  __hip_bfloat16* wxf = (__hip_bfloat16*)(ws + OFF_WXF);
  __hip_bfloat16* wpf = (__hip_bfloat16*)(ws + OFF_WPF);

  float* out_logits = (float*)d_out;
  float* out_value  = (float*)d_out + NT;
  float* out_ht     = (float*)d_out + NT + NG;
  float* out_hp     = (float*)d_out + NT + NG + (size_t)NT * EMBD;

  hipMemsetAsync(ws + OFF_DEG, 0, NT * 4, stream);
  hipMemsetAsync(ws + OFF_MEAN, 0, 2144, stream);  // msum + tpsum + tpcnt

  k_embed_task<<<782, 256, 0, stream>>>(x_task, W_task, b_task, ht, htb);
  k_degree_mean<<<(ET + 255) / 256, 256, 0, stream>>>(eidx + NE, eattr, deg, msum);
  k_scanA<<<NBLK, 1024, 0, stream>>>(deg, indptr, blksum);
  k_scanB<<<NBLK, 1024, 0, stream>>>(blksum, indptr, cursor);
  k_mprep<<<1, 128, 0, stream>>>(gat_We, att_edge, msum, Mg, Mh);
  k_fill<<<(ET + 255) / 256, 256, 0, stream>>>(eidx, eidx + NE, cursor, er);
  k_prep_w<<<192, 64, 0, stream>>>(gat_W, proj_W, wxf, wpf);

  for (int l = 0; l < 3; l++) {
    k_xl_mfma<<<782, 256, 0, stream>>>(htb, wxf + (size_t)l * 16384,
                                       att_src + l * NHEADS * EMBD,
                                       att_dst + l * NHEADS * EMBD,
                                       xl, a_src, a_dst);
    k_attn<<<NT / 4, 256, 0, stream>>>(xl, a_src, a_dst, eattr, er, indptr,
                                       Mg + l * 32, Mh + l * 4,
                                       gat_b + l * HE, agg);
    float* htout = (l == 2) ? out_ht : ht;
    k_proj_mfma<<<782, 256, 0, stream>>>(agg, wpf + (size_t)l * 16384,
                                         proj_b + l * EMBD, ln_g + l * EMBD,
                                         ln_b + l * EMBD, ht, htout, htb,
                                         (l == 2) ? 0 : 1);
  }

  k_task_head<<<NT / 8, 256, 0, stream>>>(out_ht, pt_W1, pt_b1, pt_W2, pt_b2, out_logits);
  k_pool_task<<<(NT + 511) / 512, 256, 0, stream>>>(out_ht, tbatch, tpsum, tpcnt);
  k_value<<<1, 512, 0, stream>>>(tpsum, tpcnt, x_proc, W_proc, b_proc, out_hp,
                                 pbatch, v_W1, v_b1, v_W2, v_b2, out_value);
}

// Round 7
// 719.824 us; speedup vs baseline: 2.2799x; 1.0009x over previous
//
#include <hip/hip_runtime.h>
#include <hip/hip_bf16.h>
#include <math.h>

#define NT 50000
#define NP 256
#define NE 800000
#define ET 850000   // NE + NT self loops
#define EMBD 64
#define NHEADS 4
#define HE 256      // NHEADS*EMBD
#define NG 8
#define NBLK 49     // scan blocks of 1024

typedef __attribute__((ext_vector_type(8))) short bf16x8;
typedef __attribute__((ext_vector_type(4))) float f32x4;

// ---- workspace layout (bytes) ----
#define OFF_DEG    0u           // 50000 i32
#define OFF_INDPTR 200192u      // 50001 i32
#define OFF_CURSOR 400384u      // 50000 i32
#define OFF_BLKSUM 600576u      // 64 i32
#define OFF_MG     600832u      // 96 f32 (3 layers x 32: M[k][h])
#define OFF_MH     601216u      // 12 f32 (3 layers x 4: mean-edge aeh)
#define OFF_MEAN   601280u      // 8 f32 msum        <- memset zone start
#define OFF_TPSUM  601344u      // 512 f32
#define OFF_TPCNT  603392u      // 8 f32             <- memset zone end (2144 B)
#define OFF_SRCS   603648u      // 850000 i32 (CSR src)
#define OFF_AE0    4003648u     // 850000 float4 (layer-0 aeh, CSR order)
#define OFF_AE1    17603648u
#define OFF_AE2    31203648u
#define OFF_ASRC   44803648u    // 50048*4 f32
#define OFF_ADST   45604416u    // 50048*4 f32
#define OFF_HT     46405184u    // 50048*64 f32
#define OFF_HTB    59217472u    // 50048*64 bf16
#define OFF_XL     65623616u    // 50000*256 bf16
#define OFF_AGG    91223616u    // 50048*256 bf16
#define OFF_WXF    116848192u   // 3*16384 bf16
#define OFF_WPF    116946496u   // 3*16384 bf16
// total ~117.1 MB

__device__ __forceinline__ float bf_lo(unsigned int u) {
  union { unsigned int i; float f; } v; v.i = u << 16; return v.f;
}
__device__ __forceinline__ float bf_hi(unsigned int u) {
  union { unsigned int i; float f; } v; v.i = u & 0xffff0000u; return v.f;
}

// ---------------- input embed (task) ----------------
__global__ __launch_bounds__(256) void k_embed_task(const float* __restrict__ x,
    const float* __restrict__ W, const float* __restrict__ b,
    float* __restrict__ ht, __hip_bfloat16* __restrict__ htb) {
  int lane = threadIdx.x & 63, wid = threadIdx.x >> 6;
  float breg[16];
  #pragma unroll
  for (int k = 0; k < 16; k++) breg[k] = W[k * 64 + lane];
  float bias = b[lane];
  int row0 = blockIdx.x * 64 + wid * 16;
  #pragma unroll 1
  for (int r = 0; r < 16; r++) {
    int row = row0 + r;
    if (row >= NT) return;
    const float4* xr = (const float4*)(x + (size_t)row * 16);
    float acc = bias;
    #pragma unroll
    for (int q = 0; q < 4; q++) {
      float4 v = xr[q];
      acc += v.x * breg[q*4+0] + v.y * breg[q*4+1] + v.z * breg[q*4+2] + v.w * breg[q*4+3];
    }
    ht[(size_t)row * 64 + lane] = acc;
    htb[(size_t)row * 64 + lane] = __float2bfloat16(acc);
  }
}

// ---------------- degree + edge_attr mean (fused) ----------------
__global__ __launch_bounds__(256) void k_degree_mean(const int* __restrict__ ei1,
    const float* __restrict__ ea, int* __restrict__ deg, float* __restrict__ sums) {
  __shared__ float lds[256];
  int tid = threadIdx.x;
  int e = blockIdx.x * 256 + tid;
  if (e < ET) {
    int d = (e < NE) ? ei1[e] : (e - NE);
    atomicAdd(&deg[d], 1);
  }
  int k = tid & 7, rl = tid >> 3;
  float s = 0.f;
  for (int row = blockIdx.x * 32 + rl; row < NE; row += gridDim.x * 32)
    s += ea[(size_t)row * 8 + k];
  lds[tid] = s;
  __syncthreads();
  for (int off = 128; off >= 8; off >>= 1) {
    if (tid < off) lds[tid] += lds[tid + off];
    __syncthreads();
  }
  if (tid < 8) atomicAdd(&sums[tid], lds[tid]);
}

// ---------------- parallel scan (2 kernels) ----------------
__global__ __launch_bounds__(1024) void k_scanA(const int* __restrict__ deg,
    int* __restrict__ indptr, int* __restrict__ blksum) {
  __shared__ int wsum[16];
  int tid = threadIdx.x, lane = tid & 63, wid = tid >> 6;
  int i = blockIdx.x * 1024 + tid;
  int v = (i < NT) ? deg[i] : 0;
  int x = v;
  #pragma unroll
  for (int off = 1; off < 64; off <<= 1) {
    int t = __shfl_up(x, off, 64);
    if (lane >= off) x += t;
  }
  if (lane == 63) wsum[wid] = x;
  __syncthreads();
  if (wid == 0 && lane < 16) {
    int w = wsum[lane];
    #pragma unroll
    for (int off = 1; off < 16; off <<= 1) {
      int t = __shfl_up(w, off, 64);
      if (lane >= off) w += t;
    }
    wsum[lane] = w;  // inclusive
  }
  __syncthreads();
  int woff = (wid == 0) ? 0 : wsum[wid - 1];
  if (i < NT) indptr[i] = x + woff - v;   // block-local exclusive
  if (tid == 1023) blksum[blockIdx.x] = wsum[15];
}

__global__ __launch_bounds__(1024) void k_scanB(const int* __restrict__ blksum,
    int* __restrict__ indptr, int* __restrict__ cursor) {
  __shared__ int bs[NBLK];
  int tid = threadIdx.x;
  if (tid < NBLK) bs[tid] = blksum[tid];
  __syncthreads();
  int off = 0;
  for (int j = 0; j < (int)blockIdx.x; j++) off += bs[j];
  int i = blockIdx.x * 1024 + tid;
  if (i < NT) {
    int e = indptr[i] + off;
    indptr[i] = e;
    cursor[i] = e;
  }
  if (blockIdx.x == 0 && tid == 0) {
    int tot = 0;
    for (int j = 0; j < NBLK; j++) tot += bs[j];
    indptr[NT] = tot;
  }
}

// ---------------- M matrices for edge attention (all 3 layers) ----------------
__global__ __launch_bounds__(128) void k_mprep(const float* __restrict__ We,
    const float* __restrict__ ae, const float* __restrict__ msum,
    float* __restrict__ Mg, float* __restrict__ Mh) {
  int t = threadIdx.x;
  if (t < 96) {
    int l = t >> 5, idx = t & 31, k = idx >> 2, h = idx & 3;
    const float* Wl = We + (size_t)l * 8 * HE;
    const float* al = ae + (size_t)l * NHEADS * EMBD;
    float s = 0.f;
    #pragma unroll
    for (int d = 0; d < 64; d++) s += Wl[k * HE + h * 64 + d] * al[h * 64 + d];
    Mg[t] = s;
  }
  __syncthreads();
  if (t < 12) {
    int l = t >> 2, h = t & 3;
    float m = 0.f;
    #pragma unroll
    for (int k = 0; k < 8; k++) m += msum[k] * (1.f / NE) * Mg[l * 32 + k * 4 + h];
    Mh[t] = m;
  }
}

// ---------------- CSR fill: srcs + per-layer aeh (all 3 layers) ----------------
__global__ __launch_bounds__(256) void k_fill(const int* __restrict__ ei0,
    const int* __restrict__ ei1, const float* __restrict__ ea,
    const float* __restrict__ Mg, const float* __restrict__ Mh,
    int* __restrict__ cursor, int* __restrict__ srcs,
    float4* __restrict__ ae0, float4* __restrict__ ae1, float4* __restrict__ ae2) {
  __shared__ float MgS[96];
  __shared__ float MhS[12];
  int t = threadIdx.x;
  if (t < 96) MgS[t] = Mg[t];
  if (t < 12) MhS[t] = Mh[t];
  __syncthreads();
  int e = blockIdx.x * 256 + t;
  if (e >= ET) return;
  int d, s;
  float4 r[3];
  if (e < NE) {
    d = ei1[e]; s = ei0[e];
    const float4* pp = (const float4*)(ea + (size_t)e * 8);
    float4 v0 = pp[0], v1 = pp[1];
    float v[8] = {v0.x, v0.y, v0.z, v0.w, v1.x, v1.y, v1.z, v1.w};
    #pragma unroll
    for (int l = 0; l < 3; l++) {
      float rr[4];
      #pragma unroll
      for (int h = 0; h < 4; h++) {
        float acc = 0.f;
        #pragma unroll
        for (int k = 0; k < 8; k++) acc += v[k] * MgS[l * 32 + k * 4 + h];
        rr[h] = acc;
      }
      r[l].x = rr[0]; r[l].y = rr[1]; r[l].z = rr[2]; r[l].w = rr[3];
    }
  } else {
    d = e - NE; s = d;
    #pragma unroll
    for (int l = 0; l < 3; l++) {
      r[l].x = MhS[l * 4 + 0]; r[l].y = MhS[l * 4 + 1];
      r[l].z = MhS[l * 4 + 2]; r[l].w = MhS[l * 4 + 3];
    }
  }
  int p = atomicAdd(&cursor[d], 1);
  srcs[p] = s;
  ae0[p] = r[0];
  ae1[p] = r[1];
  ae2[p] = r[2];
}

// ---------------- weight fragment prep (fused xl+proj) ----------------
__global__ void k_prep_w(const float* __restrict__ Wx, const float* __restrict__ Wp,
                         __hip_bfloat16* __restrict__ Wxf, __hip_bfloat16* __restrict__ Wpf) {
  int lane = threadIdx.x;
  int bid = blockIdx.x;
  int quad = lane >> 4, l15 = lane & 15;
  if (bid < 96) {
    int l = bid >> 5, rem = bid & 31, t = rem >> 1, kb = rem & 1;
    const float* Wl = Wx + (size_t)l * 64 * 256;
    __hip_bfloat16* out = Wxf + (size_t)l * 16384 + (size_t)((t * 2 + kb) * 64 + lane) * 8;
    #pragma unroll
    for (int j = 0; j < 8; j++)
      out[j] = __float2bfloat16(Wl[(kb * 32 + quad * 8 + j) * 256 + t * 16 + l15]);
  } else {
    bid -= 96;
    int l = bid >> 5, rem = bid & 31, t = rem >> 3, kb = rem & 7;
    const float* Wl = Wp + (size_t)l * 256 * 64;
    __hip_bfloat16* out = Wpf + (size_t)l * 16384 + (size_t)((t * 8 + kb) * 64 + lane) * 8;
    #pragma unroll
    for (int j = 0; j < 8; j++)
      out[j] = __float2bfloat16(Wl[(kb * 32 + quad * 8 + j) * 64 + t * 16 + l15]);
  }
}

// ---------------- per-layer kernels ----------------
// xl = htb @ W via MFMA + fused a_src/a_dst
__global__ __launch_bounds__(256) void k_xl_mfma(
    const __hip_bfloat16* __restrict__ htb, const __hip_bfloat16* __restrict__ Wf,
    const float* __restrict__ as, const float* __restrict__ ad,
    __hip_bfloat16* __restrict__ xl, float* __restrict__ a_src, float* __restrict__ a_dst) {
  int lane = threadIdx.x & 63, wave = threadIdx.x >> 6;
  int quad = lane >> 4, l15 = lane & 15;
  int r0 = blockIdx.x * 64 + wave * 16;
  f32x4 acc[16];
  #pragma unroll
  for (int t = 0; t < 16; t++) acc[t] = (f32x4){0.f, 0.f, 0.f, 0.f};
  #pragma unroll
  for (int kb = 0; kb < 2; kb++) {
    bf16x8 a = *(const bf16x8*)(htb + (size_t)(r0 + l15) * 64 + kb * 32 + quad * 8);
    #pragma unroll
    for (int t = 0; t < 16; t++) {
      bf16x8 bfr = *(const bf16x8*)(Wf + (size_t)((t * 2 + kb) * 64 + lane) * 8);
      acc[t] = __builtin_amdgcn_mfma_f32_16x16x32_bf16(a, bfr, acc[t], 0, 0, 0);
    }
  }
  float asv[16], adv[16];
  #pragma unroll
  for (int t = 0; t < 16; t++) { asv[t] = as[t * 16 + l15]; adv[t] = ad[t * 16 + l15]; }
  #pragma unroll
  for (int reg = 0; reg < 4; reg++) {
    int row = r0 + quad * 4 + reg;
    bool ok = row < NT;
    float vs[4] = {0.f, 0.f, 0.f, 0.f}, vd[4] = {0.f, 0.f, 0.f, 0.f};
    #pragma unroll
    for (int t = 0; t < 16; t++) {
      float v = acc[t][reg];
      if (ok) xl[(size_t)row * HE + t * 16 + l15] = __float2bfloat16(v);
      vs[t >> 2] += v * asv[t];
      vd[t >> 2] += v * adv[t];
    }
    #pragma unroll
    for (int off = 8; off; off >>= 1) {
      #pragma unroll
      for (int h = 0; h < 4; h++) {
        vs[h] += __shfl_xor(vs[h], off, 64);
        vd[h] += __shfl_xor(vd[h], off, 64);
      }
    }
    if (ok && l15 == 0) {
      float4 s4; s4.x = vs[0]; s4.y = vs[1]; s4.z = vs[2]; s4.w = vs[3];
      float4 d4; d4.x = vd[0]; d4.y = vd[1]; d4.z = vd[2]; d4.w = vd[3];
      *(float4*)(a_src + (size_t)row * 4) = s4;
      *(float4*)(a_dst + (size_t)row * 4) = d4;
    }
  }
}

// fused softmax + aggregate: one wave per node, 16-edge chunks; aeh read
// sequentially from precomputed per-layer CSR array
__global__ __launch_bounds__(256) void k_attn(
    const __hip_bfloat16* __restrict__ xl, const float* __restrict__ a_src,
    const float* __restrict__ a_dst, const float* __restrict__ aedg,
    const int* __restrict__ indptr, const int* __restrict__ srcs,
    const float* __restrict__ gb, __hip_bfloat16* __restrict__ agg) {
  int node = blockIdx.x * 4 + (threadIdx.x >> 6);
  int lane = threadIdx.x & 63;
  int h = lane >> 4;
  int hbase = lane & 48;
  int e15 = lane & 15;
  int beg = indptr[node], end = indptr[node + 1];
  float adh = a_dst[node * 4 + h];
  float M = -1e30f, S = 0.f;
  float acc0 = 0.f, acc1 = 0.f, acc2 = 0.f, acc3 = 0.f;
  for (int base = beg; base < end; base += 16) {
    int cnt = min(16, end - base);
    int el = base + e15;
    bool ok = e15 < cnt;
    int my_src = ok ? srcs[el] : 0;
    float aeh = ok ? aedg[(size_t)el * 4 + h] : 0.f;
    float asr = ok ? a_src[(size_t)my_src * 4 + h] : 0.f;
    float al = asr + adh + aeh;
    al = (al > 0.f) ? al : 0.2f * al;
    if (!ok) al = -1e30f;
    float cm = al;
    #pragma unroll
    for (int off = 1; off < 16; off <<= 1) cm = fmaxf(cm, __shfl_xor(cm, off, 64));
    float newM = fmaxf(M, cm);
    float corr = __expf(M - newM);
    float ex = __expf(al - newM);
    float cs = ex;
    #pragma unroll
    for (int off = 1; off < 16; off <<= 1) cs += __shfl_xor(cs, off, 64);
    S = S * corr + cs;
    M = newM;
    acc0 *= corr; acc1 *= corr; acc2 *= corr; acc3 *= corr;
    if (cnt == 16) {
      #pragma unroll 4
      for (int j = 0; j < 16; j++) {
        int src = __shfl(my_src, j, 64);
        float cf = __shfl(ex, hbase | j, 64);
        uint2 u = *(const uint2*)(xl + (size_t)src * HE + lane * 4);
        acc0 += cf * bf_lo(u.x);
        acc1 += cf * bf_hi(u.x);
        acc2 += cf * bf_lo(u.y);
        acc3 += cf * bf_hi(u.y);
      }
    } else {
      for (int j = 0; j < cnt; j++) {
        int src = __shfl(my_src, j, 64);
        float cf = __shfl(ex, hbase | j, 64);
        uint2 u = *(const uint2*)(xl + (size_t)src * HE + lane * 4);
        acc0 += cf * bf_lo(u.x);
        acc1 += cf * bf_hi(u.x);
        acc2 += cf * bf_lo(u.y);
        acc3 += cf * bf_hi(u.y);
      }
    }
  }
  float inv = 1.f / (S + 1e-16f);
  float4 g4 = *(const float4*)(gb + lane * 4);
  unsigned int o0 = __bfloat16_as_ushort(__float2bfloat16(acc0 * inv + g4.x));
  unsigned int o1 = __bfloat16_as_ushort(__float2bfloat16(acc1 * inv + g4.y));
  unsigned int o2 = __bfloat16_as_ushort(__float2bfloat16(acc2 * inv + g4.z));
  unsigned int o3 = __bfloat16_as_ushort(__float2bfloat16(acc3 * inv + g4.w));
  uint2 out; out.x = o0 | (o1 << 16); out.y = o2 | (o3 << 16);
  *(uint2*)(agg + (size_t)node * HE + lane * 4) = out;
}

// proj GEMM via MFMA + fused bias/ELU/residual/LN
__global__ __launch_bounds__(256) void k_proj_mfma(
    const __hip_bfloat16* __restrict__ agg, const __hip_bfloat16* __restrict__ Wf,
    const float* __restrict__ pb, const float* __restrict__ g, const float* __restrict__ b,
    const float* __restrict__ ht_in, float* __restrict__ ht_out,
    __hip_bfloat16* __restrict__ htb_out, int writebf) {
  int lane = threadIdx.x & 63, wave = threadIdx.x >> 6;
  int quad = lane >> 4, l15 = lane & 15;
  int r0 = blockIdx.x * 64 + wave * 16;
  f32x4 acc[4];
  #pragma unroll
  for (int t = 0; t < 4; t++) acc[t] = (f32x4){0.f, 0.f, 0.f, 0.f};
  #pragma unroll
  for (int kb = 0; kb < 8; kb++) {
    bf16x8 a = *(const bf16x8*)(agg + (size_t)(r0 + l15) * HE + kb * 32 + quad * 8);
    #pragma unroll
    for (int t = 0; t < 4; t++) {
      bf16x8 bfr = *(const bf16x8*)(Wf + (size_t)((t * 8 + kb) * 64 + lane) * 8);
      acc[t] = __builtin_amdgcn_mfma_f32_16x16x32_bf16(a, bfr, acc[t], 0, 0, 0);
    }
  }
  float pbv[4], gv[4], bv[4];
  #pragma unroll
  for (int t = 0; t < 4; t++) {
    pbv[t] = pb[t * 16 + l15];
    gv[t] = g[t * 16 + l15];
    bv[t] = b[t * 16 + l15];
  }
  #pragma unroll
  for (int reg = 0; reg < 4; reg++) {
    int row = r0 + quad * 4 + reg;
    bool ok = row < NT;
    float h[4], rs = 0.f;
    #pragma unroll
    for (int t = 0; t < 4; t++) {
      float u = acc[t][reg] + pbv[t];
      u = (u > 0.f) ? u : (__expf(u) - 1.f);
      h[t] = ht_in[(size_t)row * 64 + t * 16 + l15] + u;
      rs += h[t];
    }
    #pragma unroll
    for (int off = 8; off; off >>= 1) rs += __shfl_xor(rs, off, 64);
    float mu = rs * 0.015625f;
    float vv = 0.f;
    #pragma unroll
    for (int t = 0; t < 4; t++) { float d = h[t] - mu; vv += d * d; }
    #pragma unroll
    for (int off = 8; off; off >>= 1) vv += __shfl_xor(vv, off, 64);
    float rstd = rsqrtf(vv * 0.015625f + 1e-5f);
    #pragma unroll
    for (int t = 0; t < 4; t++) {
      float o = (h[t] - mu) * rstd * gv[t] + bv[t];
      if (ok) {
        ht_out[(size_t)row * 64 + t * 16 + l15] = o;
        if (writebf) htb_out[(size_t)row * 64 + t * 16 + l15] = __float2bfloat16(o);
      }
    }
  }
}

// ---------------- heads ----------------
__global__ __launch_bounds__(256) void k_task_head(const float* __restrict__ ht,
    const float* __restrict__ W1, const float* __restrict__ b1,
    const float* __restrict__ W2, const float* __restrict__ b2, float* __restrict__ logits) {
  __shared__ float lh[8 * 64];
  int t = threadIdx.x;
  size_t base = (size_t)blockIdx.x * 8 * 64;
  lh[t] = ht[base + t];
  lh[t + 256] = ht[base + t + 256];
  __syncthreads();
  int i = t >> 5, j = t & 31;
  float s = b1[j];
  #pragma unroll 8
  for (int d = 0; d < 64; d++) s += lh[i * 64 + d] * W1[d * 32 + j];
  s = fmaxf(s, 0.f);
  float p = s * W2[j];
  #pragma unroll
  for (int off = 16; off; off >>= 1) p += __shfl_xor(p, off, 64);
  if (j == 0) logits[blockIdx.x * 8 + i] = p + b2[0];
}

__global__ __launch_bounds__(256) void k_pool_task(const float* __restrict__ ht,
    const int* __restrict__ tb, float* __restrict__ sums, float* __restrict__ cnt) {
  int lane = threadIdx.x & 63, sub = threadIdx.x >> 6;
  float acc[8], c[8];
  #pragma unroll
  for (int g = 0; g < 8; g++) { acc[g] = 0.f; c[g] = 0.f; }
  int lim = min(NT, (int)((blockIdx.x + 1) * 512));
  for (int n = blockIdx.x * 512 + sub; n < lim; n += 4) {
    int g = tb[n];
    float v = ht[(size_t)n * 64 + lane];
    #pragma unroll
    for (int gg = 0; gg < 8; gg++) {
      if (g == gg) { acc[gg] += v; c[gg] += 1.f; }
    }
  }
  #pragma unroll
  for (int g = 0; g < 8; g++) {
    if (__any(acc[g] != 0.f || c[g] != 0.f)) {
      atomicAdd(&sums[g * 64 + lane], acc[g]);
      if (lane == 0) atomicAdd(&cnt[g], c[g]);
    }
  }
}

// value head with fused proc embed (writes out_hp too)
__global__ __launch_bounds__(512) void k_value(const float* __restrict__ tpsum,
    const float* __restrict__ tpcnt, const float* __restrict__ x_proc,
    const float* __restrict__ W_proc, const float* __restrict__ b_proc,
    float* __restrict__ hp_out, const int* __restrict__ pbatch,
    const float* __restrict__ vW1, const float* __restrict__ vb1,
    const float* __restrict__ vW2, const float* __restrict__ vb2,
    float* __restrict__ val_out) {
  __shared__ float ge[8 * 128];
  int t = threadIdx.x;
  int g = t >> 6, d = t & 63;
  float wreg[8];
  #pragma unroll
  for (int k = 0; k < 8; k++) wreg[k] = W_proc[k * 64 + d];
  float bd = b_proc[d];
  for (int p = g; p < 256; p += 8) {
    const float* xr = x_proc + (size_t)p * 8;
    float a = bd;
    #pragma unroll
    for (int k = 0; k < 8; k++) a += xr[k] * wreg[k];
    hp_out[(size_t)p * 64 + d] = a;
  }
  __syncthreads();
  float c = fmaxf(tpcnt[g], 1.f);
  ge[g * 128 + d] = tpsum[g * 64 + d] / c;
  float s = 0.f, cc = 0.f;
  for (int p = 0; p < 256; p++) {
    int bg = pbatch[p];
    if (bg == g) { s += hp_out[(size_t)p * 64 + d]; cc += 1.f; }
  }
  ge[g * 128 + 64 + d] = s / fmaxf(cc, 1.f);
  __syncthreads();
  float acc = vb1[d];
  #pragma unroll 8
  for (int k = 0; k < 128; k++) acc += ge[g * 128 + k] * vW1[k * 64 + d];
  acc = fmaxf(acc, 0.f);
  float p = acc * vW2[d];
  #pragma unroll
  for (int off = 32; off; off >>= 1) p += __shfl_xor(p, off, 64);
  if (d == 0) val_out[g] = p + vb2[0];
}

extern "C" void kernel_launch(void* const* d_in, const int* in_sizes, int n_in,
                              void* d_out, int out_size, void* d_ws, size_t ws_size,
                              hipStream_t stream) {
  (void)in_sizes; (void)n_in; (void)out_size; (void)ws_size;
  const float* x_task  = (const float*)d_in[0];
  const float* x_proc  = (const float*)d_in[1];
  const int*   eidx    = (const int*)d_in[2];
  const float* eattr   = (const float*)d_in[3];
  const int*   tbatch  = (const int*)d_in[4];
  const int*   pbatch  = (const int*)d_in[5];
  const float* W_task  = (const float*)d_in[6];
  const float* b_task  = (const float*)d_in[7];
  const float* W_proc  = (const float*)d_in[8];
  const float* b_proc  = (const float*)d_in[9];
  const float* gat_W   = (const float*)d_in[10];
  const float* gat_We  = (const float*)d_in[11];
  const float* att_src = (const float*)d_in[12];
  const float* att_dst = (const float*)d_in[13];
  const float* att_edge= (const float*)d_in[14];
  const float* gat_b   = (const float*)d_in[15];
  const float* proj_W  = (const float*)d_in[16];
  const float* proj_b  = (const float*)d_in[17];
  const float* ln_g    = (const float*)d_in[18];
  const float* ln_b    = (const float*)d_in[19];
  const float* pt_W1   = (const float*)d_in[20];
  const float* pt_b1   = (const float*)d_in[21];
  const float* pt_W2   = (const float*)d_in[22];
  const float* pt_b2   = (const float*)d_in[23];
  const float* v_W1    = (const float*)d_in[24];
  const float* v_b1    = (const float*)d_in[25];
  const float* v_W2    = (const float*)d_in[26];
  const float* v_b2    = (const float*)d_in[27];

  char* ws = (char*)d_ws;
  int*   deg    = (int*)(ws + OFF_DEG);
  int*   indptr = (int*)(ws + OFF_INDPTR);
  int*   cursor = (int*)(ws + OFF_CURSOR);
  int*   blksum = (int*)(ws + OFF_BLKSUM);
  float* Mg     = (float*)(ws + OFF_MG);
  float* Mh     = (float*)(ws + OFF_MH);
  float* msum   = (float*)(ws + OFF_MEAN);
  float* tpsum  = (float*)(ws + OFF_TPSUM);
  float* tpcnt  = (float*)(ws + OFF_TPCNT);
  int*   srcs   = (int*)(ws + OFF_SRCS);
  float4* ae0   = (float4*)(ws + OFF_AE0);
  float4* ae1   = (float4*)(ws + OFF_AE1);
  float4* ae2   = (float4*)(ws + OFF_AE2);
  float* a_src  = (float*)(ws + OFF_ASRC);
  float* a_dst  = (float*)(ws + OFF_ADST);
  float* ht     = (float*)(ws + OFF_HT);
  __hip_bfloat16* htb = (__hip_bfloat16*)(ws + OFF_HTB);
  __hip_bfloat16* xl  = (__hip_bfloat16*)(ws + OFF_XL);
  __hip_bfloat16* agg = (__hip_bfloat16*)(ws + OFF_AGG);
  __hip_bfloat16* wxf = (__hip_bfloat16*)(ws + OFF_WXF);
  __hip_bfloat16* wpf = (__hip_bfloat16*)(ws + OFF_WPF);
  float* aedg[3] = {(float*)ae0, (float*)ae1, (float*)ae2};

  float* out_logits = (float*)d_out;
  float* out_value  = (float*)d_out + NT;
  float* out_ht     = (float*)d_out + NT + NG;
  float* out_hp     = (float*)d_out + NT + NG + (size_t)NT * EMBD;

  hipMemsetAsync(ws + OFF_DEG, 0, NT * 4, stream);
  hipMemsetAsync(ws + OFF_MEAN, 0, 2144, stream);  // msum + tpsum + tpcnt

  k_embed_task<<<782, 256, 0, stream>>>(x_task, W_task, b_task, ht, htb);
  k_degree_mean<<<(ET + 255) / 256, 256, 0, stream>>>(eidx + NE, eattr, deg, msum);
  k_scanA<<<NBLK, 1024, 0, stream>>>(deg, indptr, blksum);
  k_scanB<<<NBLK, 1024, 0, stream>>>(blksum, indptr, cursor);
  k_mprep<<<1, 128, 0, stream>>>(gat_We, att_edge, msum, Mg, Mh);
  k_fill<<<(ET + 255) / 256, 256, 0, stream>>>(eidx, eidx + NE, eattr, Mg, Mh,
                                               cursor, srcs, ae0, ae1, ae2);
  k_prep_w<<<192, 64, 0, stream>>>(gat_W, proj_W, wxf, wpf);

  for (int l = 0; l < 3; l++) {
    k_xl_mfma<<<782, 256, 0, stream>>>(htb, wxf + (size_t)l * 16384,
                                       att_src + l * NHEADS * EMBD,
                                       att_dst + l * NHEADS * EMBD,
                                       xl, a_src, a_dst);
    k_attn<<<NT / 4, 256, 0, stream>>>(xl, a_src, a_dst, aedg[l], indptr, srcs,
                                       gat_b + l * HE, agg);
    float* htout = (l == 2) ? out_ht : ht;
    k_proj_mfma<<<782, 256, 0, stream>>>(agg, wpf + (size_t)l * 16384,
                                         proj_b + l * EMBD, ln_g + l * EMBD,
                                         ln_b + l * EMBD, ht, htout, htb,
                                         (l == 2) ? 0 : 1);
  }

  k_task_head<<<NT / 8, 256, 0, stream>>>(out_ht, pt_W1, pt_b1, pt_W2, pt_b2, out_logits);
  k_pool_task<<<(NT + 511) / 512, 256, 0, stream>>>(out_ht, tbatch, tpsum, tpcnt);
  k_value<<<1, 512, 0, stream>>>(tpsum, tpcnt, x_proc, W_proc, b_proc, out_hp,
                                 pbatch, v_W1, v_b1, v_W2, v_b2, out_value);
}

// Round 8
// 694.603 us; speedup vs baseline: 2.3626x; 1.0363x over previous
//
#include <hip/hip_runtime.h>
#include <hip/hip_bf16.h>
#include <math.h>

#define NT 50000
#define NP 256
#define NE 800000
#define ET 850000   // NE + NT self loops
#define EMBD 64
#define NHEADS 4
#define HE 256      // NHEADS*EMBD
#define NG 8
#define NBLK 49     // scan blocks of 1024

typedef __attribute__((ext_vector_type(8))) short bf16x8;
typedef __attribute__((ext_vector_type(4))) float f32x4;

// ---- workspace layout (bytes) ----
#define OFF_DEG    0u           // 50000 i32
#define OFF_INDPTR 200192u      // 50001 i32
#define OFF_CURSOR 400384u      // 50000 i32
#define OFF_BLKSUM 600576u      // 64 i32
#define OFF_MG     600832u      // 96 f32
#define OFF_MH     601216u      // 12 f32
#define OFF_MEAN   601280u      // 8 f32            <- memset zone start
#define OFF_TPSUM  601344u      // 512 f32
#define OFF_TPCNT  603392u      // 8 f32            <- memset zone end (2144 B)
#define OFF_ER0    603648u      // 850000 uint4 {src, ae01, ae23, 0}
#define OFF_ER1    14203648u
#define OFF_ER2    27803648u
#define OFF_ASRC   41403648u    // 50048*4 f32
#define OFF_ADST   42204416u
#define OFF_HT     43005184u    // 50048*64 f32
#define OFF_HTB    55817472u    // 50048*64 bf16
#define OFF_XL     62223616u    // 50000*256 bf16
#define OFF_AGG    87823616u    // 50048*256 bf16
#define OFF_WXF    113448192u   // 3*16384 bf16
#define OFF_WPF    113546496u   // 3*16384 bf16
// total ~113.6 MB

__device__ __forceinline__ float bf_lo(unsigned int u) {
  union { unsigned int i; float f; } v; v.i = u << 16; return v.f;
}
__device__ __forceinline__ float bf_hi(unsigned int u) {
  union { unsigned int i; float f; } v; v.i = u & 0xffff0000u; return v.f;
}
__device__ __forceinline__ unsigned pk2(float a, float b) {
  unsigned ua = __bfloat16_as_ushort(__float2bfloat16(a));
  unsigned ub = __bfloat16_as_ushort(__float2bfloat16(b));
  return ua | (ub << 16);
}

// ---------------- input embed (task) ----------------
__global__ __launch_bounds__(256) void k_embed_task(const float* __restrict__ x,
    const float* __restrict__ W, const float* __restrict__ b,
    float* __restrict__ ht, __hip_bfloat16* __restrict__ htb) {
  int lane = threadIdx.x & 63, wid = threadIdx.x >> 6;
  float breg[16];
  #pragma unroll
  for (int k = 0; k < 16; k++) breg[k] = W[k * 64 + lane];
  float bias = b[lane];
  int row0 = blockIdx.x * 64 + wid * 16;
  #pragma unroll 1
  for (int r = 0; r < 16; r++) {
    int row = row0 + r;
    if (row >= NT) return;
    const float4* xr = (const float4*)(x + (size_t)row * 16);
    float acc = bias;
    #pragma unroll
    for (int q = 0; q < 4; q++) {
      float4 v = xr[q];
      acc += v.x * breg[q*4+0] + v.y * breg[q*4+1] + v.z * breg[q*4+2] + v.w * breg[q*4+3];
    }
    ht[(size_t)row * 64 + lane] = acc;
    htb[(size_t)row * 64 + lane] = __float2bfloat16(acc);
  }
}

// ---------------- degree + edge_attr mean (fused) ----------------
__global__ __launch_bounds__(256) void k_degree_mean(const int* __restrict__ ei1,
    const float* __restrict__ ea, int* __restrict__ deg, float* __restrict__ sums) {
  __shared__ float lds[256];
  int tid = threadIdx.x;
  int e = blockIdx.x * 256 + tid;
  if (e < ET) {
    int d = (e < NE) ? ei1[e] : (e - NE);
    atomicAdd(&deg[d], 1);
  }
  int k = tid & 7, rl = tid >> 3;
  float s = 0.f;
  for (int row = blockIdx.x * 32 + rl; row < NE; row += gridDim.x * 32)
    s += ea[(size_t)row * 8 + k];
  lds[tid] = s;
  __syncthreads();
  for (int off = 128; off >= 8; off >>= 1) {
    if (tid < off) lds[tid] += lds[tid + off];
    __syncthreads();
  }
  if (tid < 8) atomicAdd(&sums[tid], lds[tid]);
}

// ---------------- parallel scan (2 kernels) ----------------
__global__ __launch_bounds__(1024) void k_scanA(const int* __restrict__ deg,
    int* __restrict__ indptr, int* __restrict__ blksum) {
  __shared__ int wsum[16];
  int tid = threadIdx.x, lane = tid & 63, wid = tid >> 6;
  int i = blockIdx.x * 1024 + tid;
  int v = (i < NT) ? deg[i] : 0;
  int x = v;
  #pragma unroll
  for (int off = 1; off < 64; off <<= 1) {
    int t = __shfl_up(x, off, 64);
    if (lane >= off) x += t;
  }
  if (lane == 63) wsum[wid] = x;
  __syncthreads();
  if (wid == 0 && lane < 16) {
    int w = wsum[lane];
    #pragma unroll
    for (int off = 1; off < 16; off <<= 1) {
      int t = __shfl_up(w, off, 64);
      if (lane >= off) w += t;
    }
    wsum[lane] = w;  // inclusive
  }
  __syncthreads();
  int woff = (wid == 0) ? 0 : wsum[wid - 1];
  if (i < NT) indptr[i] = x + woff - v;   // block-local exclusive
  if (tid == 1023) blksum[blockIdx.x] = wsum[15];
}

__global__ __launch_bounds__(1024) void k_scanB(const int* __restrict__ blksum,
    int* __restrict__ indptr, int* __restrict__ cursor) {
  __shared__ int bs[NBLK];
  int tid = threadIdx.x;
  if (tid < NBLK) bs[tid] = blksum[tid];
  __syncthreads();
  int off = 0;
  for (int j = 0; j < (int)blockIdx.x; j++) off += bs[j];
  int i = blockIdx.x * 1024 + tid;
  if (i < NT) {
    int e = indptr[i] + off;
    indptr[i] = e;
    cursor[i] = e;
  }
  if (blockIdx.x == 0 && tid == 0) {
    int tot = 0;
    for (int j = 0; j < NBLK; j++) tot += bs[j];
    indptr[NT] = tot;
  }
}

// ---------------- M matrices for edge attention (all 3 layers) ----------------
__global__ __launch_bounds__(128) void k_mprep(const float* __restrict__ We,
    const float* __restrict__ ae, const float* __restrict__ msum,
    float* __restrict__ Mg, float* __restrict__ Mh) {
  int t = threadIdx.x;
  if (t < 96) {
    int l = t >> 5, idx = t & 31, k = idx >> 2, h = idx & 3;
    const float* Wl = We + (size_t)l * 8 * HE;
    const float* al = ae + (size_t)l * NHEADS * EMBD;
    float s = 0.f;
    #pragma unroll
    for (int d = 0; d < 64; d++) s += Wl[k * HE + h * 64 + d] * al[h * 64 + d];
    Mg[t] = s;
  }
  __syncthreads();
  if (t < 12) {
    int l = t >> 2, h = t & 3;
    float m = 0.f;
    #pragma unroll
    for (int k = 0; k < 8; k++) m += msum[k] * (1.f / NE) * Mg[l * 32 + k * 4 + h];
    Mh[t] = m;
  }
}

// ---------------- CSR fill: packed per-layer records {src, aeh bf16 x4} ----------------
__global__ __launch_bounds__(256) void k_fill(const int* __restrict__ ei0,
    const int* __restrict__ ei1, const float* __restrict__ ea,
    const float* __restrict__ Mg, const float* __restrict__ Mh,
    int* __restrict__ cursor,
    uint4* __restrict__ er0, uint4* __restrict__ er1, uint4* __restrict__ er2) {
  __shared__ float MgS[96];
  __shared__ float MhS[12];
  int t = threadIdx.x;
  if (t < 96) MgS[t] = Mg[t];
  if (t < 12) MhS[t] = Mh[t];
  __syncthreads();
  int e = blockIdx.x * 256 + t;
  if (e >= ET) return;
  int d, s;
  float r[3][4];
  if (e < NE) {
    d = ei1[e]; s = ei0[e];
    const float4* pp = (const float4*)(ea + (size_t)e * 8);
    float4 v0 = pp[0], v1 = pp[1];
    float v[8] = {v0.x, v0.y, v0.z, v0.w, v1.x, v1.y, v1.z, v1.w};
    #pragma unroll
    for (int l = 0; l < 3; l++) {
      #pragma unroll
      for (int h = 0; h < 4; h++) {
        float acc = 0.f;
        #pragma unroll
        for (int k = 0; k < 8; k++) acc += v[k] * MgS[l * 32 + k * 4 + h];
        r[l][h] = acc;
      }
    }
  } else {
    d = e - NE; s = d;
    #pragma unroll
    for (int l = 0; l < 3; l++)
      #pragma unroll
      for (int h = 0; h < 4; h++) r[l][h] = MhS[l * 4 + h];
  }
  int p = atomicAdd(&cursor[d], 1);
  uint4 rc;
  rc.x = (unsigned)s; rc.w = 0u;
  rc.y = pk2(r[0][0], r[0][1]); rc.z = pk2(r[0][2], r[0][3]); er0[p] = rc;
  rc.y = pk2(r[1][0], r[1][1]); rc.z = pk2(r[1][2], r[1][3]); er1[p] = rc;
  rc.y = pk2(r[2][0], r[2][1]); rc.z = pk2(r[2][2], r[2][3]); er2[p] = rc;
}

// ---------------- weight fragment prep (fused xl+proj) ----------------
__global__ void k_prep_w(const float* __restrict__ Wx, const float* __restrict__ Wp,
                         __hip_bfloat16* __restrict__ Wxf, __hip_bfloat16* __restrict__ Wpf) {
  int lane = threadIdx.x;
  int bid = blockIdx.x;
  int quad = lane >> 4, l15 = lane & 15;
  if (bid < 96) {
    int l = bid >> 5, rem = bid & 31, t = rem >> 1, kb = rem & 1;
    const float* Wl = Wx + (size_t)l * 64 * 256;
    __hip_bfloat16* out = Wxf + (size_t)l * 16384 + (size_t)((t * 2 + kb) * 64 + lane) * 8;
    #pragma unroll
    for (int j = 0; j < 8; j++)
      out[j] = __float2bfloat16(Wl[(kb * 32 + quad * 8 + j) * 256 + t * 16 + l15]);
  } else {
    bid -= 96;
    int l = bid >> 5, rem = bid & 31, t = rem >> 3, kb = rem & 7;
    const float* Wl = Wp + (size_t)l * 256 * 64;
    __hip_bfloat16* out = Wpf + (size_t)l * 16384 + (size_t)((t * 8 + kb) * 64 + lane) * 8;
    #pragma unroll
    for (int j = 0; j < 8; j++)
      out[j] = __float2bfloat16(Wl[(kb * 32 + quad * 8 + j) * 64 + t * 16 + l15]);
  }
}

// ---------------- per-layer kernels ----------------
// xl = htb @ W via MFMA; LDS-staged epilogue: shuffle-free a_src/a_dst + coalesced xl stores
__global__ __launch_bounds__(256) void k_xl_mfma(
    const __hip_bfloat16* __restrict__ htb, const __hip_bfloat16* __restrict__ Wf,
    const float* __restrict__ as, const float* __restrict__ ad,
    __hip_bfloat16* __restrict__ xl, float* __restrict__ a_src, float* __restrict__ a_dst) {
  __shared__ __hip_bfloat16 cbuf[64 * 264];   // pitch 264 bf16 (528 B, 16B-aligned)
  __shared__ float asL[256], adL[256];
  int tid = threadIdx.x;
  int lane = tid & 63, wave = tid >> 6;
  int quad = lane >> 4, l15 = lane & 15;
  asL[tid] = as[tid];
  adL[tid] = ad[tid];
  int r0 = blockIdx.x * 64;
  int arow = r0 + wave * 16 + l15;
  f32x4 acc[16];
  #pragma unroll
  for (int t = 0; t < 16; t++) acc[t] = (f32x4){0.f, 0.f, 0.f, 0.f};
  #pragma unroll
  for (int kb = 0; kb < 2; kb++) {
    bf16x8 a = *(const bf16x8*)(htb + (size_t)arow * 64 + kb * 32 + quad * 8);
    #pragma unroll
    for (int t = 0; t < 16; t++) {
      bf16x8 bfr = *(const bf16x8*)(Wf + (size_t)((t * 2 + kb) * 64 + lane) * 8);
      acc[t] = __builtin_amdgcn_mfma_f32_16x16x32_bf16(a, bfr, acc[t], 0, 0, 0);
    }
  }
  int rloc = wave * 16 + quad * 4;
  #pragma unroll
  for (int t = 0; t < 16; t++) {
    #pragma unroll
    for (int reg = 0; reg < 4; reg++)
      cbuf[(rloc + reg) * 264 + t * 16 + l15] = __float2bfloat16(acc[t][reg]);
  }
  __syncthreads();
  // a_src/a_dst: wave = head q, lane = row r
  {
    int r = tid & 63, q = tid >> 6;
    const __hip_bfloat16* rowp = &cbuf[r * 264 + q * 64];
    float vs = 0.f, vd = 0.f;
    #pragma unroll
    for (int d8 = 0; d8 < 8; d8++) {
      uint4 u = *(const uint4*)(rowp + d8 * 8);
      float x0 = bf_lo(u.x), x1 = bf_hi(u.x), x2 = bf_lo(u.y), x3 = bf_hi(u.y);
      float x4 = bf_lo(u.z), x5 = bf_hi(u.z), x6 = bf_lo(u.w), x7 = bf_hi(u.w);
      const float* ap = &asL[q * 64 + d8 * 8];
      const float* dp = &adL[q * 64 + d8 * 8];
      vs += x0*ap[0]+x1*ap[1]+x2*ap[2]+x3*ap[3]+x4*ap[4]+x5*ap[5]+x6*ap[6]+x7*ap[7];
      vd += x0*dp[0]+x1*dp[1]+x2*dp[2]+x3*dp[3]+x4*dp[4]+x5*dp[5]+x6*dp[6]+x7*dp[7];
    }
    int row = r0 + r;
    if (row < NT) {
      a_src[row * 4 + q] = vs;
      a_dst[row * 4 + q] = vd;
    }
  }
  // coalesced xl copy-out: 2048 chunks of 16B
  #pragma unroll
  for (int k = 0; k < 8; k++) {
    int c = k * 256 + tid;
    int row = c >> 5, off = c & 31;
    if (r0 + row < NT) {
      uint4 v = *(const uint4*)(&cbuf[row * 264 + off * 8]);
      *(uint4*)(xl + (size_t)(r0 + row) * HE + off * 8) = v;
    }
  }
}

// fused softmax + aggregate: one wave per node, 16-edge chunks; per-edge record
// {src, aeh bf16 x4} read as one uint4
__global__ __launch_bounds__(256) void k_attn(
    const __hip_bfloat16* __restrict__ xl, const float* __restrict__ a_src,
    const float* __restrict__ a_dst, const uint4* __restrict__ er,
    const int* __restrict__ indptr, const float* __restrict__ gb,
    __hip_bfloat16* __restrict__ agg) {
  int node = blockIdx.x * 4 + (threadIdx.x >> 6);
  int lane = threadIdx.x & 63;
  int h = lane >> 4;
  int hbase = lane & 48;
  int e15 = lane & 15;
  int beg = indptr[node], end = indptr[node + 1];
  float adh = a_dst[node * 4 + h];
  float M = -1e30f, S = 0.f;
  float acc0 = 0.f, acc1 = 0.f, acc2 = 0.f, acc3 = 0.f;
  for (int base = beg; base < end; base += 16) {
    int cnt = min(16, end - base);
    bool ok = e15 < cnt;
    uint4 rec; rec.x = 0u; rec.y = 0u; rec.z = 0u; rec.w = 0u;
    if (ok) rec = er[base + e15];
    int my_src = (int)rec.x;
    unsigned wsel = (h < 2) ? rec.y : rec.z;
    float aeh = (h & 1) ? bf_hi(wsel) : bf_lo(wsel);
    float asr = ok ? a_src[(size_t)my_src * 4 + h] : 0.f;
    float al = asr + adh + aeh;
    al = (al > 0.f) ? al : 0.2f * al;
    if (!ok) al = -1e30f;
    float cm = al;
    #pragma unroll
    for (int off = 1; off < 16; off <<= 1) cm = fmaxf(cm, __shfl_xor(cm, off, 64));
    float newM = fmaxf(M, cm);
    float corr = __expf(M - newM);
    float ex = __expf(al - newM);
    float cs = ex;
    #pragma unroll
    for (int off = 1; off < 16; off <<= 1) cs += __shfl_xor(cs, off, 64);
    S = S * corr + cs;
    M = newM;
    acc0 *= corr; acc1 *= corr; acc2 *= corr; acc3 *= corr;
    if (cnt == 16) {
      #pragma unroll 4
      for (int j = 0; j < 16; j++) {
        int src = __shfl(my_src, j, 64);
        float cf = __shfl(ex, hbase | j, 64);
        uint2 u = *(const uint2*)(xl + (size_t)src * HE + lane * 4);
        acc0 += cf * bf_lo(u.x);
        acc1 += cf * bf_hi(u.x);
        acc2 += cf * bf_lo(u.y);
        acc3 += cf * bf_hi(u.y);
      }
    } else {
      for (int j = 0; j < cnt; j++) {
        int src = __shfl(my_src, j, 64);
        float cf = __shfl(ex, hbase | j, 64);
        uint2 u = *(const uint2*)(xl + (size_t)src * HE + lane * 4);
        acc0 += cf * bf_lo(u.x);
        acc1 += cf * bf_hi(u.x);
        acc2 += cf * bf_lo(u.y);
        acc3 += cf * bf_hi(u.y);
      }
    }
  }
  float inv = 1.f / (S + 1e-16f);
  float4 g4 = *(const float4*)(gb + lane * 4);
  unsigned int o0 = __bfloat16_as_ushort(__float2bfloat16(acc0 * inv + g4.x));
  unsigned int o1 = __bfloat16_as_ushort(__float2bfloat16(acc1 * inv + g4.y));
  unsigned int o2 = __bfloat16_as_ushort(__float2bfloat16(acc2 * inv + g4.z));
  unsigned int o3 = __bfloat16_as_ushort(__float2bfloat16(acc3 * inv + g4.w));
  uint2 out; out.x = o0 | (o1 << 16); out.y = o2 | (o3 << 16);
  *(uint2*)(agg + (size_t)node * HE + lane * 4) = out;
}

// proj GEMM via MFMA; LDS-staged epilogue with coalesced stores + LDS LN
__global__ __launch_bounds__(256) void k_proj_mfma(
    const __hip_bfloat16* __restrict__ agg, const __hip_bfloat16* __restrict__ Wf,
    const float* __restrict__ pb, const float* __restrict__ g, const float* __restrict__ b,
    const float* __restrict__ ht_in, float* __restrict__ ht_out,
    __hip_bfloat16* __restrict__ htb_out, int writebf) {
  __shared__ float cbuf[64 * 68];     // pitch 68 f32
  __shared__ float red[8 * 64];
  __shared__ float stats[2 * 64];
  __shared__ float pbL[64], gL[64], bL[64];
  int tid = threadIdx.x;
  int lane = tid & 63, wave = tid >> 6;
  int quad = lane >> 4, l15 = lane & 15;
  if (tid < 64) { pbL[tid] = pb[tid]; gL[tid] = g[tid]; bL[tid] = b[tid]; }
  int r0 = blockIdx.x * 64;
  int arow = r0 + wave * 16 + l15;
  f32x4 acc[4];
  #pragma unroll
  for (int t = 0; t < 4; t++) acc[t] = (f32x4){0.f, 0.f, 0.f, 0.f};
  #pragma unroll
  for (int kb = 0; kb < 8; kb++) {
    bf16x8 a = *(const bf16x8*)(agg + (size_t)arow * HE + kb * 32 + quad * 8);
    #pragma unroll
    for (int t = 0; t < 4; t++) {
      bf16x8 bfr = *(const bf16x8*)(Wf + (size_t)((t * 8 + kb) * 64 + lane) * 8);
      acc[t] = __builtin_amdgcn_mfma_f32_16x16x32_bf16(a, bfr, acc[t], 0, 0, 0);
    }
  }
  int rloc = wave * 16 + quad * 4;
  #pragma unroll
  for (int t = 0; t < 4; t++) {
    #pragma unroll
    for (int reg = 0; reg < 4; reg++)
      cbuf[(rloc + reg) * 68 + t * 16 + l15] = acc[t][reg];
  }
  __syncthreads();
  int r = tid >> 2, q = tid & 3;       // row r, col quarter q (16 cols)
  int row = r0 + r;
  float h[16];
  float s1 = 0.f, s2 = 0.f;
  const float* hin = ht_in + (size_t)row * 64 + q * 16;
  #pragma unroll
  for (int d = 0; d < 16; d++) {
    float u = cbuf[r * 68 + q * 16 + d] + pbL[q * 16 + d];
    u = (u > 0.f) ? u : (__expf(u) - 1.f);
    float hv = hin[d] + u;
    h[d] = hv;
    s1 += hv; s2 += hv * hv;
  }
  red[q * 64 + r] = s1;
  red[256 + q * 64 + r] = s2;
  __syncthreads();
  if (tid < 64) {
    float sa = red[tid] + red[64 + tid] + red[128 + tid] + red[192 + tid];
    float sb = red[256 + tid] + red[320 + tid] + red[384 + tid] + red[448 + tid];
    float mu = sa * 0.015625f;
    float var = sb * 0.015625f - mu * mu;
    stats[tid] = mu;
    stats[64 + tid] = rsqrtf(var + 1e-5f);
  }
  __syncthreads();
  float mu = stats[r], rstd = stats[64 + r];
  if (row < NT) {
    float o[16];
    #pragma unroll
    for (int d = 0; d < 16; d++)
      o[d] = (h[d] - mu) * rstd * gL[q * 16 + d] + bL[q * 16 + d];
    float* outp = ht_out + (size_t)row * 64 + q * 16;
    #pragma unroll
    for (int d4 = 0; d4 < 4; d4++) {
      float4 v; v.x = o[d4*4]; v.y = o[d4*4+1]; v.z = o[d4*4+2]; v.w = o[d4*4+3];
      *(float4*)(outp + d4 * 4) = v;
    }
    if (writebf) {
      uint4 u0, u1;
      u0.x = pk2(o[0], o[1]);  u0.y = pk2(o[2], o[3]);
      u0.z = pk2(o[4], o[5]);  u0.w = pk2(o[6], o[7]);
      u1.x = pk2(o[8], o[9]);  u1.y = pk2(o[10], o[11]);
      u1.z = pk2(o[12], o[13]); u1.w = pk2(o[14], o[15]);
      uint4* hb = (uint4*)(htb_out + (size_t)row * 64 + q * 16);
      hb[0] = u0; hb[1] = u1;
    }
  }
}

// ---------------- heads ----------------
__global__ __launch_bounds__(256) void k_task_head(const float* __restrict__ ht,
    const float* __restrict__ W1, const float* __restrict__ b1,
    const float* __restrict__ W2, const float* __restrict__ b2, float* __restrict__ logits) {
  __shared__ float lh[8 * 64];
  int t = threadIdx.x;
  size_t base = (size_t)blockIdx.x * 8 * 64;
  lh[t] = ht[base + t];
  lh[t + 256] = ht[base + t + 256];
  __syncthreads();
  int i = t >> 5, j = t & 31;
  float s = b1[j];
  #pragma unroll 8
  for (int d = 0; d < 64; d++) s += lh[i * 64 + d] * W1[d * 32 + j];
  s = fmaxf(s, 0.f);
  float p = s * W2[j];
  #pragma unroll
  for (int off = 16; off; off >>= 1) p += __shfl_xor(p, off, 64);
  if (j == 0) logits[blockIdx.x * 8 + i] = p + b2[0];
}

__global__ __launch_bounds__(256) void k_pool_task(const float* __restrict__ ht,
    const int* __restrict__ tb, float* __restrict__ sums, float* __restrict__ cnt) {
  int lane = threadIdx.x & 63, sub = threadIdx.x >> 6;
  float acc[8], c[8];
  #pragma unroll
  for (int g = 0; g < 8; g++) { acc[g] = 0.f; c[g] = 0.f; }
  int lim = min(NT, (int)((blockIdx.x + 1) * 512));
  for (int n = blockIdx.x * 512 + sub; n < lim; n += 4) {
    int g = tb[n];
    float v = ht[(size_t)n * 64 + lane];
    #pragma unroll
    for (int gg = 0; gg < 8; gg++) {
      if (g == gg) { acc[gg] += v; c[gg] += 1.f; }
    }
  }
  #pragma unroll
  for (int g = 0; g < 8; g++) {
    if (__any(acc[g] != 0.f || c[g] != 0.f)) {
      atomicAdd(&sums[g * 64 + lane], acc[g]);
      if (lane == 0) atomicAdd(&cnt[g], c[g]);
    }
  }
}

// value head with fused proc embed (writes out_hp too)
__global__ __launch_bounds__(512) void k_value(const float* __restrict__ tpsum,
    const float* __restrict__ tpcnt, const float* __restrict__ x_proc,
    const float* __restrict__ W_proc, const float* __restrict__ b_proc,
    float* __restrict__ hp_out, const int* __restrict__ pbatch,
    const float* __restrict__ vW1, const float* __restrict__ vb1,
    const float* __restrict__ vW2, const float* __restrict__ vb2,
    float* __restrict__ val_out) {
  __shared__ float ge[8 * 128];
  int t = threadIdx.x;
  int g = t >> 6, d = t & 63;
  float wreg[8];
  #pragma unroll
  for (int k = 0; k < 8; k++) wreg[k] = W_proc[k * 64 + d];
  float bd = b_proc[d];
  for (int p = g; p < 256; p += 8) {
    const float* xr = x_proc + (size_t)p * 8;
    float a = bd;
    #pragma unroll
    for (int k = 0; k < 8; k++) a += xr[k] * wreg[k];
    hp_out[(size_t)p * 64 + d] = a;
  }
  __syncthreads();
  float c = fmaxf(tpcnt[g], 1.f);
  ge[g * 128 + d] = tpsum[g * 64 + d] / c;
  float s = 0.f, cc = 0.f;
  for (int p = 0; p < 256; p++) {
    int bg = pbatch[p];
    if (bg == g) { s += hp_out[(size_t)p * 64 + d]; cc += 1.f; }
  }
  ge[g * 128 + 64 + d] = s / fmaxf(cc, 1.f);
  __syncthreads();
  float acc = vb1[d];
  #pragma unroll 8
  for (int k = 0; k < 128; k++) acc += ge[g * 128 + k] * vW1[k * 64 + d];
  acc = fmaxf(acc, 0.f);
  float p = acc * vW2[d];
  #pragma unroll
  for (int off = 32; off; off >>= 1) p += __shfl_xor(p, off, 64);
  if (d == 0) val_out[g] = p + vb2[0];
}

extern "C" void kernel_launch(void* const* d_in, const int* in_sizes, int n_in,
                              void* d_out, int out_size, void* d_ws, size_t ws_size,
                              hipStream_t stream) {
  (void)in_sizes; (void)n_in; (void)out_size; (void)ws_size;
  const float* x_task  = (const float*)d_in[0];
  const float* x_proc  = (const float*)d_in[1];
  const int*   eidx    = (const int*)d_in[2];
  const float* eattr   = (const float*)d_in[3];
  const int*   tbatch  = (const int*)d_in[4];
  const int*   pbatch  = (const int*)d_in[5];
  const float* W_task  = (const float*)d_in[6];
  const float* b_task  = (const float*)d_in[7];
  const float* W_proc  = (const float*)d_in[8];
  const float* b_proc  = (const float*)d_in[9];
  const float* gat_W   = (const float*)d_in[10];
  const float* gat_We  = (const float*)d_in[11];
  const float* att_src = (const float*)d_in[12];
  const float* att_dst = (const float*)d_in[13];
  const float* att_edge= (const float*)d_in[14];
  const float* gat_b   = (const float*)d_in[15];
  const float* proj_W  = (const float*)d_in[16];
  const float* proj_b  = (const float*)d_in[17];
  const float* ln_g    = (const float*)d_in[18];
  const float* ln_b    = (const float*)d_in[19];
  const float* pt_W1   = (const float*)d_in[20];
  const float* pt_b1   = (const float*)d_in[21];
  const float* pt_W2   = (const float*)d_in[22];
  const float* pt_b2   = (const float*)d_in[23];
  const float* v_W1    = (const float*)d_in[24];
  const float* v_b1    = (const float*)d_in[25];
  const float* v_W2    = (const float*)d_in[26];
  const float* v_b2    = (const float*)d_in[27];

  char* ws = (char*)d_ws;
  int*   deg    = (int*)(ws + OFF_DEG);
  int*   indptr = (int*)(ws + OFF_INDPTR);
  int*   cursor = (int*)(ws + OFF_CURSOR);
  int*   blksum = (int*)(ws + OFF_BLKSUM);
  float* Mg     = (float*)(ws + OFF_MG);
  float* Mh     = (float*)(ws + OFF_MH);
  float* msum   = (float*)(ws + OFF_MEAN);
  float* tpsum  = (float*)(ws + OFF_TPSUM);
  float* tpcnt  = (float*)(ws + OFF_TPCNT);
  uint4* er0    = (uint4*)(ws + OFF_ER0);
  uint4* er1    = (uint4*)(ws + OFF_ER1);
  uint4* er2    = (uint4*)(ws + OFF_ER2);
  float* a_src  = (float*)(ws + OFF_ASRC);
  float* a_dst  = (float*)(ws + OFF_ADST);
  float* ht     = (float*)(ws + OFF_HT);
  __hip_bfloat16* htb = (__hip_bfloat16*)(ws + OFF_HTB);
  __hip_bfloat16* xl  = (__hip_bfloat16*)(ws + OFF_XL);
  __hip_bfloat16* agg = (__hip_bfloat16*)(ws + OFF_AGG);
  __hip_bfloat16* wxf = (__hip_bfloat16*)(ws + OFF_WXF);
  __hip_bfloat16* wpf = (__hip_bfloat16*)(ws + OFF_WPF);
  uint4* ers[3] = {er0, er1, er2};

  float* out_logits = (float*)d_out;
  float* out_value  = (float*)d_out + NT;
  float* out_ht     = (float*)d_out + NT + NG;
  float* out_hp     = (float*)d_out + NT + NG + (size_t)NT * EMBD;

  hipMemsetAsync(ws + OFF_DEG, 0, NT * 4, stream);
  hipMemsetAsync(ws + OFF_MEAN, 0, 2144, stream);  // msum + tpsum + tpcnt

  k_embed_task<<<782, 256, 0, stream>>>(x_task, W_task, b_task, ht, htb);
  k_degree_mean<<<(ET + 255) / 256, 256, 0, stream>>>(eidx + NE, eattr, deg, msum);
  k_scanA<<<NBLK, 1024, 0, stream>>>(deg, indptr, blksum);
  k_scanB<<<NBLK, 1024, 0, stream>>>(blksum, indptr, cursor);
  k_mprep<<<1, 128, 0, stream>>>(gat_We, att_edge, msum, Mg, Mh);
  k_fill<<<(ET + 255) / 256, 256, 0, stream>>>(eidx, eidx + NE, eattr, Mg, Mh,
                                               cursor, er0, er1, er2);
  k_prep_w<<<192, 64, 0, stream>>>(gat_W, proj_W, wxf, wpf);

  for (int l = 0; l < 3; l++) {
    k_xl_mfma<<<782, 256, 0, stream>>>(htb, wxf + (size_t)l * 16384,
                                       att_src + l * NHEADS * EMBD,
                                       att_dst + l * NHEADS * EMBD,
                                       xl, a_src, a_dst);
    k_attn<<<NT / 4, 256, 0, stream>>>(xl, a_src, a_dst, ers[l], indptr,
                                       gat_b + l * HE, agg);
    float* htout = (l == 2) ? out_ht : ht;
    k_proj_mfma<<<782, 256, 0, stream>>>(agg, wpf + (size_t)l * 16384,
                                         proj_b + l * EMBD, ln_g + l * EMBD,
                                         ln_b + l * EMBD, ht, htout, htb,
                                         (l == 2) ? 0 : 1);
  }

  k_task_head<<<NT / 8, 256, 0, stream>>>(out_ht, pt_W1, pt_b1, pt_W2, pt_b2, out_logits);
  k_pool_task<<<(NT + 511) / 512, 256, 0, stream>>>(out_ht, tbatch, tpsum, tpcnt);
  k_value<<<1, 512, 0, stream>>>(tpsum, tpcnt, x_proc, W_proc, b_proc, out_hp,
                                 pbatch, v_W1, v_b1, v_W2, v_b2, out_value);
}

// Round 9
// 684.692 us; speedup vs baseline: 2.3968x; 1.0145x over previous
//
#include <hip/hip_runtime.h>
#include <hip/hip_bf16.h>
#include <math.h>

#define NT 50000
#define NP 256
#define NE 800000
#define ET 850000   // NE + NT self loops
#define EMBD 64
#define NHEADS 4
#define HE 256      // NHEADS*EMBD
#define NG 8
#define NBLK 49     // scan blocks of 1024

typedef __attribute__((ext_vector_type(8))) short bf16x8;
typedef __attribute__((ext_vector_type(4))) float f32x4;

// ---- workspace layout (bytes) ----
#define OFF_DEG    0u           // 50000 i32
#define OFF_INDPTR 200192u      // 50001 i32
#define OFF_CURSOR 400384u      // 50000 i32
#define OFF_BLKSUM 600576u      // 64 i32
#define OFF_MG     600832u      // 96 f32
#define OFF_MH     601216u      // 12 f32
#define OFF_MEAN   601280u      // 8 f32            <- memset zone start
#define OFF_TPSUM  601344u      // 512 f32
#define OFF_TPCNT  603392u      // 8 f32            <- memset zone end (2144 B)
#define OFF_ER0    603648u      // 850000 uint4 {src, ae01, ae23, 0}
#define OFF_ER1    14203648u
#define OFF_ER2    27803648u
#define OFF_ASRC   41403648u    // 50048*4 f32
#define OFF_ADST   42204416u
#define OFF_HT     43005184u    // 50048*64 f32
#define OFF_XL     55817472u    // 50000*256 bf16
#define OFF_AGG    81417472u    // 50048*256 bf16
#define OFF_WXF    107042048u   // 3*16384 bf16
#define OFF_WPF    107140352u   // 3*16384 bf16
#define OFF_WSD    107238656u   // 3*1024 bf16 (a_src/a_dst MFMA B-tiles)
// total ~107.3 MB

__device__ __forceinline__ float bf_lo(unsigned int u) {
  union { unsigned int i; float f; } v; v.i = u << 16; return v.f;
}
__device__ __forceinline__ float bf_hi(unsigned int u) {
  union { unsigned int i; float f; } v; v.i = u & 0xffff0000u; return v.f;
}
__device__ __forceinline__ unsigned pk2(float a, float b) {
  unsigned ua = __bfloat16_as_ushort(__float2bfloat16(a));
  unsigned ub = __bfloat16_as_ushort(__float2bfloat16(b));
  return ua | (ub << 16);
}

// ---------------- degree + edge_attr mean (fused) ----------------
__global__ __launch_bounds__(256) void k_degree_mean(const int* __restrict__ ei1,
    const float* __restrict__ ea, int* __restrict__ deg, float* __restrict__ sums) {
  __shared__ float lds[256];
  int tid = threadIdx.x;
  int e = blockIdx.x * 256 + tid;
  if (e < ET) {
    int d = (e < NE) ? ei1[e] : (e - NE);
    atomicAdd(&deg[d], 1);
  }
  int k = tid & 7, rl = tid >> 3;
  float s = 0.f;
  for (int row = blockIdx.x * 32 + rl; row < NE; row += gridDim.x * 32)
    s += ea[(size_t)row * 8 + k];
  lds[tid] = s;
  __syncthreads();
  for (int off = 128; off >= 8; off >>= 1) {
    if (tid < off) lds[tid] += lds[tid + off];
    __syncthreads();
  }
  if (tid < 8) atomicAdd(&sums[tid], lds[tid]);
}

// ---------------- parallel scan (2 kernels) ----------------
__global__ __launch_bounds__(1024) void k_scanA(const int* __restrict__ deg,
    int* __restrict__ indptr, int* __restrict__ blksum) {
  __shared__ int wsum[16];
  int tid = threadIdx.x, lane = tid & 63, wid = tid >> 6;
  int i = blockIdx.x * 1024 + tid;
  int v = (i < NT) ? deg[i] : 0;
  int x = v;
  #pragma unroll
  for (int off = 1; off < 64; off <<= 1) {
    int t = __shfl_up(x, off, 64);
    if (lane >= off) x += t;
  }
  if (lane == 63) wsum[wid] = x;
  __syncthreads();
  if (wid == 0 && lane < 16) {
    int w = wsum[lane];
    #pragma unroll
    for (int off = 1; off < 16; off <<= 1) {
      int t = __shfl_up(w, off, 64);
      if (lane >= off) w += t;
    }
    wsum[lane] = w;  // inclusive
  }
  __syncthreads();
  int woff = (wid == 0) ? 0 : wsum[wid - 1];
  if (i < NT) indptr[i] = x + woff - v;   // block-local exclusive
  if (tid == 1023) blksum[blockIdx.x] = wsum[15];
}

__global__ __launch_bounds__(1024) void k_scanB(const int* __restrict__ blksum,
    int* __restrict__ indptr, int* __restrict__ cursor) {
  __shared__ int bs[NBLK];
  int tid = threadIdx.x;
  if (tid < NBLK) bs[tid] = blksum[tid];
  __syncthreads();
  int off = 0;
  for (int j = 0; j < (int)blockIdx.x; j++) off += bs[j];
  int i = blockIdx.x * 1024 + tid;
  if (i < NT) {
    int e = indptr[i] + off;
    indptr[i] = e;
    cursor[i] = e;
  }
  if (blockIdx.x == 0 && tid == 0) {
    int tot = 0;
    for (int j = 0; j < NBLK; j++) tot += bs[j];
    indptr[NT] = tot;
  }
}

// ---------------- M matrices + wsd tiles (all 3 layers) ----------------
__global__ __launch_bounds__(256) void k_mprep(const float* __restrict__ We,
    const float* __restrict__ ae, const float* __restrict__ msum,
    const float* __restrict__ Wx, const float* __restrict__ as_all,
    const float* __restrict__ ad_all,
    float* __restrict__ Mg, float* __restrict__ Mh, __hip_bfloat16* __restrict__ wsd) {
  int t = threadIdx.x;
  if (t < 96) {
    int l = t >> 5, idx = t & 31, k = idx >> 2, h = idx & 3;
    const float* Wl = We + (size_t)l * 8 * HE;
    const float* al = ae + (size_t)l * NHEADS * EMBD;
    float s = 0.f;
    #pragma unroll
    for (int d = 0; d < 64; d++) s += Wl[k * HE + h * 64 + d] * al[h * 64 + d];
    Mg[t] = s;
  }
  __syncthreads();
  if (t < 12) {
    int l = t >> 2, h = t & 3;
    float m = 0.f;
    #pragma unroll
    for (int k = 0; k < 8; k++) m += msum[k] * (1.f / NE) * Mg[l * 32 + k * 4 + h];
    Mh[t] = m;
  }
  // wsd: per layer l, B-tile value for (kb, lane, j): k = kb*32+quad*8+j, col=l15
  // col<4: was_h (h=col), col in 4..7: wad_h, else 0
  for (int v = t; v < 3072; v += 256) {
    int l = v >> 10, rem = v & 1023;
    int kb = rem >> 9, rem2 = rem & 511;
    int lane = rem2 >> 3, j = rem2 & 7;
    int quad = lane >> 4, l15 = lane & 15;
    int k = kb * 32 + quad * 8 + j;
    float val = 0.f;
    if (l15 < 8) {
      int h = l15 & 3;
      const float* av = ((l15 < 4) ? as_all : ad_all) + (size_t)l * NHEADS * EMBD + h * 64;
      const float* Wr = Wx + (size_t)l * 64 * 256 + (size_t)k * 256 + h * 64;
      #pragma unroll
      for (int d = 0; d < 64; d++) val += Wr[d] * av[d];
    }
    wsd[(size_t)l * 1024 + (size_t)(kb * 64 + lane) * 8 + j] = __float2bfloat16(val);
  }
}

// ---------------- CSR fill: packed per-layer records {src, aeh bf16 x4} ----------------
__global__ __launch_bounds__(256) void k_fill(const int* __restrict__ ei0,
    const int* __restrict__ ei1, const float* __restrict__ ea,
    const float* __restrict__ Mg, const float* __restrict__ Mh,
    int* __restrict__ cursor,
    uint4* __restrict__ er0, uint4* __restrict__ er1, uint4* __restrict__ er2) {
  __shared__ float MgS[96];
  __shared__ float MhS[12];
  int t = threadIdx.x;
  if (t < 96) MgS[t] = Mg[t];
  if (t < 12) MhS[t] = Mh[t];
  __syncthreads();
  int e = blockIdx.x * 256 + t;
  if (e >= ET) return;
  int d, s;
  float r[3][4];
  if (e < NE) {
    d = ei1[e]; s = ei0[e];
    const float4* pp = (const float4*)(ea + (size_t)e * 8);
    float4 v0 = pp[0], v1 = pp[1];
    float v[8] = {v0.x, v0.y, v0.z, v0.w, v1.x, v1.y, v1.z, v1.w};
    #pragma unroll
    for (int l = 0; l < 3; l++) {
      #pragma unroll
      for (int h = 0; h < 4; h++) {
        float acc = 0.f;
        #pragma unroll
        for (int k = 0; k < 8; k++) acc += v[k] * MgS[l * 32 + k * 4 + h];
        r[l][h] = acc;
      }
    }
  } else {
    d = e - NE; s = d;
    #pragma unroll
    for (int l = 0; l < 3; l++)
      #pragma unroll
      for (int h = 0; h < 4; h++) r[l][h] = MhS[l * 4 + h];
  }
  int p = atomicAdd(&cursor[d], 1);
  uint4 rc;
  rc.x = (unsigned)s; rc.w = 0u;
  rc.y = pk2(r[0][0], r[0][1]); rc.z = pk2(r[0][2], r[0][3]); er0[p] = rc;
  rc.y = pk2(r[1][0], r[1][1]); rc.z = pk2(r[1][2], r[1][3]); er1[p] = rc;
  rc.y = pk2(r[2][0], r[2][1]); rc.z = pk2(r[2][2], r[2][3]); er2[p] = rc;
}

// ---------------- weight fragment prep (fused xl+proj) ----------------
__global__ void k_prep_w(const float* __restrict__ Wx, const float* __restrict__ Wp,
                         __hip_bfloat16* __restrict__ Wxf, __hip_bfloat16* __restrict__ Wpf) {
  int lane = threadIdx.x;
  int bid = blockIdx.x;
  int quad = lane >> 4, l15 = lane & 15;
  if (bid < 96) {
    int l = bid >> 5, rem = bid & 31, t = rem >> 1, kb = rem & 1;
    const float* Wl = Wx + (size_t)l * 64 * 256;
    __hip_bfloat16* out = Wxf + (size_t)l * 16384 + (size_t)((t * 2 + kb) * 64 + lane) * 8;
    #pragma unroll
    for (int j = 0; j < 8; j++)
      out[j] = __float2bfloat16(Wl[(kb * 32 + quad * 8 + j) * 256 + t * 16 + l15]);
  } else {
    bid -= 96;
    int l = bid >> 5, rem = bid & 31, t = rem >> 3, kb = rem & 7;
    const float* Wl = Wp + (size_t)l * 256 * 64;
    __hip_bfloat16* out = Wpf + (size_t)l * 16384 + (size_t)((t * 8 + kb) * 64 + lane) * 8;
    #pragma unroll
    for (int j = 0; j < 8; j++)
      out[j] = __float2bfloat16(Wl[(kb * 32 + quad * 8 + j) * 64 + t * 16 + l15]);
  }
}

// ---------------- fused embed + xl(0) + a_src/a_dst(0) ----------------
__global__ __launch_bounds__(256) void k_embed_xl(const float* __restrict__ x,
    const float* __restrict__ W, const float* __restrict__ b,
    const __hip_bfloat16* __restrict__ Wf, const __hip_bfloat16* __restrict__ wsd,
    float* __restrict__ ht, __hip_bfloat16* __restrict__ xl,
    float* __restrict__ a_src, float* __restrict__ a_dst) {
  __shared__ __hip_bfloat16 hbuf[64 * 72];
  __shared__ __hip_bfloat16 cb16[64 * 264];
  int tid = threadIdx.x, lane = tid & 63, wave = tid >> 6;
  int quad = lane >> 4, l15 = lane & 15;
  int r0 = blockIdx.x * 64;
  // embed phase
  {
    float breg[16];
    #pragma unroll
    for (int k = 0; k < 16; k++) breg[k] = W[k * 64 + lane];
    float bias = b[lane];
    #pragma unroll 1
    for (int rr = 0; rr < 16; rr++) {
      int row = r0 + wave * 16 + rr;
      float acc = bias;
      if (row < NT) {
        const float4* xr = (const float4*)(x + (size_t)row * 16);
        #pragma unroll
        for (int q = 0; q < 4; q++) {
          float4 v = xr[q];
          acc += v.x * breg[q*4+0] + v.y * breg[q*4+1] + v.z * breg[q*4+2] + v.w * breg[q*4+3];
        }
        ht[(size_t)row * 64 + lane] = acc;
      }
      hbuf[(wave * 16 + rr) * 72 + lane] = __float2bfloat16(acc);
    }
  }
  __syncthreads();
  // xl MFMA phase (A from LDS)
  f32x4 acc[16], accE;
  #pragma unroll
  for (int t = 0; t < 16; t++) acc[t] = (f32x4){0.f, 0.f, 0.f, 0.f};
  accE = (f32x4){0.f, 0.f, 0.f, 0.f};
  #pragma unroll
  for (int kb = 0; kb < 2; kb++) {
    bf16x8 a = *(const bf16x8*)(&hbuf[(wave * 16 + l15) * 72 + kb * 32 + quad * 8]);
    #pragma unroll
    for (int t = 0; t < 16; t++) {
      bf16x8 bfr = *(const bf16x8*)(Wf + (size_t)((t * 2 + kb) * 64 + lane) * 8);
      acc[t] = __builtin_amdgcn_mfma_f32_16x16x32_bf16(a, bfr, acc[t], 0, 0, 0);
    }
    bf16x8 bs = *(const bf16x8*)(wsd + (size_t)(kb * 64 + lane) * 8);
    accE = __builtin_amdgcn_mfma_f32_16x16x32_bf16(a, bs, accE, 0, 0, 0);
  }
  int rloc = wave * 16 + quad * 4;
  #pragma unroll
  for (int t = 0; t < 16; t++) {
    #pragma unroll
    for (int reg = 0; reg < 4; reg++)
      cb16[(rloc + reg) * 264 + t * 16 + l15] = __float2bfloat16(acc[t][reg]);
  }
  #pragma unroll
  for (int reg = 0; reg < 4; reg++) {
    int row = r0 + rloc + reg;
    if (l15 < 8 && row < NT) {
      float* dst = (l15 < 4) ? a_src : a_dst;
      dst[row * 4 + (l15 & 3)] = accE[reg];
    }
  }
  __syncthreads();
  #pragma unroll
  for (int k = 0; k < 8; k++) {
    int c = k * 256 + tid;
    int row = c >> 5, off = c & 31;
    if (r0 + row < NT) {
      uint4 v = *(const uint4*)(&cb16[row * 264 + off * 8]);
      *(uint4*)(xl + (size_t)(r0 + row) * HE + off * 8) = v;
    }
  }
}

// ---------------- fused softmax + aggregate ----------------
__global__ __launch_bounds__(256) void k_attn(
    const __hip_bfloat16* __restrict__ xl, const float* __restrict__ a_src,
    const float* __restrict__ a_dst, const uint4* __restrict__ er,
    const int* __restrict__ indptr, const float* __restrict__ gb,
    __hip_bfloat16* __restrict__ agg) {
  int node = blockIdx.x * 4 + (threadIdx.x >> 6);
  int lane = threadIdx.x & 63;
  int h = lane >> 4;
  int hbase = lane & 48;
  int e15 = lane & 15;
  int beg = indptr[node], end = indptr[node + 1];
  float adh = a_dst[node * 4 + h];
  float M = -1e30f, S = 0.f;
  float acc0 = 0.f, acc1 = 0.f, acc2 = 0.f, acc3 = 0.f;
  for (int base = beg; base < end; base += 16) {
    int cnt = min(16, end - base);
    bool ok = e15 < cnt;
    uint4 rec; rec.x = 0u; rec.y = 0u; rec.z = 0u; rec.w = 0u;
    if (ok) rec = er[base + e15];
    int my_src = (int)rec.x;
    unsigned wsel = (h < 2) ? rec.y : rec.z;
    float aeh = (h & 1) ? bf_hi(wsel) : bf_lo(wsel);
    float asr = ok ? a_src[(size_t)my_src * 4 + h] : 0.f;
    float al = asr + adh + aeh;
    al = (al > 0.f) ? al : 0.2f * al;
    if (!ok) al = -1e30f;
    float cm = al;
    #pragma unroll
    for (int off = 1; off < 16; off <<= 1) cm = fmaxf(cm, __shfl_xor(cm, off, 64));
    float newM = fmaxf(M, cm);
    float corr = __expf(M - newM);
    float ex = __expf(al - newM);
    float cs = ex;
    #pragma unroll
    for (int off = 1; off < 16; off <<= 1) cs += __shfl_xor(cs, off, 64);
    S = S * corr + cs;
    M = newM;
    acc0 *= corr; acc1 *= corr; acc2 *= corr; acc3 *= corr;
    if (cnt == 16) {
      #pragma unroll 4
      for (int j = 0; j < 16; j++) {
        int src = __shfl(my_src, j, 64);
        float cf = __shfl(ex, hbase | j, 64);
        uint2 u = *(const uint2*)(xl + (size_t)src * HE + lane * 4);
        acc0 += cf * bf_lo(u.x);
        acc1 += cf * bf_hi(u.x);
        acc2 += cf * bf_lo(u.y);
        acc3 += cf * bf_hi(u.y);
      }
    } else {
      for (int j = 0; j < cnt; j++) {
        int src = __shfl(my_src, j, 64);
        float cf = __shfl(ex, hbase | j, 64);
        uint2 u = *(const uint2*)(xl + (size_t)src * HE + lane * 4);
        acc0 += cf * bf_lo(u.x);
        acc1 += cf * bf_hi(u.x);
        acc2 += cf * bf_lo(u.y);
        acc3 += cf * bf_hi(u.y);
      }
    }
  }
  float inv = 1.f / (S + 1e-16f);
  float4 g4 = *(const float4*)(gb + lane * 4);
  unsigned int o0 = __bfloat16_as_ushort(__float2bfloat16(acc0 * inv + g4.x));
  unsigned int o1 = __bfloat16_as_ushort(__float2bfloat16(acc1 * inv + g4.y));
  unsigned int o2 = __bfloat16_as_ushort(__float2bfloat16(acc2 * inv + g4.z));
  unsigned int o3 = __bfloat16_as_ushort(__float2bfloat16(acc3 * inv + g4.w));
  uint2 out; out.x = o0 | (o1 << 16); out.y = o2 | (o3 << 16);
  *(uint2*)(agg + (size_t)node * HE + lane * 4) = out;
}

// ---------------- fused proj + LN + next-layer xl + a_src/a_dst ----------------
__global__ __launch_bounds__(256) void k_proj_xl(
    const __hip_bfloat16* __restrict__ agg, const __hip_bfloat16* __restrict__ Wpf,
    const float* __restrict__ pb, const float* __restrict__ g, const float* __restrict__ bln,
    const float* __restrict__ ht_io,
    const __hip_bfloat16* __restrict__ Wxf, const __hip_bfloat16* __restrict__ wsd,
    float* __restrict__ ht_out, __hip_bfloat16* __restrict__ xl,
    float* __restrict__ a_src, float* __restrict__ a_dst) {
  __shared__ __hip_bfloat16 cb16[64 * 264];   // also used as f32 cbuf (pitch 68)
  __shared__ __hip_bfloat16 hbuf[64 * 72];
  __shared__ float pbL[64], gL[64], bL[64];
  float* cbf = (float*)cb16;
  int tid = threadIdx.x, lane = tid & 63, wave = tid >> 6;
  int quad = lane >> 4, l15 = lane & 15;
  if (tid < 64) { pbL[tid] = pb[tid]; gL[tid] = g[tid]; bL[tid] = bln[tid]; }
  int r0 = blockIdx.x * 64;
  int arow = r0 + wave * 16 + l15;
  // proj MFMA
  {
    f32x4 pacc[4];
    #pragma unroll
    for (int t = 0; t < 4; t++) pacc[t] = (f32x4){0.f, 0.f, 0.f, 0.f};
    #pragma unroll
    for (int kb = 0; kb < 8; kb++) {
      bf16x8 a = *(const bf16x8*)(agg + (size_t)arow * HE + kb * 32 + quad * 8);
      #pragma unroll
      for (int t = 0; t < 4; t++) {
        bf16x8 bfr = *(const bf16x8*)(Wpf + (size_t)((t * 8 + kb) * 64 + lane) * 8);
        pacc[t] = __builtin_amdgcn_mfma_f32_16x16x32_bf16(a, bfr, pacc[t], 0, 0, 0);
      }
    }
    int rloc = wave * 16 + quad * 4;
    #pragma unroll
    for (int t = 0; t < 4; t++) {
      #pragma unroll
      for (int reg = 0; reg < 4; reg++)
        cbf[(rloc + reg) * 68 + t * 16 + l15] = pacc[t][reg];
    }
  }
  __syncthreads();
  // LN phase: thread (r = tid>>2, q = tid&3); 4 consecutive lanes share a row
  {
    int r = tid >> 2, q = tid & 3;
    int row = r0 + r;
    float h[16], s1 = 0.f, s2 = 0.f;
    const float* hin = ht_io + (size_t)row * 64 + q * 16;
    #pragma unroll
    for (int d = 0; d < 16; d++) {
      float u = cbf[r * 68 + q * 16 + d] + pbL[q * 16 + d];
      u = (u > 0.f) ? u : (__expf(u) - 1.f);
      float hv = hin[d] + u;
      h[d] = hv;
      s1 += hv; s2 += hv * hv;
    }
    s1 += __shfl_xor(s1, 1, 64); s1 += __shfl_xor(s1, 2, 64);
    s2 += __shfl_xor(s2, 1, 64); s2 += __shfl_xor(s2, 2, 64);
    float mu = s1 * 0.015625f;
    float var = s2 * 0.015625f - mu * mu;
    float rstd = rsqrtf(var + 1e-5f);
    float o[16];
    #pragma unroll
    for (int d = 0; d < 16; d++)
      o[d] = (h[d] - mu) * rstd * gL[q * 16 + d] + bL[q * 16 + d];
    if (row < NT) {
      float* outp = ht_out + (size_t)row * 64 + q * 16;
      #pragma unroll
      for (int d4 = 0; d4 < 4; d4++) {
        float4 v; v.x = o[d4*4]; v.y = o[d4*4+1]; v.z = o[d4*4+2]; v.w = o[d4*4+3];
        *(float4*)(outp + d4 * 4) = v;
      }
    }
    uint4 u0, u1;
    u0.x = pk2(o[0], o[1]);  u0.y = pk2(o[2], o[3]);
    u0.z = pk2(o[4], o[5]);  u0.w = pk2(o[6], o[7]);
    u1.x = pk2(o[8], o[9]);  u1.y = pk2(o[10], o[11]);
    u1.z = pk2(o[12], o[13]); u1.w = pk2(o[14], o[15]);
    uint4* hb = (uint4*)(&hbuf[r * 72 + q * 16]);
    hb[0] = u0; hb[1] = u1;
  }
  __syncthreads();
  // next-layer xl MFMA (A from hbuf) — cbf region is dead, reuse as bf16
  f32x4 acc[16], accE;
  #pragma unroll
  for (int t = 0; t < 16; t++) acc[t] = (f32x4){0.f, 0.f, 0.f, 0.f};
  accE = (f32x4){0.f, 0.f, 0.f, 0.f};
  #pragma unroll
  for (int kb = 0; kb < 2; kb++) {
    bf16x8 a = *(const bf16x8*)(&hbuf[(wave * 16 + l15) * 72 + kb * 32 + quad * 8]);
    #pragma unroll
    for (int t = 0; t < 16; t++) {
      bf16x8 bfr = *(const bf16x8*)(Wxf + (size_t)((t * 2 + kb) * 64 + lane) * 8);
      acc[t] = __builtin_amdgcn_mfma_f32_16x16x32_bf16(a, bfr, acc[t], 0, 0, 0);
    }
    bf16x8 bs = *(const bf16x8*)(wsd + (size_t)(kb * 64 + lane) * 8);
    accE = __builtin_amdgcn_mfma_f32_16x16x32_bf16(a, bs, accE, 0, 0, 0);
  }
  int rloc = wave * 16 + quad * 4;
  #pragma unroll
  for (int t = 0; t < 16; t++) {
    #pragma unroll
    for (int reg = 0; reg < 4; reg++)
      cb16[(rloc + reg) * 264 + t * 16 + l15] = __float2bfloat16(acc[t][reg]);
  }
  #pragma unroll
  for (int reg = 0; reg < 4; reg++) {
    int row = r0 + rloc + reg;
    if (l15 < 8 && row < NT) {
      float* dst = (l15 < 4) ? a_src : a_dst;
      dst[row * 4 + (l15 & 3)] = accE[reg];
    }
  }
  __syncthreads();
  #pragma unroll
  for (int k = 0; k < 8; k++) {
    int c = k * 256 + tid;
    int row = c >> 5, off = c & 31;
    if (r0 + row < NT) {
      uint4 v = *(const uint4*)(&cb16[row * 264 + off * 8]);
      *(uint4*)(xl + (size_t)(r0 + row) * HE + off * 8) = v;
    }
  }
}

// ---------------- last-layer proj + LN (writes out_ht only) ----------------
__global__ __launch_bounds__(256) void k_proj_last(
    const __hip_bfloat16* __restrict__ agg, const __hip_bfloat16* __restrict__ Wpf,
    const float* __restrict__ pb, const float* __restrict__ g, const float* __restrict__ bln,
    const float* __restrict__ ht_in, float* __restrict__ ht_out) {
  __shared__ float cbf[64 * 68];
  __shared__ float pbL[64], gL[64], bL[64];
  int tid = threadIdx.x, lane = tid & 63, wave = tid >> 6;
  int quad = lane >> 4, l15 = lane & 15;
  if (tid < 64) { pbL[tid] = pb[tid]; gL[tid] = g[tid]; bL[tid] = bln[tid]; }
  int r0 = blockIdx.x * 64;
  int arow = r0 + wave * 16 + l15;
  f32x4 pacc[4];
  #pragma unroll
  for (int t = 0; t < 4; t++) pacc[t] = (f32x4){0.f, 0.f, 0.f, 0.f};
  #pragma unroll
  for (int kb = 0; kb < 8; kb++) {
    bf16x8 a = *(const bf16x8*)(agg + (size_t)arow * HE + kb * 32 + quad * 8);
    #pragma unroll
    for (int t = 0; t < 4; t++) {
      bf16x8 bfr = *(const bf16x8*)(Wpf + (size_t)((t * 8 + kb) * 64 + lane) * 8);
      pacc[t] = __builtin_amdgcn_mfma_f32_16x16x32_bf16(a, bfr, pacc[t], 0, 0, 0);
    }
  }
  int rloc = wave * 16 + quad * 4;
  #pragma unroll
  for (int t = 0; t < 4; t++) {
    #pragma unroll
    for (int reg = 0; reg < 4; reg++)
      cbf[(rloc + reg) * 68 + t * 16 + l15] = pacc[t][reg];
  }
  __syncthreads();
  int r = tid >> 2, q = tid & 3;
  int row = r0 + r;
  float h[16], s1 = 0.f, s2 = 0.f;
  const float* hin = ht_in + (size_t)row * 64 + q * 16;
  #pragma unroll
  for (int d = 0; d < 16; d++) {
    float u = cbf[r * 68 + q * 16 + d] + pbL[q * 16 + d];
    u = (u > 0.f) ? u : (__expf(u) - 1.f);
    float hv = hin[d] + u;
    h[d] = hv;
    s1 += hv; s2 += hv * hv;
  }
  s1 += __shfl_xor(s1, 1, 64); s1 += __shfl_xor(s1, 2, 64);
  s2 += __shfl_xor(s2, 1, 64); s2 += __shfl_xor(s2, 2, 64);
  float mu = s1 * 0.015625f;
  float var = s2 * 0.015625f - mu * mu;
  float rstd = rsqrtf(var + 1e-5f);
  if (row < NT) {
    float* outp = ht_out + (size_t)row * 64 + q * 16;
    #pragma unroll
    for (int d4 = 0; d4 < 4; d4++) {
      float4 v;
      v.x = (h[d4*4+0] - mu) * rstd * gL[q*16+d4*4+0] + bL[q*16+d4*4+0];
      v.y = (h[d4*4+1] - mu) * rstd * gL[q*16+d4*4+1] + bL[q*16+d4*4+1];
      v.z = (h[d4*4+2] - mu) * rstd * gL[q*16+d4*4+2] + bL[q*16+d4*4+2];
      v.w = (h[d4*4+3] - mu) * rstd * gL[q*16+d4*4+3] + bL[q*16+d4*4+3];
      *(float4*)(outp + d4 * 4) = v;
    }
  }
}

// ---------------- heads ----------------
__global__ __launch_bounds__(256) void k_task_head(const float* __restrict__ ht,
    const float* __restrict__ W1, const float* __restrict__ b1,
    const float* __restrict__ W2, const float* __restrict__ b2, float* __restrict__ logits) {
  __shared__ float lh[8 * 64];
  int t = threadIdx.x;
  size_t base = (size_t)blockIdx.x * 8 * 64;
  lh[t] = ht[base + t];
  lh[t + 256] = ht[base + t + 256];
  __syncthreads();
  int i = t >> 5, j = t & 31;
  float s = b1[j];
  #pragma unroll 8
  for (int d = 0; d < 64; d++) s += lh[i * 64 + d] * W1[d * 32 + j];
  s = fmaxf(s, 0.f);
  float p = s * W2[j];
  #pragma unroll
  for (int off = 16; off; off >>= 1) p += __shfl_xor(p, off, 64);
  if (j == 0) logits[blockIdx.x * 8 + i] = p + b2[0];
}

__global__ __launch_bounds__(256) void k_pool_task(const float* __restrict__ ht,
    const int* __restrict__ tb, float* __restrict__ sums, float* __restrict__ cnt) {
  int lane = threadIdx.x & 63, sub = threadIdx.x >> 6;
  float acc[8], c[8];
  #pragma unroll
  for (int g = 0; g < 8; g++) { acc[g] = 0.f; c[g] = 0.f; }
  int lim = min(NT, (int)((blockIdx.x + 1) * 512));
  for (int n = blockIdx.x * 512 + sub; n < lim; n += 4) {
    int g = tb[n];
    float v = ht[(size_t)n * 64 + lane];
    #pragma unroll
    for (int gg = 0; gg < 8; gg++) {
      if (g == gg) { acc[gg] += v; c[gg] += 1.f; }
    }
  }
  #pragma unroll
  for (int g = 0; g < 8; g++) {
    if (__any(acc[g] != 0.f || c[g] != 0.f)) {
      atomicAdd(&sums[g * 64 + lane], acc[g]);
      if (lane == 0) atomicAdd(&cnt[g], c[g]);
    }
  }
}

// value head with fused proc embed (writes out_hp too)
__global__ __launch_bounds__(512) void k_value(const float* __restrict__ tpsum,
    const float* __restrict__ tpcnt, const float* __restrict__ x_proc,
    const float* __restrict__ W_proc, const float* __restrict__ b_proc,
    float* __restrict__ hp_out, const int* __restrict__ pbatch,
    const float* __restrict__ vW1, const float* __restrict__ vb1,
    const float* __restrict__ vW2, const float* __restrict__ vb2,
    float* __restrict__ val_out) {
  __shared__ float ge[8 * 128];
  int t = threadIdx.x;
  int g = t >> 6, d = t & 63;
  float wreg[8];
  #pragma unroll
  for (int k = 0; k < 8; k++) wreg[k] = W_proc[k * 64 + d];
  float bd = b_proc[d];
  for (int p = g; p < 256; p += 8) {
    const float* xr = x_proc + (size_t)p * 8;
    float a = bd;
    #pragma unroll
    for (int k = 0; k < 8; k++) a += xr[k] * wreg[k];
    hp_out[(size_t)p * 64 + d] = a;
  }
  __syncthreads();
  float c = fmaxf(tpcnt[g], 1.f);
  ge[g * 128 + d] = tpsum[g * 64 + d] / c;
  float s = 0.f, cc = 0.f;
  for (int p = 0; p < 256; p++) {
    int bg = pbatch[p];
    if (bg == g) { s += hp_out[(size_t)p * 64 + d]; cc += 1.f; }
  }
  ge[g * 128 + 64 + d] = s / fmaxf(cc, 1.f);
  __syncthreads();
  float acc = vb1[d];
  #pragma unroll 8
  for (int k = 0; k < 128; k++) acc += ge[g * 128 + k] * vW1[k * 64 + d];
  acc = fmaxf(acc, 0.f);
  float p = acc * vW2[d];
  #pragma unroll
  for (int off = 32; off; off >>= 1) p += __shfl_xor(p, off, 64);
  if (d == 0) val_out[g] = p + vb2[0];
}

extern "C" void kernel_launch(void* const* d_in, const int* in_sizes, int n_in,
                              void* d_out, int out_size, void* d_ws, size_t ws_size,
                              hipStream_t stream) {
  (void)in_sizes; (void)n_in; (void)out_size; (void)ws_size;
  const float* x_task  = (const float*)d_in[0];
  const float* x_proc  = (const float*)d_in[1];
  const int*   eidx    = (const int*)d_in[2];
  const float* eattr   = (const float*)d_in[3];
  const int*   tbatch  = (const int*)d_in[4];
  const int*   pbatch  = (const int*)d_in[5];
  const float* W_task  = (const float*)d_in[6];
  const float* b_task  = (const float*)d_in[7];
  const float* W_proc  = (const float*)d_in[8];
  const float* b_proc  = (const float*)d_in[9];
  const float* gat_W   = (const float*)d_in[10];
  const float* gat_We  = (const float*)d_in[11];
  const float* att_src = (const float*)d_in[12];
  const float* att_dst = (const float*)d_in[13];
  const float* att_edge= (const float*)d_in[14];
  const float* gat_b   = (const float*)d_in[15];
  const float* proj_W  = (const float*)d_in[16];
  const float* proj_b  = (const float*)d_in[17];
  const float* ln_g    = (const float*)d_in[18];
  const float* ln_b    = (const float*)d_in[19];
  const float* pt_W1   = (const float*)d_in[20];
  const float* pt_b1   = (const float*)d_in[21];
  const float* pt_W2   = (const float*)d_in[22];
  const float* pt_b2   = (const float*)d_in[23];
  const float* v_W1    = (const float*)d_in[24];
  const float* v_b1    = (const float*)d_in[25];
  const float* v_W2    = (const float*)d_in[26];
  const float* v_b2    = (const float*)d_in[27];

  char* ws = (char*)d_ws;
  int*   deg    = (int*)(ws + OFF_DEG);
  int*   indptr = (int*)(ws + OFF_INDPTR);
  int*   cursor = (int*)(ws + OFF_CURSOR);
  int*   blksum = (int*)(ws + OFF_BLKSUM);
  float* Mg     = (float*)(ws + OFF_MG);
  float* Mh     = (float*)(ws + OFF_MH);
  float* msum   = (float*)(ws + OFF_MEAN);
  float* tpsum  = (float*)(ws + OFF_TPSUM);
  float* tpcnt  = (float*)(ws + OFF_TPCNT);
  uint4* er0    = (uint4*)(ws + OFF_ER0);
  uint4* er1    = (uint4*)(ws + OFF_ER1);
  uint4* er2    = (uint4*)(ws + OFF_ER2);
  float* a_src  = (float*)(ws + OFF_ASRC);
  float* a_dst  = (float*)(ws + OFF_ADST);
  float* ht     = (float*)(ws + OFF_HT);
  __hip_bfloat16* xl  = (__hip_bfloat16*)(ws + OFF_XL);
  __hip_bfloat16* agg = (__hip_bfloat16*)(ws + OFF_AGG);
  __hip_bfloat16* wxf = (__hip_bfloat16*)(ws + OFF_WXF);
  __hip_bfloat16* wpf = (__hip_bfloat16*)(ws + OFF_WPF);
  __hip_bfloat16* wsd = (__hip_bfloat16*)(ws + OFF_WSD);
  uint4* ers[3] = {er0, er1, er2};

  float* out_logits = (float*)d_out;
  float* out_value  = (float*)d_out + NT;
  float* out_ht     = (float*)d_out + NT + NG;
  float* out_hp     = (float*)d_out + NT + NG + (size_t)NT * EMBD;

  hipMemsetAsync(ws + OFF_DEG, 0, NT * 4, stream);
  hipMemsetAsync(ws + OFF_MEAN, 0, 2144, stream);  // msum + tpsum + tpcnt

  k_degree_mean<<<(ET + 255) / 256, 256, 0, stream>>>(eidx + NE, eattr, deg, msum);
  k_scanA<<<NBLK, 1024, 0, stream>>>(deg, indptr, blksum);
  k_scanB<<<NBLK, 1024, 0, stream>>>(blksum, indptr, cursor);
  k_mprep<<<1, 256, 0, stream>>>(gat_We, att_edge, msum, gat_W, att_src, att_dst,
                                 Mg, Mh, wsd);
  k_prep_w<<<192, 64, 0, stream>>>(gat_W, proj_W, wxf, wpf);
  k_fill<<<(ET + 255) / 256, 256, 0, stream>>>(eidx, eidx + NE, eattr, Mg, Mh,
                                               cursor, er0, er1, er2);
  k_embed_xl<<<782, 256, 0, stream>>>(x_task, W_task, b_task, wxf, wsd,
                                      ht, xl, a_src, a_dst);

  for (int l = 0; l < 3; l++) {
    k_attn<<<NT / 4, 256, 0, stream>>>(xl, a_src, a_dst, ers[l], indptr,
                                       gat_b + l * HE, agg);
    if (l < 2) {
      k_proj_xl<<<782, 256, 0, stream>>>(agg, wpf + (size_t)l * 16384,
                                         proj_b + l * EMBD, ln_g + l * EMBD,
                                         ln_b + l * EMBD, ht,
                                         wxf + (size_t)(l + 1) * 16384,
                                         wsd + (size_t)(l + 1) * 1024,
                                         ht, xl, a_src, a_dst);
    } else {
      k_proj_last<<<782, 256, 0, stream>>>(agg, wpf + (size_t)l * 16384,
                                           proj_b + l * EMBD, ln_g + l * EMBD,
                                           ln_b + l * EMBD, ht, out_ht);
    }
  }

  k_task_head<<<NT / 8, 256, 0, stream>>>(out_ht, pt_W1, pt_b1, pt_W2, pt_b2, out_logits);
  k_pool_task<<<(NT + 511) / 512, 256, 0, stream>>>(out_ht, tbatch, tpsum, tpcnt);
  k_value<<<1, 512, 0, stream>>>(tpsum, tpcnt, x_proc, W_proc, b_proc, out_hp,
                                 pbatch, v_W1, v_b1, v_W2, v_b2, out_value);
}